// Round 2
// baseline (5288.390 us; speedup 1.0000x reference)
//
#include <hip/hip_runtime.h>
#include <math.h>

#define HW_ 65536
#define NCHUNK 16
typedef long long i64;
#define TWO_PI 6.283185307179586476925f

typedef __bf16 bf16x8 __attribute__((ext_vector_type(8)));
typedef float f32x4 __attribute__((ext_vector_type(4)));

#define MFMA16(A,B,C) __builtin_amdgcn_mfma_f32_16x16x32_bf16(A,B,C,0,0,0)

__device__ __forceinline__ float sigm(float x){ return 1.0f/(1.0f+expf(-x)); }

// convert 8 consecutive fp32 to a bf16x8 A-fragment
__device__ __forceinline__ bf16x8 cvt_w8(const float* wp){
  float4 w0 = *(const float4*)wp;
  float4 w1 = *(const float4*)(wp+4);
  bf16x8 r;
  r[0]=(__bf16)w0.x; r[1]=(__bf16)w0.y; r[2]=(__bf16)w0.z; r[3]=(__bf16)w0.w;
  r[4]=(__bf16)w1.x; r[5]=(__bf16)w1.y; r[6]=(__bf16)w1.z; r[7]=(__bf16)w1.w;
  return r;
}

// ---------------- resize (nb,3,128,128) -> (nb,3,256,256) bilinear half-pixel ----------------
__global__ __launch_bounds__(256) void k_resize(const float* __restrict__ x, float* __restrict__ R, int b0){
  int idx = blockIdx.x*256 + threadIdx.x;
  int ox = idx & 255;
  int oy = (idx >> 8) & 255;
  int bc = idx >> 16;                               // lb*3 + c
  int lb = bc/3; int c = bc - lb*3;
  float sx = ox*0.5f - 0.25f;
  float sy = oy*0.5f - 0.25f;
  int x0 = (int)floorf(sx); float fx = sx - (float)x0;
  int y0 = (int)floorf(sy); float fy = sy - (float)y0;
  int x1 = min(x0+1,127); int y1 = min(y0+1,127);
  x0 = max(x0,0); y0 = max(y0,0);
  const float* p = x + ((i64)(b0+lb)*3 + c)*16384;
  float v00=p[y0*128+x0], v01=p[y0*128+x1], v10=p[y1*128+x0], v11=p[y1*128+x1];
  R[idx] = (1.0f-fy)*((1.0f-fx)*v00 + fx*v01) + fy*((1.0f-fx)*v10 + fx*v11);
}

// ---------------- conv3x3 3->64: block per (b,row), all 64 outs per thread ----------------
__global__ __launch_bounds__(256) void k_conv3(const float* __restrict__ R, const float* __restrict__ w, float* __restrict__ out){
  int y = blockIdx.x & 255; int b = blockIdx.x >> 8; int t = threadIdx.x;
  float win[27];
  #pragma unroll
  for (int ci=0;ci<3;ci++){
    #pragma unroll
    for (int ky=0;ky<3;ky++){
      int yy = y+ky-1;
      const float* ip = R + (((i64)(b*3+ci))<<16) + yy*256;
      #pragma unroll
      for (int kx=0;kx<3;kx++){
        int xx = t+kx-1;
        float v = 0.f;
        if ((unsigned)yy<256u && (unsigned)xx<256u) v = ip[xx];
        win[ci*9+ky*3+kx] = v;
      }
    }
  }
  i64 obase = ((i64)b<<22) + (y<<8) + t;
  for (int o=0;o<64;o++){
    const float* wp = w + o*27;
    float acc=0.f;
    #pragma unroll
    for (int j=0;j<27;j++) acc += wp[j]*win[j];
    out[obase + ((i64)o<<16)] = acc;
  }
}

// ---------------- DFT coeffs (7 reals incl. DC) + pooled mean per (b,c) ----------------
__global__ __launch_bounds__(256) void k_dft(const float* __restrict__ xc, float* __restrict__ coeff, float* __restrict__ pooled){
  __shared__ float tc[256], ts[256];
  __shared__ float red[256];
  int t = threadIdx.x;
  float ang = TWO_PI * ((float)t/256.0f);
  tc[t] = cosf(ang); ts[t] = sinf(ang);
  __syncthreads();
  int bc = blockIdx.x;
  const float* p = xc + (i64)bc*HW_;
  float s=0, cr=0, ci=0, rr=0, ri=0, dr=0, di=0;
  for (int i=t; i<HW_; i+=256){
    float v = p[i];
    int col = i & 255, row = i >> 8, ds = (row+col)&255;
    s  += v;
    cr += v*tc[col]; ci += v*ts[col];
    rr += v*tc[row]; ri += v*ts[row];
    dr += v*tc[ds];  di += v*ts[ds];
  }
  float vals[7] = {s,cr,ci,rr,ri,dr,di};
  for (int j=0;j<7;j++){
    red[t] = vals[j]; __syncthreads();
    for (int st=128; st>0; st>>=1){ if (t<st) red[t]+=red[t+st]; __syncthreads(); }
    if (t==0) vals[j] = red[0];
    __syncthreads();
  }
  if (t==0){
    const float sc = 1.0f/65536.0f;
    for (int j=0;j<7;j++) coeff[bc*8+j] = vals[j]*sc;
    pooled[bc] = vals[0]*sc;
  }
}

// ---------------- threshold MLP -> per-batch mask flag ----------------
__global__ __launch_bounds__(64) void k_thr(const float* __restrict__ pooled, const float* __restrict__ w1,
                      const float* __restrict__ w2, float* __restrict__ flag){
  __shared__ float hid[8];
  int b = blockIdx.x; int t = threadIdx.x;
  if (t < 8){
    float a = 0.f;
    for (int c=0;c<64;c++) a += pooled[b*64+c]*w1[t*64+c];
    hid[t] = 0.5f*a*(1.0f+erff(a*0.70710678118654752440f));
  }
  __syncthreads();
  if (t==0){
    float t0=0,t1=0;
    for (int k=0;k<8;k++){ t0 += hid[k]*w2[k]; t1 += hid[k]*w2[8+k]; }
    int h_ = (int)(2.0f*sigm(t0));
    int w_ = (int)(2.0f*sigm(t1));
    flag[b] = (h_>0 && w_>0) ? 1.0f : 0.0f;
  }
}

// ---------------- fused: high/low reconstruction + conv1x1 (q path of cca0/cca1) ----------------
template<int WHICH>   // 0 = high, 1 = low
__global__ __launch_bounds__(256) void k_convq_fre(const float* __restrict__ xc, const float* __restrict__ coeff,
      const float* __restrict__ flag, const float* __restrict__ qw, float* __restrict__ out){
  __shared__ float tc[256], ts[256];
  int t = threadIdx.x;
  float ang = TWO_PI * ((float)t/256.0f);
  tc[t]=cosf(ang); ts[t]=sinf(ang);
  __syncthreads();
  int blk2 = blockIdx.x & 127; int b = blockIdx.x >> 7;
  int px0 = blk2*512 + 2*t;
  int x0 = px0 & 255; int y = px0 >> 8;
  float fl = flag[b];
  float crow = tc[y], srow = ts[y];
  int d0 = (x0 + y) & 255;
  int d1 = (x0 + 1 + y) & 255;
  float c0=tc[x0], s0=ts[x0], c1=tc[x0+1], s1=ts[x0+1];
  float cd0=tc[d0], sd0=ts[d0], cd1=tc[d1], sd1=ts[d1];
  i64 ibase = ((i64)b<<22) + px0;
  float2 xv[64];
  #pragma unroll
  for (int c=0;c<64;c++){
    const float* cf = coeff + ((b<<6)+c)*8;
    float F00=cf[0], cR=cf[1], cI=cf[2], rR=cf[3], rI=cf[4], dR=cf[5], dI=cf[6];
    float2 xr = *(const float2*)(xc + ibase + ((i64)c<<16));
    float re0 = F00 + cR*c0 + cI*s0 + rR*crow + rI*srow + dR*cd0 + dI*sd0;
    float im0 =       cI*c0 - cR*s0 + rI*crow - rR*srow + dI*cd0 - dR*sd0;
    float re1 = F00 + cR*c1 + cI*s1 + rR*crow + rI*srow + dR*cd1 + dI*sd1;
    float im1 =       cI*c1 - cR*s1 + rI*crow - rR*srow + dI*cd1 - dR*sd1;
    re0*=fl; im0*=fl; re1*=fl; im1*=fl;
    float v0, v1;
    if (WHICH==1){ v0 = sqrtf(re0*re0+im0*im0); v1 = sqrtf(re1*re1+im1*im1); }
    else { float h0=xr.x-re0, h1=xr.y-re1; v0 = sqrtf(h0*h0+im0*im0); v1 = sqrtf(h1*h1+im1*im1); }
    xv[c] = make_float2(v0,v1);
  }
  for (int o=0;o<64;o++){
    const float* wr = qw + o*64;
    float ax=0.f, ay=0.f;
    #pragma unroll
    for (int c=0;c<64;c++){ float wv=wr[c]; ax += xv[c].x*wv; ay += xv[c].y*wv; }
    *(float2*)(out + ibase + ((i64)o<<16)) = make_float2(ax,ay);
  }
}

// =====================================================================================
// MFMA pixel-matmul family: per wave, one 64px x 64out strip.
// A-frag (weights, row-major [O][64] fp32): lane holds row = m*16+(lane&15),
//   k = s*32 + (lane>>4)*8 + j  (8 consecutive fp32 -> bf16x8).
// B-frag (input planes [c][px]): col = lane&15 -> px = p0 + 4*(lane&15) + e (e=0..3 via
//   float4 components -> 4 parity fragments), k = s*32 + (lane>>4)*8 + j (per-plane loads).
// C/D: col(px)=lane&15, row(out)=(lane>>4)*4+reg  [verified m89 layout].
// =====================================================================================

// loads B for one strip: bq[s][j] float4 (4 px per lane); builds bf[s][e] frags
#define MM_LOAD_B(in_ptr) \
  float4 bq[2][8]; \
  _Pragma("unroll") \
  for (int s=0;s<2;s++){ \
    const float* bp = (in_ptr) + ((i64)(s*32 + kg*8)<<16) + 4*lm; \
    _Pragma("unroll") \
    for (int j=0;j<8;j++) bq[s][j] = *(const float4*)(bp + ((i64)j<<16)); \
  } \
  bf16x8 bf[2][4]; \
  _Pragma("unroll") \
  for (int s=0;s<2;s++){ \
    bf16x8 f0,f1,f2,f3; \
    _Pragma("unroll") \
    for (int j=0;j<8;j++){ \
      f0[j]=(__bf16)bq[s][j].x; f1[j]=(__bf16)bq[s][j].y; \
      f2[j]=(__bf16)bq[s][j].z; f3[j]=(__bf16)bq[s][j].w; \
    } \
    bf[s][0]=f0; bf[s][1]=f1; bf[s][2]=f2; bf[s][3]=f3; \
  }

#define MM_COMPUTE(Wbase) \
  bf16x8 af[4][2]; \
  _Pragma("unroll") \
  for (int m=0;m<4;m++){ \
    _Pragma("unroll") \
    for (int s=0;s<2;s++) af[m][s] = cvt_w8((Wbase) + (m*16 + lm)*64 + s*32 + kg*8); \
  } \
  f32x4 acc[4][4]; \
  _Pragma("unroll") \
  for (int m=0;m<4;m++){ \
    _Pragma("unroll") \
    for (int e=0;e<4;e++){ f32x4 z = {0.f,0.f,0.f,0.f}; acc[m][e]=z; } \
  } \
  _Pragma("unroll") \
  for (int m=0;m<4;m++){ \
    _Pragma("unroll") \
    for (int e=0;e<4;e++){ \
      _Pragma("unroll") \
      for (int s=0;s<2;s++) acc[m][e] = MFMA16(af[m][s], bf[s][e], acc[m][e]); \
    } \
  }

#define MM_SETUP \
  int t = threadIdx.x; \
  int lane = t & 63, wvi = t >> 6; \
  i64 px0 = (i64)blockIdx.x*256 + wvi*64; \
  int b = (int)(px0 >> 16); \
  int p0 = (int)(px0 & (HW_-1)); \
  i64 ibase = ((i64)b<<22) + p0; \
  int lm = lane & 15, kg = lane >> 4;

// ---------------- conv1x1 64->128 (k and v pre-tensors), MFMA ----------------
__global__ __launch_bounds__(256) void k_mm_kv(const float* __restrict__ in, const float* __restrict__ w,
      float* __restrict__ kout, float* __restrict__ vout){
  MM_SETUP
  MM_LOAD_B(in + ibase)
  #pragma unroll
  for (int half=0; half<2; half++){
    float* outp = half ? vout : kout;
    const float* Wb = w + half*4096;
    MM_COMPUTE(Wb)
    #pragma unroll
    for (int m=0;m<4;m++){
      #pragma unroll
      for (int r=0;r<4;r++){
        int oc = m*16 + kg*4 + r;
        float4 st = make_float4(acc[m][0][r], acc[m][1][r], acc[m][2][r], acc[m][3][r]);
        *(float4*)(outp + ibase + ((i64)oc<<16) + 4*lm) = st;
      }
    }
  }
}

// ---------------- plain conv1x1 64->64, MFMA ----------------
__global__ __launch_bounds__(256) void k_mm_64(const float* __restrict__ in, const float* __restrict__ w,
      float* __restrict__ out){
  MM_SETUP
  MM_LOAD_B(in + ibase)
  MM_COMPUTE(w)
  #pragma unroll
  for (int m=0;m<4;m++){
    #pragma unroll
    for (int r=0;r<4;r++){
      int oc = m*16 + kg*4 + r;
      float4 st = make_float4(acc[m][0][r], acc[m][1][r], acc[m][2][r], acc[m][3][r]);
      *(float4*)(out + ibase + ((i64)oc<<16) + 4*lm) = st;
    }
  }
}

// ---------------- mconv high: M x v + per-px channel max/mean, MFMA ----------------
__global__ __launch_bounds__(256) void k_mm_hi(const float* __restrict__ v, const float* __restrict__ M,
        float* __restrict__ mx, float* __restrict__ mn, float* __restrict__ out){
  MM_SETUP
  MM_LOAD_B(v + ibase)
  const float* Wb = M + ((i64)b<<12);
  MM_COMPUTE(Wb)
  float pmx[4] = {-1e30f,-1e30f,-1e30f,-1e30f};
  float ps[4]  = {0.f,0.f,0.f,0.f};
  #pragma unroll
  for (int m=0;m<4;m++){
    #pragma unroll
    for (int r=0;r<4;r++){
      int oc = m*16 + kg*4 + r;
      float4 st = make_float4(acc[m][0][r], acc[m][1][r], acc[m][2][r], acc[m][3][r]);
      *(float4*)(out + ibase + ((i64)oc<<16) + 4*lm) = st;
      pmx[0]=fmaxf(pmx[0],st.x); ps[0]+=st.x;
      pmx[1]=fmaxf(pmx[1],st.y); ps[1]+=st.y;
      pmx[2]=fmaxf(pmx[2],st.z); ps[2]+=st.z;
      pmx[3]=fmaxf(pmx[3],st.w); ps[3]+=st.w;
    }
  }
  // reduce across kg groups (lanes lm, lm+16, lm+32, lm+48) -> full 64-channel reduce
  #pragma unroll
  for (int e=0;e<4;e++){
    pmx[e] = fmaxf(pmx[e], __shfl_xor(pmx[e],16));
    pmx[e] = fmaxf(pmx[e], __shfl_xor(pmx[e],32));
    ps[e] += __shfl_xor(ps[e],16);
    ps[e] += __shfl_xor(ps[e],32);
  }
  if (kg==0){
    i64 pbase = ((i64)b<<16) + p0 + 4*lm;
    *(float4*)(mx+pbase) = make_float4(pmx[0],pmx[1],pmx[2],pmx[3]);
    *(float4*)(mn+pbase) = make_float4(ps[0]*(1.0f/64.0f),ps[1]*(1.0f/64.0f),
                                       ps[2]*(1.0f/64.0f),ps[3]*(1.0f/64.0f));
  }
}

// ---------------- mconv low: M x v + per-channel sum/max partials, MFMA ----------------
__global__ __launch_bounds__(256) void k_mm_lo(const float* __restrict__ v, const float* __restrict__ M,
        float* __restrict__ out, float* __restrict__ spart){
  __shared__ float ls[4][64], lmx[4][64];
  MM_SETUP
  MM_LOAD_B(v + ibase)
  const float* Wb = M + ((i64)b<<12);
  MM_COMPUTE(Wb)
  #pragma unroll
  for (int m=0;m<4;m++){
    #pragma unroll
    for (int r=0;r<4;r++){
      int oc = m*16 + kg*4 + r;
      float4 st = make_float4(acc[m][0][r], acc[m][1][r], acc[m][2][r], acc[m][3][r]);
      *(float4*)(out + ibase + ((i64)oc<<16) + 4*lm) = st;
      float s = st.x+st.y+st.z+st.w;
      float mm = fmaxf(fmaxf(st.x,st.y),fmaxf(st.z,st.w));
      // reduce across lm within the 16-lane kg group (pixel dim)
      #pragma unroll
      for (int off=8; off; off>>=1){ s += __shfl_xor(s,off); mm = fmaxf(mm,__shfl_xor(mm,off)); }
      if (lm==0){ ls[wvi][oc]=s; lmx[wvi][oc]=mm; }
    }
  }
  __syncthreads();
  if (t<64){
    float s = ls[0][t]+ls[1][t]+ls[2][t]+ls[3][t];
    float mm = fmaxf(fmaxf(lmx[0][t],lmx[1][t]),fmaxf(lmx[2][t],lmx[3][t]));
    spart[(i64)blockIdx.x*128 + t*2]   = s;
    spart[(i64)blockIdx.x*128 + t*2+1] = mm;
  }
}

// ---------------- fused comb + refine conv1x1, MFMA ----------------
__global__ __launch_bounds__(256) void k_mm_comb(const float* __restrict__ lo2, const float* __restrict__ hi2,
        const float* __restrict__ swb, const float* __restrict__ cwv,
        const float* __restrict__ w, const float* __restrict__ bias, float* __restrict__ out){
  MM_SETUP
  float4 sw4 = *(const float4*)(swb + ((i64)b<<16) + p0 + 4*lm);
  bf16x8 bf[2][4];
  #pragma unroll
  for (int s=0;s<2;s++){
    bf16x8 f0,f1,f2,f3;
    #pragma unroll
    for (int j=0;j<8;j++){
      int ch = s*32 + kg*8 + j;
      float4 l4 = *(const float4*)(lo2 + ibase + ((i64)ch<<16) + 4*lm);
      float4 h4 = *(const float4*)(hi2 + ibase + ((i64)ch<<16) + 4*lm);
      float cw = cwv[(b<<6) + ch];
      f0[j]=(__bf16)(l4.x*sw4.x + h4.x*cw);
      f1[j]=(__bf16)(l4.y*sw4.y + h4.y*cw);
      f2[j]=(__bf16)(l4.z*sw4.z + h4.z*cw);
      f3[j]=(__bf16)(l4.w*sw4.w + h4.w*cw);
    }
    bf[s][0]=f0; bf[s][1]=f1; bf[s][2]=f2; bf[s][3]=f3;
  }
  MM_COMPUTE(w)
  #pragma unroll
  for (int m=0;m<4;m++){
    #pragma unroll
    for (int r=0;r<4;r++){
      int oc = m*16 + kg*4 + r;
      float bv = bias[oc];
      float4 st = make_float4(acc[m][0][r]+bv, acc[m][1][r]+bv, acc[m][2][r]+bv, acc[m][3][r]+bv);
      *(float4*)(out + ibase + ((i64)oc<<16) + 4*lm) = st;
    }
  }
}

// ---------------- final mconv: M x v, *para1 + y*para2, MFMA ----------------
__global__ __launch_bounds__(256) void k_mm_fin(const float* __restrict__ v, const float* __restrict__ M,
      const float* __restrict__ para1, const float* __restrict__ para2,
      const float* __restrict__ yin, float* __restrict__ out){
  MM_SETUP
  MM_LOAD_B(v + ibase)
  const float* Wb = M + ((i64)b<<12);
  MM_COMPUTE(Wb)
  #pragma unroll
  for (int m=0;m<4;m++){
    #pragma unroll
    for (int r=0;r<4;r++){
      int oc = m*16 + kg*4 + r;
      float p1 = para1[oc], p2 = para2[oc];
      float4 yv = *(const float4*)(yin + ibase + ((i64)oc<<16) + 4*lm);
      float4 st = make_float4(acc[m][0][r]*p1 + yv.x*p2,
                              acc[m][1][r]*p1 + yv.y*p2,
                              acc[m][2][r]*p1 + yv.z*p2,
                              acc[m][3][r]*p1 + yv.w*p2);
      *(float4*)(out + ibase + ((i64)oc<<16) + 4*lm) = st;
    }
  }
}

// ---------------- fused dw3x3(q)+dw3x3(k)+stats, row-rolling: per (b,head,chunk16rows) ----------------
// Separable accumulation: input row r contributes w[0]-row to out r+1, w[1]-row to out r,
// w[2]-row to out r-1. Keep 2 pending partials per plane -> each input value loaded 3x (not 9x).
__global__ __launch_bounds__(256,3) void k_statsdw(const float* __restrict__ qpre, const float* __restrict__ kpre,
        const float* __restrict__ qdw, const float* __restrict__ kdw, float* __restrict__ part){
  __shared__ float wql[8][12], wkl[8][12];   // padded to 12 for float4 reads
  __shared__ float red[4][80];
  int blk = blockIdx.x;
  int chunk = blk & (NCHUNK-1);
  int bh = blk / NCHUNK;
  int h = bh & 7, b = bh >> 3;
  int x = threadIdx.x;
  if (x < 72){ int a = x/9, j = x - a*9; wql[a][j] = qdw[h*72+x]; wkl[a][j] = kdw[h*72+x]; }
  __syncthreads();
  const float* qp = qpre + (((i64)((b<<6) + (h<<3)))<<16);
  const float* kp = kpre + (((i64)((b<<6) + (h<<3)))<<16);
  float dot[8][8], qn[8], kn[8];
  float q0[8], q1[8], k0[8], k1[8];
  #pragma unroll
  for (int a=0;a<8;a++){
    qn[a]=0.f; kn[a]=0.f; q0[a]=0.f; q1[a]=0.f; k0[a]=0.f; k1[a]=0.f;
    #pragma unroll
    for (int d=0;d<8;d++) dot[a][d]=0.f;
  }
  int y0 = chunk*16;
  bool xl = (x>0), xr = (x<255);
  for (int r = y0-1; r <= y0+16; r++){
    bool rok = ((unsigned)r < 256u);
    bool dostats = (r > y0);                 // finalizes output row r-1 in [y0, y0+15]
    float kv[8];
    #pragma unroll
    for (int a=0;a<8;a++){
      const float* rp = kp + ((i64)a<<16) + r*256;
      float vm = (rok&&xl)? rp[x-1]:0.f;
      float vc =  rok     ? rp[x]  :0.f;
      float vp = (rok&&xr)? rp[x+1]:0.f;
      float4 wA = *(const float4*)&wkl[a][0];
      float4 wB = *(const float4*)&wkl[a][4];
      float w8 = wkl[a][8];
      float t0 = wA.x*vm + wA.y*vc + wA.z*vp;
      float t1 = wA.w*vm + wB.x*vc + wB.y*vp;
      float t2 = wB.z*vm + wB.w*vc + w8*vp;
      kv[a] = k0[a] + t2;
      k0[a] = k1[a] + t1;
      k1[a] = t0;
    }
    #pragma unroll
    for (int a=0;a<8;a++){
      const float* rp = qp + ((i64)a<<16) + r*256;
      float vm = (rok&&xl)? rp[x-1]:0.f;
      float vc =  rok     ? rp[x]  :0.f;
      float vp = (rok&&xr)? rp[x+1]:0.f;
      float4 wA = *(const float4*)&wql[a][0];
      float4 wB = *(const float4*)&wql[a][4];
      float w8 = wql[a][8];
      float t0 = wA.x*vm + wA.y*vc + wA.z*vp;
      float t1 = wA.w*vm + wB.x*vc + wB.y*vp;
      float t2 = wB.z*vm + wB.w*vc + w8*vp;
      float qv = q0[a] + t2;
      q0[a] = q1[a] + t1;
      q1[a] = t0;
      if (dostats){
        qn[a] += qv*qv;
        #pragma unroll
        for (int d=0;d<8;d++) dot[a][d] += qv*kv[d];
      }
    }
    if (dostats){
      #pragma unroll
      for (int a=0;a<8;a++) kn[a] += kv[a]*kv[a];
    }
  }
  int lane = x & 63, wv = x >> 6;
  #pragma unroll
  for (int j=0;j<80;j++){
    float v;
    if (j<64) v = dot[j>>3][j&7];
    else if (j<72) v = qn[j-64];
    else v = kn[j-72];
    #pragma unroll
    for (int off=32; off; off>>=1) v += __shfl_down(v, off);
    if (lane==0) red[wv][j] = v;
  }
  __syncthreads();
  for (int j=x; j<80; j+=256)
    part[(i64)blk*80 + j] = red[0][j]+red[1][j]+red[2][j]+red[3][j];
}

__global__ __launch_bounds__(128) void k_stats_fin(const float* __restrict__ part, float* __restrict__ stats){
  int bh = blockIdx.x; int t = threadIdx.x;
  if (t < 80){
    float s=0.f;
    for (int c=0;c<NCHUNK;c++) s += part[((i64)bh*NCHUNK+c)*80 + t];
    stats[bh*80+t] = s;
  }
}

// ---------------- softmax + fold attn into per-batch 64x64 M ----------------
__global__ __launch_bounds__(64) void k_attn_m(const float* __restrict__ stats, const float* __restrict__ temp,
                         const float* __restrict__ projw, float* __restrict__ M){
  __shared__ float attn[8][8][8];
  int b = blockIdx.x; int t = threadIdx.x;
  int h = t >> 3, cc = t & 7;
  const float* st = stats + (b*8+h)*80;
  float nq = fmaxf(sqrtf(st[64+cc]), 1e-12f);
  float tmp = temp[h];
  float s[8];
  float mx = -1e30f;
  #pragma unroll
  for (int d=0;d<8;d++){
    float nk = fmaxf(sqrtf(st[72+d]), 1e-12f);
    s[d] = st[cc*8+d]/(nq*nk)*tmp;
    mx = fmaxf(mx, s[d]);
  }
  float sum=0.f;
  #pragma unroll
  for (int d=0;d<8;d++){ s[d]=expf(s[d]-mx); sum+=s[d]; }
  float inv = 1.0f/sum;
  #pragma unroll
  for (int d=0;d<8;d++) attn[h][cc][d] = s[d]*inv;
  __syncthreads();
  int o = t;
  for (int hh=0; hh<8; hh++){
    #pragma unroll
    for (int d=0; d<8; d++){
      float acc=0.f;
      #pragma unroll
      for (int c2=0;c2<8;c2++) acc += projw[o*64 + hh*8 + c2]*attn[hh][c2][d];
      M[((i64)b*64 + o)*64 + hh*8 + d] = acc;
    }
  }
}

// ---------------- depthwise 3x3 (v path): row-swept, 16 rows/thread-column ----------------
__global__ __launch_bounds__(256) void k_dw(const float* __restrict__ in, const float* __restrict__ wd,
                                            float* __restrict__ out){
  int blk = blockIdx.x;              // ((b*64+c)*16 + yt)
  int yt = blk & 15; int c = (blk>>4)&63; int b = blk>>10;
  int x = threadIdx.x;
  const float* ip = in + (((i64)((b<<6)+c))<<16);
  float* op = out + (((i64)((b<<6)+c))<<16);
  const float* wp = wd + c*9;
  int y0 = yt*16;
  float a0,a1,a2, b0,b1,b2;
  {
    int yy = y0-1;
    if ((unsigned)yy<256u){ const float* rp = ip + yy*256;
      a0 = (x>0)? rp[x-1]:0.f; a1 = rp[x]; a2 = (x<255)? rp[x+1]:0.f;
    } else { a0=a1=a2=0.f; }
    const float* rp = ip + y0*256;
    b0 = (x>0)? rp[x-1]:0.f; b1 = rp[x]; b2 = (x<255)? rp[x+1]:0.f;
  }
  for (int rr=0;rr<16;rr++){
    float d0,d1,d2;
    int yy = y0+rr+1;
    if ((unsigned)yy<256u){ const float* rp = ip + yy*256;
      d0 = (x>0)? rp[x-1]:0.f; d1 = rp[x]; d2 = (x<255)? rp[x+1]:0.f;
    } else { d0=d1=d2=0.f; }
    float acc = wp[0]*a0+wp[1]*a1+wp[2]*a2 + wp[3]*b0+wp[4]*b1+wp[5]*b2 + wp[6]*d0+wp[7]*d1+wp[8]*d2;
    op[(y0+rr)*256 + x] = acc;
    a0=b0;a1=b1;a2=b2; b0=d0;b1=d1;b2=d2;
  }
}

// ---------------- refine small kernels ----------------
__global__ __launch_bounds__(64) void k_spatfin(const float* __restrict__ spart, float* __restrict__ lmean, float* __restrict__ lmax){
  int b = blockIdx.x; int c = threadIdx.x;
  float s=0.f, m=-1e30f;
  for (int r=0;r<256;r++){
    s += spart[(i64)(b*256+r)*128 + c*2];
    m = fmaxf(m, spart[(i64)(b*256+r)*128 + c*2+1]);
  }
  lmean[b*64+c] = s*(1.0f/65536.0f);
  lmax[b*64+c]  = m;
}

__global__ __launch_bounds__(64) void k_cw(const float* __restrict__ mean, const float* __restrict__ mxv,
                     const float* __restrict__ w1, const float* __restrict__ w2, float* __restrict__ cw){
  __shared__ float ha[4], hm[4];
  int b = blockIdx.x; int t = threadIdx.x;
  if (t < 4){
    float sa=0.f, sm_=0.f;
    for (int c=0;c<64;c++){ sa += w1[t*64+c]*mean[b*64+c]; sm_ += w1[t*64+c]*mxv[b*64+c]; }
    ha[t] = fmaxf(sa, 0.f); hm[t] = fmaxf(sm_, 0.f);
  }
  __syncthreads();
  float a=0.f;
  #pragma unroll
  for (int j=0;j<4;j++) a += w2[t*4+j]*(ha[j]+hm[j]);
  cw[b*64+t] = sigm(a);
}

__global__ __launch_bounds__(256) void k_sw(const float* __restrict__ mx, const float* __restrict__ mn,
                     const float* __restrict__ w, float* __restrict__ sw){
  int row = blockIdx.x & 255; int b = blockIdx.x >> 8; int t = threadIdx.x;
  const float* m0 = mx + ((i64)b<<16);
  const float* m1 = mn + ((i64)b<<16);
  float acc=0.f;
  for (int ky=0;ky<7;ky++){
    int yy = row+ky-3; if ((unsigned)yy>255u) continue;
    for (int kx=0;kx<7;kx++){
      int xx = t+kx-3; if ((unsigned)xx>255u) continue;
      acc += w[ky*7+kx]*m0[yy*256+xx] + w[49+ky*7+kx]*m1[yy*256+xx];
    }
  }
  sw[((i64)b<<16) + row*256 + t] = sigm(acc);
}

// =====================================================================================
extern "C" void kernel_launch(void* const* d_in, const int* in_sizes, int n_in,
                              void* d_out, int out_size, void* d_ws, size_t ws_size,
                              hipStream_t stream){
  const float* x      = (const float*)d_in[0];
  const float* y      = (const float*)d_in[1];
  const float* conv1w = (const float*)d_in[2];
  const float* ratew1 = (const float*)d_in[3];
  const float* ratew2 = (const float*)d_in[4];
  const float* temp   = (const float*)d_in[5];
  const float* qw     = (const float*)d_in[6];
  const float* qdw    = (const float*)d_in[7];
  const float* kvw    = (const float*)d_in[8];
  const float* kvdw   = (const float*)d_in[9];
  const float* projw  = (const float*)d_in[10];
  const float* spw    = (const float*)d_in[11];
  const float* cgw1   = (const float*)d_in[12];
  const float* cgw2   = (const float*)d_in[13];
  const float* rprojw = (const float*)d_in[14];
  const float* rprojb = (const float*)d_in[15];
  const float* para1  = (const float*)d_in[16];
  const float* para2  = (const float*)d_in[17];
  float* D = (float*)d_out;

  // pick largest batch-group size whose footprint fits: 3 big units + pool
  int nb = 8;
  for (;;){
    size_t unit = (size_t)nb*64*HW_;
    size_t pool = (size_t)nb*3*HW_            // Rbuf
                + (size_t)nb*512 + (size_t)nb*64 + 64
                + (size_t)nb*8*NCHUNK*80      // part
                + (size_t)nb*8*80             // stats
                + (size_t)nb*64*64            // M
                + 3*(size_t)nb*HW_            // mxmap, mnmap, swb
                + (size_t)nb*256*128          // spart
                + 3*(size_t)nb*64;            // lmean, lmax, cwb
    if ((3*unit + pool)*sizeof(float) <= ws_size || nb==1) break;
    nb >>= 1;
  }

  size_t unit = (size_t)nb*64*HW_;
  float* U0 = (float*)d_ws;
  float* U1 = U0 + unit;
  float* U2 = U1 + unit;
  float* sm = U2 + unit;
  float* Rbuf  = sm;  sm += (size_t)nb*3*HW_;
  float* coeff = sm;  sm += (size_t)nb*512;
  float* pooled= sm;  sm += (size_t)nb*64;
  float* flagb = sm;  sm += 64;
  float* part  = sm;  sm += (size_t)nb*8*NCHUNK*80;
  float* stats = sm;  sm += (size_t)nb*8*80;
  float* Mb    = sm;  sm += (size_t)nb*64*64;
  float* mxmap = sm;  sm += (size_t)nb*HW_;
  float* mnmap = sm;  sm += (size_t)nb*HW_;
  float* swb   = sm;  sm += (size_t)nb*HW_;
  float* spart = sm;  sm += (size_t)nb*256*128;
  float* lmean = sm;  sm += (size_t)nb*64;
  float* lmax  = sm;  sm += (size_t)nb*64;
  float* cwb   = sm;  sm += (size_t)nb*64;

  for (int b0 = 0; b0 < 8; b0 += nb){
    const float* yg = y + (i64)b0*64*HW_;
    float*       Dg = D + (i64)b0*64*HW_;

    // frontend
    k_resize <<<nb*3*256, 256,0,stream>>>(x, Rbuf, b0);
    k_conv3  <<<nb*256,   256,0,stream>>>(Rbuf, conv1w, U0);           // xc = U0
    k_dft    <<<nb*64,    256,0,stream>>>(U0, coeff, pooled);
    k_thr    <<<nb,       64, 0,stream>>>(pooled, ratew1, ratew2, flagb);

    // cca0 (a = high, from xc)
    k_convq_fre<0><<<nb*128,256,0,stream>>>(U0, coeff, flagb, qw + 0*4096, U1);   // qpre=U1
    k_mm_kv  <<<nb*256,256,0,stream>>>(yg, kvw + 0*8192, U2, Dg);                 // kpre=U2, vpre=Dg
    k_statsdw <<<nb*8*NCHUNK,256,0,stream>>>(U1, U2, qdw + 0*576, kvdw + 0*1152, part);
    k_stats_fin<<<nb*8,  128,0,stream>>>(part, stats);
    k_dw      <<<nb*1024,256,0,stream>>>(Dg, kvdw + 0*1152 + 576, U1);            // v=U1
    k_attn_m  <<<nb,     64, 0,stream>>>(stats, temp + 0*8, projw + 0*4096, Mb);
    k_mm_hi  <<<nb*256, 256,0,stream>>>(U1, Mb, mxmap, mnmap, U2);                // high2=U2

    // cca1 (a = low, from xc)  [xc dead after this conv]
    k_convq_fre<1><<<nb*128,256,0,stream>>>(U0, coeff, flagb, qw + 1*4096, U1);   // qpre=U1
    k_mm_kv  <<<nb*256,256,0,stream>>>(yg, kvw + 1*8192, U0, Dg);                 // kpre=U0, vpre=Dg
    k_statsdw <<<nb*8*NCHUNK,256,0,stream>>>(U1, U0, qdw + 1*576, kvdw + 1*1152, part);
    k_stats_fin<<<nb*8,  128,0,stream>>>(part, stats);
    k_dw      <<<nb*1024,256,0,stream>>>(Dg, kvdw + 1*1152 + 576, U1);            // v=U1
    k_attn_m  <<<nb,     64, 0,stream>>>(stats, temp + 1*8, projw + 1*4096, Mb);
    k_mm_lo  <<<nb*256, 256,0,stream>>>(U1, Mb, Dg, spart);                       // low2=Dg

    // refine: high2=U2, low2=Dg -> agg=U0
    k_spatfin <<<nb,     64, 0,stream>>>(spart, lmean, lmax);
    k_cw      <<<nb,     64, 0,stream>>>(lmean, lmax, cgw1, cgw2, cwb);
    k_sw      <<<nb*256, 256,0,stream>>>(mxmap, mnmap, spw, swb);
    k_mm_comb<<<nb*256,256,0,stream>>>(Dg, U2, swb, cwb, rprojw, rprojb, U0);     // agg=U0

    // cca2 (q from y, kv from agg=U0)
    k_mm_64  <<<nb*256,256,0,stream>>>(yg, qw + 2*4096, U1);                      // qpre=U1
    k_mm_kv  <<<nb*256,256,0,stream>>>(U0, kvw + 2*8192, U2, Dg);                 // kpre=U2, vpre=Dg
    k_statsdw <<<nb*8*NCHUNK,256,0,stream>>>(U1, U2, qdw + 2*576, kvdw + 2*1152, part);
    k_stats_fin<<<nb*8,  128,0,stream>>>(part, stats);
    k_dw      <<<nb*1024,256,0,stream>>>(Dg, kvdw + 2*1152 + 576, U1);            // v=U1
    k_attn_m  <<<nb,     64, 0,stream>>>(stats, temp + 2*8, projw + 2*4096, Mb);
    k_mm_fin <<<nb*256,256,0,stream>>>(U1, Mb, para1, para2, yg, Dg);             // out
  }
}

// Round 3
// 2668.701 us; speedup vs baseline: 1.9816x; 1.9816x over previous
//
#include <hip/hip_runtime.h>
#include <math.h>

#define HW_ 65536
#define NCHUNK 16
typedef long long i64;
#define TWO_PI 6.283185307179586476925f

typedef __bf16 bf16x8 __attribute__((ext_vector_type(8)));
typedef float f32x4 __attribute__((ext_vector_type(4)));

#define MFMA16(A,B,C) __builtin_amdgcn_mfma_f32_16x16x32_bf16(A,B,C,0,0,0)

__device__ __forceinline__ float sigm(float x){ return 1.0f/(1.0f+expf(-x)); }

// convert 8 consecutive fp32 to a bf16x8 A-fragment
__device__ __forceinline__ bf16x8 cvt_w8(const float* wp){
  float4 w0 = *(const float4*)wp;
  float4 w1 = *(const float4*)(wp+4);
  bf16x8 r;
  r[0]=(__bf16)w0.x; r[1]=(__bf16)w0.y; r[2]=(__bf16)w0.z; r[3]=(__bf16)w0.w;
  r[4]=(__bf16)w1.x; r[5]=(__bf16)w1.y; r[6]=(__bf16)w1.z; r[7]=(__bf16)w1.w;
  return r;
}

// ---------------- resize (nb,3,128,128) -> (nb,3,256,256) bilinear half-pixel ----------------
__global__ __launch_bounds__(256) void k_resize(const float* __restrict__ x, float* __restrict__ R, int b0){
  int idx = blockIdx.x*256 + threadIdx.x;
  int ox = idx & 255;
  int oy = (idx >> 8) & 255;
  int bc = idx >> 16;                               // lb*3 + c
  int lb = bc/3; int c = bc - lb*3;
  float sx = ox*0.5f - 0.25f;
  float sy = oy*0.5f - 0.25f;
  int x0 = (int)floorf(sx); float fx = sx - (float)x0;
  int y0 = (int)floorf(sy); float fy = sy - (float)y0;
  int x1 = min(x0+1,127); int y1 = min(y0+1,127);
  x0 = max(x0,0); y0 = max(y0,0);
  const float* p = x + ((i64)(b0+lb)*3 + c)*16384;
  float v00=p[y0*128+x0], v01=p[y0*128+x1], v10=p[y1*128+x0], v11=p[y1*128+x1];
  R[idx] = (1.0f-fy)*((1.0f-fx)*v00 + fx*v01) + fy*((1.0f-fx)*v10 + fx*v11);
}

// ---------------- conv3x3 3->64: block per (b,row), all 64 outs per thread ----------------
__global__ __launch_bounds__(256) void k_conv3(const float* __restrict__ R, const float* __restrict__ w, float* __restrict__ out){
  int y = blockIdx.x & 255; int b = blockIdx.x >> 8; int t = threadIdx.x;
  float win[27];
  #pragma unroll
  for (int ci=0;ci<3;ci++){
    #pragma unroll
    for (int ky=0;ky<3;ky++){
      int yy = y+ky-1;
      const float* ip = R + (((i64)(b*3+ci))<<16) + yy*256;
      #pragma unroll
      for (int kx=0;kx<3;kx++){
        int xx = t+kx-1;
        float v = 0.f;
        if ((unsigned)yy<256u && (unsigned)xx<256u) v = ip[xx];
        win[ci*9+ky*3+kx] = v;
      }
    }
  }
  i64 obase = ((i64)b<<22) + (y<<8) + t;
  for (int o=0;o<64;o++){
    const float* wp = w + o*27;
    float acc=0.f;
    #pragma unroll
    for (int j=0;j<27;j++) acc += wp[j]*win[j];
    out[obase + ((i64)o<<16)] = acc;
  }
}

// ---------------- DFT coeffs (7 reals incl. DC) + pooled mean per (b,c) ----------------
__global__ __launch_bounds__(256) void k_dft(const float* __restrict__ xc, float* __restrict__ coeff, float* __restrict__ pooled){
  __shared__ float tc[256], ts[256];
  __shared__ float red[256];
  int t = threadIdx.x;
  float ang = TWO_PI * ((float)t/256.0f);
  tc[t] = cosf(ang); ts[t] = sinf(ang);
  __syncthreads();
  int bc = blockIdx.x;
  const float* p = xc + (i64)bc*HW_;
  float s=0, cr=0, ci=0, rr=0, ri=0, dr=0, di=0;
  for (int i=t; i<HW_; i+=256){
    float v = p[i];
    int col = i & 255, row = i >> 8, ds = (row+col)&255;
    s  += v;
    cr += v*tc[col]; ci += v*ts[col];
    rr += v*tc[row]; ri += v*ts[row];
    dr += v*tc[ds];  di += v*ts[ds];
  }
  float vals[7] = {s,cr,ci,rr,ri,dr,di};
  for (int j=0;j<7;j++){
    red[t] = vals[j]; __syncthreads();
    for (int st=128; st>0; st>>=1){ if (t<st) red[t]+=red[t+st]; __syncthreads(); }
    if (t==0) vals[j] = red[0];
    __syncthreads();
  }
  if (t==0){
    const float sc = 1.0f/65536.0f;
    for (int j=0;j<7;j++) coeff[bc*8+j] = vals[j]*sc;
    pooled[bc] = vals[0]*sc;
  }
}

// ---------------- threshold MLP -> per-batch mask flag ----------------
__global__ __launch_bounds__(64) void k_thr(const float* __restrict__ pooled, const float* __restrict__ w1,
                      const float* __restrict__ w2, float* __restrict__ flag){
  __shared__ float hid[8];
  int b = blockIdx.x; int t = threadIdx.x;
  if (t < 8){
    float a = 0.f;
    for (int c=0;c<64;c++) a += pooled[b*64+c]*w1[t*64+c];
    hid[t] = 0.5f*a*(1.0f+erff(a*0.70710678118654752440f));
  }
  __syncthreads();
  if (t==0){
    float t0=0,t1=0;
    for (int k=0;k<8;k++){ t0 += hid[k]*w2[k]; t1 += hid[k]*w2[8+k]; }
    int h_ = (int)(2.0f*sigm(t0));
    int w_ = (int)(2.0f*sigm(t1));
    flag[b] = (h_>0 && w_>0) ? 1.0f : 0.0f;
  }
}

// ---------------- fused: high/low reconstruction + conv1x1 (q path of cca0/cca1) ----------------
template<int WHICH>   // 0 = high, 1 = low
__global__ __launch_bounds__(256) void k_convq_fre(const float* __restrict__ xc, const float* __restrict__ coeff,
      const float* __restrict__ flag, const float* __restrict__ qw, float* __restrict__ out){
  __shared__ float tc[256], ts[256];
  int t = threadIdx.x;
  float ang = TWO_PI * ((float)t/256.0f);
  tc[t]=cosf(ang); ts[t]=sinf(ang);
  __syncthreads();
  int blk2 = blockIdx.x & 127; int b = blockIdx.x >> 7;
  int px0 = blk2*512 + 2*t;
  int x0 = px0 & 255; int y = px0 >> 8;
  float fl = flag[b];
  float crow = tc[y], srow = ts[y];
  int d0 = (x0 + y) & 255;
  int d1 = (x0 + 1 + y) & 255;
  float c0=tc[x0], s0=ts[x0], c1=tc[x0+1], s1=ts[x0+1];
  float cd0=tc[d0], sd0=ts[d0], cd1=tc[d1], sd1=ts[d1];
  i64 ibase = ((i64)b<<22) + px0;
  float2 xv[64];
  #pragma unroll
  for (int c=0;c<64;c++){
    const float* cf = coeff + ((b<<6)+c)*8;
    float F00=cf[0], cR=cf[1], cI=cf[2], rR=cf[3], rI=cf[4], dR=cf[5], dI=cf[6];
    float2 xr = *(const float2*)(xc + ibase + ((i64)c<<16));
    float re0 = F00 + cR*c0 + cI*s0 + rR*crow + rI*srow + dR*cd0 + dI*sd0;
    float im0 =       cI*c0 - cR*s0 + rI*crow - rR*srow + dI*cd0 - dR*sd0;
    float re1 = F00 + cR*c1 + cI*s1 + rR*crow + rI*srow + dR*cd1 + dI*sd1;
    float im1 =       cI*c1 - cR*s1 + rI*crow - rR*srow + dI*cd1 - dR*sd1;
    re0*=fl; im0*=fl; re1*=fl; im1*=fl;
    float v0, v1;
    if (WHICH==1){ v0 = sqrtf(re0*re0+im0*im0); v1 = sqrtf(re1*re1+im1*im1); }
    else { float h0=xr.x-re0, h1=xr.y-re1; v0 = sqrtf(h0*h0+im0*im0); v1 = sqrtf(h1*h1+im1*im1); }
    xv[c] = make_float2(v0,v1);
  }
  for (int o=0;o<64;o++){
    const float* wr = qw + o*64;
    float ax=0.f, ay=0.f;
    #pragma unroll
    for (int c=0;c<64;c++){ float wv=wr[c]; ax += xv[c].x*wv; ay += xv[c].y*wv; }
    *(float2*)(out + ibase + ((i64)o<<16)) = make_float2(ax,ay);
  }
}

// =====================================================================================
// MFMA pixel-matmul family: per wave, one 64px x 64out strip.
// A-frag (weights, row-major [O][64] fp32): lane holds row = m*16+(lane&15),
//   k = s*32 + (lane>>4)*8 + j  (8 consecutive fp32 -> bf16x8).
// B-frag (input planes [c][px]): col = lane&15 -> px = p0 + 4*(lane&15) + e (e=0..3 via
//   float4 components -> 4 parity fragments), k = s*32 + (lane>>4)*8 + j (per-plane loads).
// C/D: col(px)=lane&15, row(out)=(lane>>4)*4+reg  [verified m89 layout].
// =====================================================================================

// loads B for one strip: bq[s][j] float4 (4 px per lane); builds bf[s][e] frags
#define MM_LOAD_B(in_ptr) \
  float4 bq[2][8]; \
  _Pragma("unroll") \
  for (int s=0;s<2;s++){ \
    const float* bp = (in_ptr) + ((i64)(s*32 + kg*8)<<16) + 4*lm; \
    _Pragma("unroll") \
    for (int j=0;j<8;j++) bq[s][j] = *(const float4*)(bp + ((i64)j<<16)); \
  } \
  bf16x8 bf[2][4]; \
  _Pragma("unroll") \
  for (int s=0;s<2;s++){ \
    bf16x8 f0,f1,f2,f3; \
    _Pragma("unroll") \
    for (int j=0;j<8;j++){ \
      f0[j]=(__bf16)bq[s][j].x; f1[j]=(__bf16)bq[s][j].y; \
      f2[j]=(__bf16)bq[s][j].z; f3[j]=(__bf16)bq[s][j].w; \
    } \
    bf[s][0]=f0; bf[s][1]=f1; bf[s][2]=f2; bf[s][3]=f3; \
  }

#define MM_COMPUTE(Wbase) \
  bf16x8 af[4][2]; \
  _Pragma("unroll") \
  for (int m=0;m<4;m++){ \
    _Pragma("unroll") \
    for (int s=0;s<2;s++) af[m][s] = cvt_w8((Wbase) + (m*16 + lm)*64 + s*32 + kg*8); \
  } \
  f32x4 acc[4][4]; \
  _Pragma("unroll") \
  for (int m=0;m<4;m++){ \
    _Pragma("unroll") \
    for (int e=0;e<4;e++){ f32x4 z = {0.f,0.f,0.f,0.f}; acc[m][e]=z; } \
  } \
  _Pragma("unroll") \
  for (int m=0;m<4;m++){ \
    _Pragma("unroll") \
    for (int e=0;e<4;e++){ \
      _Pragma("unroll") \
      for (int s=0;s<2;s++) acc[m][e] = MFMA16(af[m][s], bf[s][e], acc[m][e]); \
    } \
  }

#define MM_SETUP \
  int t = threadIdx.x; \
  int lane = t & 63, wvi = t >> 6; \
  i64 px0 = (i64)blockIdx.x*256 + wvi*64; \
  int b = (int)(px0 >> 16); \
  int p0 = (int)(px0 & (HW_-1)); \
  i64 ibase = ((i64)b<<22) + p0; \
  int lm = lane & 15, kg = lane >> 4;

// ---------------- conv1x1 64->128 (k and v pre-tensors), MFMA ----------------
__global__ __launch_bounds__(256) void k_mm_kv(const float* __restrict__ in, const float* __restrict__ w,
      float* __restrict__ kout, float* __restrict__ vout){
  MM_SETUP
  MM_LOAD_B(in + ibase)
  #pragma unroll
  for (int half=0; half<2; half++){
    float* outp = half ? vout : kout;
    const float* Wb = w + half*4096;
    MM_COMPUTE(Wb)
    #pragma unroll
    for (int m=0;m<4;m++){
      #pragma unroll
      for (int r=0;r<4;r++){
        int oc = m*16 + kg*4 + r;
        float4 st = make_float4(acc[m][0][r], acc[m][1][r], acc[m][2][r], acc[m][3][r]);
        *(float4*)(outp + ibase + ((i64)oc<<16) + 4*lm) = st;
      }
    }
  }
}

// ---------------- plain conv1x1 64->64, MFMA ----------------
__global__ __launch_bounds__(256) void k_mm_64(const float* __restrict__ in, const float* __restrict__ w,
      float* __restrict__ out){
  MM_SETUP
  MM_LOAD_B(in + ibase)
  MM_COMPUTE(w)
  #pragma unroll
  for (int m=0;m<4;m++){
    #pragma unroll
    for (int r=0;r<4;r++){
      int oc = m*16 + kg*4 + r;
      float4 st = make_float4(acc[m][0][r], acc[m][1][r], acc[m][2][r], acc[m][3][r]);
      *(float4*)(out + ibase + ((i64)oc<<16) + 4*lm) = st;
    }
  }
}

// ---------------- mconv high: M x v + per-px channel max/mean, MFMA ----------------
__global__ __launch_bounds__(256) void k_mm_hi(const float* __restrict__ v, const float* __restrict__ M,
        float* __restrict__ mx, float* __restrict__ mn, float* __restrict__ out){
  MM_SETUP
  MM_LOAD_B(v + ibase)
  const float* Wb = M + ((i64)b<<12);
  MM_COMPUTE(Wb)
  float pmx[4] = {-1e30f,-1e30f,-1e30f,-1e30f};
  float ps[4]  = {0.f,0.f,0.f,0.f};
  #pragma unroll
  for (int m=0;m<4;m++){
    #pragma unroll
    for (int r=0;r<4;r++){
      int oc = m*16 + kg*4 + r;
      float4 st = make_float4(acc[m][0][r], acc[m][1][r], acc[m][2][r], acc[m][3][r]);
      *(float4*)(out + ibase + ((i64)oc<<16) + 4*lm) = st;
      pmx[0]=fmaxf(pmx[0],st.x); ps[0]+=st.x;
      pmx[1]=fmaxf(pmx[1],st.y); ps[1]+=st.y;
      pmx[2]=fmaxf(pmx[2],st.z); ps[2]+=st.z;
      pmx[3]=fmaxf(pmx[3],st.w); ps[3]+=st.w;
    }
  }
  // reduce across kg groups (lanes lm, lm+16, lm+32, lm+48) -> full 64-channel reduce
  #pragma unroll
  for (int e=0;e<4;e++){
    pmx[e] = fmaxf(pmx[e], __shfl_xor(pmx[e],16));
    pmx[e] = fmaxf(pmx[e], __shfl_xor(pmx[e],32));
    ps[e] += __shfl_xor(ps[e],16);
    ps[e] += __shfl_xor(ps[e],32);
  }
  if (kg==0){
    i64 pbase = ((i64)b<<16) + p0 + 4*lm;
    *(float4*)(mx+pbase) = make_float4(pmx[0],pmx[1],pmx[2],pmx[3]);
    *(float4*)(mn+pbase) = make_float4(ps[0]*(1.0f/64.0f),ps[1]*(1.0f/64.0f),
                                       ps[2]*(1.0f/64.0f),ps[3]*(1.0f/64.0f));
  }
}

// ---------------- mconv low: M x v + per-channel sum/max partials, MFMA ----------------
__global__ __launch_bounds__(256) void k_mm_lo(const float* __restrict__ v, const float* __restrict__ M,
        float* __restrict__ out, float* __restrict__ spart){
  __shared__ float ls[4][64], lmx[4][64];
  MM_SETUP
  MM_LOAD_B(v + ibase)
  const float* Wb = M + ((i64)b<<12);
  MM_COMPUTE(Wb)
  #pragma unroll
  for (int m=0;m<4;m++){
    #pragma unroll
    for (int r=0;r<4;r++){
      int oc = m*16 + kg*4 + r;
      float4 st = make_float4(acc[m][0][r], acc[m][1][r], acc[m][2][r], acc[m][3][r]);
      *(float4*)(out + ibase + ((i64)oc<<16) + 4*lm) = st;
      float s = st.x+st.y+st.z+st.w;
      float mm = fmaxf(fmaxf(st.x,st.y),fmaxf(st.z,st.w));
      // reduce across lm within the 16-lane kg group (pixel dim)
      #pragma unroll
      for (int off=8; off; off>>=1){ s += __shfl_xor(s,off); mm = fmaxf(mm,__shfl_xor(mm,off)); }
      if (lm==0){ ls[wvi][oc]=s; lmx[wvi][oc]=mm; }
    }
  }
  __syncthreads();
  if (t<64){
    float s = ls[0][t]+ls[1][t]+ls[2][t]+ls[3][t];
    float mm = fmaxf(fmaxf(lmx[0][t],lmx[1][t]),fmaxf(lmx[2][t],lmx[3][t]));
    spart[(i64)blockIdx.x*128 + t*2]   = s;
    spart[(i64)blockIdx.x*128 + t*2+1] = mm;
  }
}

// ---------------- fused comb + refine conv1x1, MFMA ----------------
__global__ __launch_bounds__(256) void k_mm_comb(const float* __restrict__ lo2, const float* __restrict__ hi2,
        const float* __restrict__ swb, const float* __restrict__ cwv,
        const float* __restrict__ w, const float* __restrict__ bias, float* __restrict__ out){
  MM_SETUP
  float4 sw4 = *(const float4*)(swb + ((i64)b<<16) + p0 + 4*lm);
  bf16x8 bf[2][4];
  #pragma unroll
  for (int s=0;s<2;s++){
    bf16x8 f0,f1,f2,f3;
    #pragma unroll
    for (int j=0;j<8;j++){
      int ch = s*32 + kg*8 + j;
      float4 l4 = *(const float4*)(lo2 + ibase + ((i64)ch<<16) + 4*lm);
      float4 h4 = *(const float4*)(hi2 + ibase + ((i64)ch<<16) + 4*lm);
      float cw = cwv[(b<<6) + ch];
      f0[j]=(__bf16)(l4.x*sw4.x + h4.x*cw);
      f1[j]=(__bf16)(l4.y*sw4.y + h4.y*cw);
      f2[j]=(__bf16)(l4.z*sw4.z + h4.z*cw);
      f3[j]=(__bf16)(l4.w*sw4.w + h4.w*cw);
    }
    bf[s][0]=f0; bf[s][1]=f1; bf[s][2]=f2; bf[s][3]=f3;
  }
  MM_COMPUTE(w)
  #pragma unroll
  for (int m=0;m<4;m++){
    #pragma unroll
    for (int r=0;r<4;r++){
      int oc = m*16 + kg*4 + r;
      float bv = bias[oc];
      float4 st = make_float4(acc[m][0][r]+bv, acc[m][1][r]+bv, acc[m][2][r]+bv, acc[m][3][r]+bv);
      *(float4*)(out + ibase + ((i64)oc<<16) + 4*lm) = st;
    }
  }
}

// ---------------- final mconv: M x v, *para1 + y*para2, MFMA ----------------
__global__ __launch_bounds__(256) void k_mm_fin(const float* __restrict__ v, const float* __restrict__ M,
      const float* __restrict__ para1, const float* __restrict__ para2,
      const float* __restrict__ yin, float* __restrict__ out){
  MM_SETUP
  MM_LOAD_B(v + ibase)
  const float* Wb = M + ((i64)b<<12);
  MM_COMPUTE(Wb)
  #pragma unroll
  for (int m=0;m<4;m++){
    #pragma unroll
    for (int r=0;r<4;r++){
      int oc = m*16 + kg*4 + r;
      float p1 = para1[oc], p2 = para2[oc];
      float4 yv = *(const float4*)(yin + ibase + ((i64)oc<<16) + 4*lm);
      float4 st = make_float4(acc[m][0][r]*p1 + yv.x*p2,
                              acc[m][1][r]*p1 + yv.y*p2,
                              acc[m][2][r]*p1 + yv.z*p2,
                              acc[m][3][r]*p1 + yv.w*p2);
      *(float4*)(out + ibase + ((i64)oc<<16) + 4*lm) = st;
    }
  }
}

// ---------------- fused dw3x3(q)+dw3x3(k)+stats, row-rolling: per (b,head,chunk16rows) ----------------
// Separable accumulation: input row r contributes w[0]-row to out r+1, w[1]-row to out r,
// w[2]-row to out r-1. Keep 2 pending partials per plane -> each input value loaded 3x (not 9x).
// NOTE: no min-waves hint! Live state is ~120 floats (dot[8][8]+norms+rolling partials);
// forcing 3 waves/EU capped VGPR at 84 and spilled ~3.4 GB/dispatch to scratch (R2 post-mortem).
__global__ __launch_bounds__(256) void k_statsdw(const float* __restrict__ qpre, const float* __restrict__ kpre,
        const float* __restrict__ qdw, const float* __restrict__ kdw, float* __restrict__ part){
  __shared__ float wql[8][12], wkl[8][12];   // padded to 12 for float4 reads
  __shared__ float red[4][80];
  int blk = blockIdx.x;
  int chunk = blk & (NCHUNK-1);
  int bh = blk / NCHUNK;
  int h = bh & 7, b = bh >> 3;
  int x = threadIdx.x;
  if (x < 72){ int a = x/9, j = x - a*9; wql[a][j] = qdw[h*72+x]; wkl[a][j] = kdw[h*72+x]; }
  __syncthreads();
  const float* qp = qpre + (((i64)((b<<6) + (h<<3)))<<16);
  const float* kp = kpre + (((i64)((b<<6) + (h<<3)))<<16);
  float dot[8][8], qn[8], kn[8];
  float q0[8], q1[8], k0[8], k1[8];
  #pragma unroll
  for (int a=0;a<8;a++){
    qn[a]=0.f; kn[a]=0.f; q0[a]=0.f; q1[a]=0.f; k0[a]=0.f; k1[a]=0.f;
    #pragma unroll
    for (int d=0;d<8;d++) dot[a][d]=0.f;
  }
  int y0 = chunk*16;
  bool xl = (x>0), xr = (x<255);
  for (int r = y0-1; r <= y0+16; r++){
    bool rok = ((unsigned)r < 256u);
    bool dostats = (r > y0);                 // finalizes output row r-1 in [y0, y0+15]
    float kv[8];
    #pragma unroll
    for (int a=0;a<8;a++){
      const float* rp = kp + ((i64)a<<16) + r*256;
      float vm = (rok&&xl)? rp[x-1]:0.f;
      float vc =  rok     ? rp[x]  :0.f;
      float vp = (rok&&xr)? rp[x+1]:0.f;
      float4 wA = *(const float4*)&wkl[a][0];
      float4 wB = *(const float4*)&wkl[a][4];
      float w8 = wkl[a][8];
      float t0 = wA.x*vm + wA.y*vc + wA.z*vp;
      float t1 = wA.w*vm + wB.x*vc + wB.y*vp;
      float t2 = wB.z*vm + wB.w*vc + w8*vp;
      kv[a] = k0[a] + t2;
      k0[a] = k1[a] + t1;
      k1[a] = t0;
    }
    #pragma unroll
    for (int a=0;a<8;a++){
      const float* rp = qp + ((i64)a<<16) + r*256;
      float vm = (rok&&xl)? rp[x-1]:0.f;
      float vc =  rok     ? rp[x]  :0.f;
      float vp = (rok&&xr)? rp[x+1]:0.f;
      float4 wA = *(const float4*)&wql[a][0];
      float4 wB = *(const float4*)&wql[a][4];
      float w8 = wql[a][8];
      float t0 = wA.x*vm + wA.y*vc + wA.z*vp;
      float t1 = wA.w*vm + wB.x*vc + wB.y*vp;
      float t2 = wB.z*vm + wB.w*vc + w8*vp;
      float qv = q0[a] + t2;
      q0[a] = q1[a] + t1;
      q1[a] = t0;
      if (dostats){
        qn[a] += qv*qv;
        #pragma unroll
        for (int d=0;d<8;d++) dot[a][d] += qv*kv[d];
      }
    }
    if (dostats){
      #pragma unroll
      for (int a=0;a<8;a++) kn[a] += kv[a]*kv[a];
    }
  }
  int lane = x & 63, wv = x >> 6;
  #pragma unroll
  for (int j=0;j<80;j++){
    float v;
    if (j<64) v = dot[j>>3][j&7];
    else if (j<72) v = qn[j-64];
    else v = kn[j-72];
    #pragma unroll
    for (int off=32; off; off>>=1) v += __shfl_down(v, off);
    if (lane==0) red[wv][j] = v;
  }
  __syncthreads();
  for (int j=x; j<80; j+=256)
    part[(i64)blk*80 + j] = red[0][j]+red[1][j]+red[2][j]+red[3][j];
}

__global__ __launch_bounds__(128) void k_stats_fin(const float* __restrict__ part, float* __restrict__ stats){
  int bh = blockIdx.x; int t = threadIdx.x;
  if (t < 80){
    float s=0.f;
    for (int c=0;c<NCHUNK;c++) s += part[((i64)bh*NCHUNK+c)*80 + t];
    stats[bh*80+t] = s;
  }
}

// ---------------- softmax + fold attn into per-batch 64x64 M ----------------
__global__ __launch_bounds__(64) void k_attn_m(const float* __restrict__ stats, const float* __restrict__ temp,
                         const float* __restrict__ projw, float* __restrict__ M){
  __shared__ float attn[8][8][8];
  int b = blockIdx.x; int t = threadIdx.x;
  int h = t >> 3, cc = t & 7;
  const float* st = stats + (b*8+h)*80;
  float nq = fmaxf(sqrtf(st[64+cc]), 1e-12f);
  float tmp = temp[h];
  float s[8];
  float mx = -1e30f;
  #pragma unroll
  for (int d=0;d<8;d++){
    float nk = fmaxf(sqrtf(st[72+d]), 1e-12f);
    s[d] = st[cc*8+d]/(nq*nk)*tmp;
    mx = fmaxf(mx, s[d]);
  }
  float sum=0.f;
  #pragma unroll
  for (int d=0;d<8;d++){ s[d]=expf(s[d]-mx); sum+=s[d]; }
  float inv = 1.0f/sum;
  #pragma unroll
  for (int d=0;d<8;d++) attn[h][cc][d] = s[d]*inv;
  __syncthreads();
  int o = t;
  for (int hh=0; hh<8; hh++){
    #pragma unroll
    for (int d=0; d<8; d++){
      float acc=0.f;
      #pragma unroll
      for (int c2=0;c2<8;c2++) acc += projw[o*64 + hh*8 + c2]*attn[hh][c2][d];
      M[((i64)b*64 + o)*64 + hh*8 + d] = acc;
    }
  }
}

// ---------------- depthwise 3x3 (v path): row-swept, 16 rows/thread-column ----------------
__global__ __launch_bounds__(256) void k_dw(const float* __restrict__ in, const float* __restrict__ wd,
                                            float* __restrict__ out){
  int blk = blockIdx.x;              // ((b*64+c)*16 + yt)
  int yt = blk & 15; int c = (blk>>4)&63; int b = blk>>10;
  int x = threadIdx.x;
  const float* ip = in + (((i64)((b<<6)+c))<<16);
  float* op = out + (((i64)((b<<6)+c))<<16);
  const float* wp = wd + c*9;
  int y0 = yt*16;
  float a0,a1,a2, b0,b1,b2;
  {
    int yy = y0-1;
    if ((unsigned)yy<256u){ const float* rp = ip + yy*256;
      a0 = (x>0)? rp[x-1]:0.f; a1 = rp[x]; a2 = (x<255)? rp[x+1]:0.f;
    } else { a0=a1=a2=0.f; }
    const float* rp = ip + y0*256;
    b0 = (x>0)? rp[x-1]:0.f; b1 = rp[x]; b2 = (x<255)? rp[x+1]:0.f;
  }
  for (int rr=0;rr<16;rr++){
    float d0,d1,d2;
    int yy = y0+rr+1;
    if ((unsigned)yy<256u){ const float* rp = ip + yy*256;
      d0 = (x>0)? rp[x-1]:0.f; d1 = rp[x]; d2 = (x<255)? rp[x+1]:0.f;
    } else { d0=d1=d2=0.f; }
    float acc = wp[0]*a0+wp[1]*a1+wp[2]*a2 + wp[3]*b0+wp[4]*b1+wp[5]*b2 + wp[6]*d0+wp[7]*d1+wp[8]*d2;
    op[(y0+rr)*256 + x] = acc;
    a0=b0;a1=b1;a2=b2; b0=d0;b1=d1;b2=d2;
  }
}

// ---------------- refine small kernels ----------------
__global__ __launch_bounds__(64) void k_spatfin(const float* __restrict__ spart, float* __restrict__ lmean, float* __restrict__ lmax){
  int b = blockIdx.x; int c = threadIdx.x;
  float s=0.f, m=-1e30f;
  for (int r=0;r<256;r++){
    s += spart[(i64)(b*256+r)*128 + c*2];
    m = fmaxf(m, spart[(i64)(b*256+r)*128 + c*2+1]);
  }
  lmean[b*64+c] = s*(1.0f/65536.0f);
  lmax[b*64+c]  = m;
}

__global__ __launch_bounds__(64) void k_cw(const float* __restrict__ mean, const float* __restrict__ mxv,
                     const float* __restrict__ w1, const float* __restrict__ w2, float* __restrict__ cw){
  __shared__ float ha[4], hm[4];
  int b = blockIdx.x; int t = threadIdx.x;
  if (t < 4){
    float sa=0.f, sm_=0.f;
    for (int c=0;c<64;c++){ sa += w1[t*64+c]*mean[b*64+c]; sm_ += w1[t*64+c]*mxv[b*64+c]; }
    ha[t] = fmaxf(sa, 0.f); hm[t] = fmaxf(sm_, 0.f);
  }
  __syncthreads();
  float a=0.f;
  #pragma unroll
  for (int j=0;j<4;j++) a += w2[t*4+j]*(ha[j]+hm[j]);
  cw[b*64+t] = sigm(a);
}

__global__ __launch_bounds__(256) void k_sw(const float* __restrict__ mx, const float* __restrict__ mn,
                     const float* __restrict__ w, float* __restrict__ sw){
  int row = blockIdx.x & 255; int b = blockIdx.x >> 8; int t = threadIdx.x;
  const float* m0 = mx + ((i64)b<<16);
  const float* m1 = mn + ((i64)b<<16);
  float acc=0.f;
  for (int ky=0;ky<7;ky++){
    int yy = row+ky-3; if ((unsigned)yy>255u) continue;
    for (int kx=0;kx<7;kx++){
      int xx = t+kx-3; if ((unsigned)xx>255u) continue;
      acc += w[ky*7+kx]*m0[yy*256+xx] + w[49+ky*7+kx]*m1[yy*256+xx];
    }
  }
  sw[((i64)b<<16) + row*256 + t] = sigm(acc);
}

// =====================================================================================
extern "C" void kernel_launch(void* const* d_in, const int* in_sizes, int n_in,
                              void* d_out, int out_size, void* d_ws, size_t ws_size,
                              hipStream_t stream){
  const float* x      = (const float*)d_in[0];
  const float* y      = (const float*)d_in[1];
  const float* conv1w = (const float*)d_in[2];
  const float* ratew1 = (const float*)d_in[3];
  const float* ratew2 = (const float*)d_in[4];
  const float* temp   = (const float*)d_in[5];
  const float* qw     = (const float*)d_in[6];
  const float* qdw    = (const float*)d_in[7];
  const float* kvw    = (const float*)d_in[8];
  const float* kvdw   = (const float*)d_in[9];
  const float* projw  = (const float*)d_in[10];
  const float* spw    = (const float*)d_in[11];
  const float* cgw1   = (const float*)d_in[12];
  const float* cgw2   = (const float*)d_in[13];
  const float* rprojw = (const float*)d_in[14];
  const float* rprojb = (const float*)d_in[15];
  const float* para1  = (const float*)d_in[16];
  const float* para2  = (const float*)d_in[17];
  float* D = (float*)d_out;

  // pick largest batch-group size whose footprint fits: 3 big units + pool
  int nb = 8;
  for (;;){
    size_t unit = (size_t)nb*64*HW_;
    size_t pool = (size_t)nb*3*HW_            // Rbuf
                + (size_t)nb*512 + (size_t)nb*64 + 64
                + (size_t)nb*8*NCHUNK*80      // part
                + (size_t)nb*8*80             // stats
                + (size_t)nb*64*64            // M
                + 3*(size_t)nb*HW_            // mxmap, mnmap, swb
                + (size_t)nb*256*128          // spart
                + 3*(size_t)nb*64;            // lmean, lmax, cwb
    if ((3*unit + pool)*sizeof(float) <= ws_size || nb==1) break;
    nb >>= 1;
  }

  size_t unit = (size_t)nb*64*HW_;
  float* U0 = (float*)d_ws;
  float* U1 = U0 + unit;
  float* U2 = U1 + unit;
  float* sm = U2 + unit;
  float* Rbuf  = sm;  sm += (size_t)nb*3*HW_;
  float* coeff = sm;  sm += (size_t)nb*512;
  float* pooled= sm;  sm += (size_t)nb*64;
  float* flagb = sm;  sm += 64;
  float* part  = sm;  sm += (size_t)nb*8*NCHUNK*80;
  float* stats = sm;  sm += (size_t)nb*8*80;
  float* Mb    = sm;  sm += (size_t)nb*64*64;
  float* mxmap = sm;  sm += (size_t)nb*HW_;
  float* mnmap = sm;  sm += (size_t)nb*HW_;
  float* swb   = sm;  sm += (size_t)nb*HW_;
  float* spart = sm;  sm += (size_t)nb*256*128;
  float* lmean = sm;  sm += (size_t)nb*64;
  float* lmax  = sm;  sm += (size_t)nb*64;
  float* cwb   = sm;  sm += (size_t)nb*64;

  for (int b0 = 0; b0 < 8; b0 += nb){
    const float* yg = y + (i64)b0*64*HW_;
    float*       Dg = D + (i64)b0*64*HW_;

    // frontend
    k_resize <<<nb*3*256, 256,0,stream>>>(x, Rbuf, b0);
    k_conv3  <<<nb*256,   256,0,stream>>>(Rbuf, conv1w, U0);           // xc = U0
    k_dft    <<<nb*64,    256,0,stream>>>(U0, coeff, pooled);
    k_thr    <<<nb,       64, 0,stream>>>(pooled, ratew1, ratew2, flagb);

    // cca0 (a = high, from xc)
    k_convq_fre<0><<<nb*128,256,0,stream>>>(U0, coeff, flagb, qw + 0*4096, U1);   // qpre=U1
    k_mm_kv  <<<nb*256,256,0,stream>>>(yg, kvw + 0*8192, U2, Dg);                 // kpre=U2, vpre=Dg
    k_statsdw <<<nb*8*NCHUNK,256,0,stream>>>(U1, U2, qdw + 0*576, kvdw + 0*1152, part);
    k_stats_fin<<<nb*8,  128,0,stream>>>(part, stats);
    k_dw      <<<nb*1024,256,0,stream>>>(Dg, kvdw + 0*1152 + 576, U1);            // v=U1
    k_attn_m  <<<nb,     64, 0,stream>>>(stats, temp + 0*8, projw + 0*4096, Mb);
    k_mm_hi  <<<nb*256, 256,0,stream>>>(U1, Mb, mxmap, mnmap, U2);                // high2=U2

    // cca1 (a = low, from xc)  [xc dead after this conv]
    k_convq_fre<1><<<nb*128,256,0,stream>>>(U0, coeff, flagb, qw + 1*4096, U1);   // qpre=U1
    k_mm_kv  <<<nb*256,256,0,stream>>>(yg, kvw + 1*8192, U0, Dg);                 // kpre=U0, vpre=Dg
    k_statsdw <<<nb*8*NCHUNK,256,0,stream>>>(U1, U0, qdw + 1*576, kvdw + 1*1152, part);
    k_stats_fin<<<nb*8,  128,0,stream>>>(part, stats);
    k_dw      <<<nb*1024,256,0,stream>>>(Dg, kvdw + 1*1152 + 576, U1);            // v=U1
    k_attn_m  <<<nb,     64, 0,stream>>>(stats, temp + 1*8, projw + 1*4096, Mb);
    k_mm_lo  <<<nb*256, 256,0,stream>>>(U1, Mb, Dg, spart);                       // low2=Dg

    // refine: high2=U2, low2=Dg -> agg=U0
    k_spatfin <<<nb,     64, 0,stream>>>(spart, lmean, lmax);
    k_cw      <<<nb,     64, 0,stream>>>(lmean, lmax, cgw1, cgw2, cwb);
    k_sw      <<<nb*256, 256,0,stream>>>(mxmap, mnmap, spw, swb);
    k_mm_comb<<<nb*256,256,0,stream>>>(Dg, U2, swb, cwb, rprojw, rprojb, U0);     // agg=U0

    // cca2 (q from y, kv from agg=U0)
    k_mm_64  <<<nb*256,256,0,stream>>>(yg, qw + 2*4096, U1);                      // qpre=U1
    k_mm_kv  <<<nb*256,256,0,stream>>>(U0, kvw + 2*8192, U2, Dg);                 // kpre=U2, vpre=Dg
    k_statsdw <<<nb*8*NCHUNK,256,0,stream>>>(U1, U2, qdw + 2*576, kvdw + 2*1152, part);
    k_stats_fin<<<nb*8,  128,0,stream>>>(part, stats);
    k_dw      <<<nb*1024,256,0,stream>>>(Dg, kvdw + 2*1152 + 576, U1);            // v=U1
    k_attn_m  <<<nb,     64, 0,stream>>>(stats, temp + 2*8, projw + 2*4096, Mb);
    k_mm_fin <<<nb*256,256,0,stream>>>(U1, Mb, para1, para2, yg, Dg);             // out
  }
}

// Round 4
// 2002.866 us; speedup vs baseline: 2.6404x; 1.3324x over previous
//
#include <hip/hip_runtime.h>
#include <math.h>

#define HW_ 65536
#define NCHUNK 16
typedef long long i64;
#define TWO_PI 6.283185307179586476925f

typedef __bf16 bf16x8 __attribute__((ext_vector_type(8)));
typedef float f32x4 __attribute__((ext_vector_type(4)));

#define MFMA16(A,B,C) __builtin_amdgcn_mfma_f32_16x16x32_bf16(A,B,C,0,0,0)

__device__ __forceinline__ float sigm(float x){ return 1.0f/(1.0f+expf(-x)); }

// convert 8 consecutive fp32 to a bf16x8 A-fragment
__device__ __forceinline__ bf16x8 cvt_w8(const float* wp){
  float4 w0 = *(const float4*)wp;
  float4 w1 = *(const float4*)(wp+4);
  bf16x8 r;
  r[0]=(__bf16)w0.x; r[1]=(__bf16)w0.y; r[2]=(__bf16)w0.z; r[3]=(__bf16)w0.w;
  r[4]=(__bf16)w1.x; r[5]=(__bf16)w1.y; r[6]=(__bf16)w1.z; r[7]=(__bf16)w1.w;
  return r;
}

// ---------------- resize (nb,3,128,128) -> (nb,3,256,256) bilinear half-pixel ----------------
__global__ __launch_bounds__(256) void k_resize(const float* __restrict__ x, float* __restrict__ R, int b0){
  int idx = blockIdx.x*256 + threadIdx.x;
  int ox = idx & 255;
  int oy = (idx >> 8) & 255;
  int bc = idx >> 16;                               // lb*3 + c
  int lb = bc/3; int c = bc - lb*3;
  float sx = ox*0.5f - 0.25f;
  float sy = oy*0.5f - 0.25f;
  int x0 = (int)floorf(sx); float fx = sx - (float)x0;
  int y0 = (int)floorf(sy); float fy = sy - (float)y0;
  int x1 = min(x0+1,127); int y1 = min(y0+1,127);
  x0 = max(x0,0); y0 = max(y0,0);
  const float* p = x + ((i64)(b0+lb)*3 + c)*16384;
  float v00=p[y0*128+x0], v01=p[y0*128+x1], v10=p[y1*128+x0], v11=p[y1*128+x1];
  R[idx] = (1.0f-fy)*((1.0f-fx)*v00 + fx*v01) + fy*((1.0f-fx)*v10 + fx*v11);
}

// ---------------- conv3x3 3->64: block per (b,row), all 64 outs per thread ----------------
__global__ __launch_bounds__(256) void k_conv3(const float* __restrict__ R, const float* __restrict__ w, float* __restrict__ out){
  int y = blockIdx.x & 255; int b = blockIdx.x >> 8; int t = threadIdx.x;
  float win[27];
  #pragma unroll
  for (int ci=0;ci<3;ci++){
    #pragma unroll
    for (int ky=0;ky<3;ky++){
      int yy = y+ky-1;
      const float* ip = R + (((i64)(b*3+ci))<<16) + yy*256;
      #pragma unroll
      for (int kx=0;kx<3;kx++){
        int xx = t+kx-1;
        float v = 0.f;
        if ((unsigned)yy<256u && (unsigned)xx<256u) v = ip[xx];
        win[ci*9+ky*3+kx] = v;
      }
    }
  }
  i64 obase = ((i64)b<<22) + (y<<8) + t;
  for (int o=0;o<64;o++){
    const float* wp = w + o*27;
    float acc=0.f;
    #pragma unroll
    for (int j=0;j<27;j++) acc += wp[j]*win[j];
    out[obase + ((i64)o<<16)] = acc;
  }
}

// ---------------- DFT coeffs (7 reals incl. DC) + pooled mean per (b,c) ----------------
__global__ __launch_bounds__(256) void k_dft(const float* __restrict__ xc, float* __restrict__ coeff, float* __restrict__ pooled){
  __shared__ float tc[256], ts[256];
  __shared__ float red[256];
  int t = threadIdx.x;
  float ang = TWO_PI * ((float)t/256.0f);
  tc[t] = cosf(ang); ts[t] = sinf(ang);
  __syncthreads();
  int bc = blockIdx.x;
  const float* p = xc + (i64)bc*HW_;
  float s=0, cr=0, ci=0, rr=0, ri=0, dr=0, di=0;
  for (int i=t; i<HW_; i+=256){
    float v = p[i];
    int col = i & 255, row = i >> 8, ds = (row+col)&255;
    s  += v;
    cr += v*tc[col]; ci += v*ts[col];
    rr += v*tc[row]; ri += v*ts[row];
    dr += v*tc[ds];  di += v*ts[ds];
  }
  float vals[7] = {s,cr,ci,rr,ri,dr,di};
  for (int j=0;j<7;j++){
    red[t] = vals[j]; __syncthreads();
    for (int st=128; st>0; st>>=1){ if (t<st) red[t]+=red[t+st]; __syncthreads(); }
    if (t==0) vals[j] = red[0];
    __syncthreads();
  }
  if (t==0){
    const float sc = 1.0f/65536.0f;
    for (int j=0;j<7;j++) coeff[bc*8+j] = vals[j]*sc;
    pooled[bc] = vals[0]*sc;
  }
}

// ---------------- threshold MLP -> per-batch mask flag ----------------
__global__ __launch_bounds__(64) void k_thr(const float* __restrict__ pooled, const float* __restrict__ w1,
                      const float* __restrict__ w2, float* __restrict__ flag){
  __shared__ float hid[8];
  int b = blockIdx.x; int t = threadIdx.x;
  if (t < 8){
    float a = 0.f;
    for (int c=0;c<64;c++) a += pooled[b*64+c]*w1[t*64+c];
    hid[t] = 0.5f*a*(1.0f+erff(a*0.70710678118654752440f));
  }
  __syncthreads();
  if (t==0){
    float t0=0,t1=0;
    for (int k=0;k<8;k++){ t0 += hid[k]*w2[k]; t1 += hid[k]*w2[8+k]; }
    int h_ = (int)(2.0f*sigm(t0));
    int w_ = (int)(2.0f*sigm(t1));
    flag[b] = (h_>0 && w_>0) ? 1.0f : 0.0f;
  }
}

// =====================================================================================
// MFMA pixel-matmul family: per wave, one 64px x 64out strip.
// A-frag (weights, row-major [O][64] fp32): lane holds row = m*16+(lane&15),
//   k = s*32 + (lane>>4)*8 + j  (8 consecutive fp32 -> bf16x8).
// B-frag (input planes [c][px]): col = lane&15 -> px = p0 + 4*(lane&15) + e (e=0..3 via
//   float4 components -> 4 parity fragments), k = s*32 + (lane>>4)*8 + j (per-plane loads).
// C/D: col(px)=lane&15, row(out)=(lane>>4)*4+reg  [verified m89 layout].
// =====================================================================================

// loads B for one strip: bq[s][j] float4 (4 px per lane); builds bf[s][e] frags
#define MM_LOAD_B(in_ptr) \
  float4 bq[2][8]; \
  _Pragma("unroll") \
  for (int s=0;s<2;s++){ \
    const float* bp = (in_ptr) + ((i64)(s*32 + kg*8)<<16) + 4*lm; \
    _Pragma("unroll") \
    for (int j=0;j<8;j++) bq[s][j] = *(const float4*)(bp + ((i64)j<<16)); \
  } \
  bf16x8 bf[2][4]; \
  _Pragma("unroll") \
  for (int s=0;s<2;s++){ \
    bf16x8 f0,f1,f2,f3; \
    _Pragma("unroll") \
    for (int j=0;j<8;j++){ \
      f0[j]=(__bf16)bq[s][j].x; f1[j]=(__bf16)bq[s][j].y; \
      f2[j]=(__bf16)bq[s][j].z; f3[j]=(__bf16)bq[s][j].w; \
    } \
    bf[s][0]=f0; bf[s][1]=f1; bf[s][2]=f2; bf[s][3]=f3; \
  }

#define MM_COMPUTE(Wbase) \
  bf16x8 af[4][2]; \
  _Pragma("unroll") \
  for (int m=0;m<4;m++){ \
    _Pragma("unroll") \
    for (int s=0;s<2;s++) af[m][s] = cvt_w8((Wbase) + (m*16 + lm)*64 + s*32 + kg*8); \
  } \
  f32x4 acc[4][4]; \
  _Pragma("unroll") \
  for (int m=0;m<4;m++){ \
    _Pragma("unroll") \
    for (int e=0;e<4;e++){ f32x4 z = {0.f,0.f,0.f,0.f}; acc[m][e]=z; } \
  } \
  _Pragma("unroll") \
  for (int m=0;m<4;m++){ \
    _Pragma("unroll") \
    for (int e=0;e<4;e++){ \
      _Pragma("unroll") \
      for (int s=0;s<2;s++) acc[m][e] = MFMA16(af[m][s], bf[s][e], acc[m][e]); \
    } \
  }

#define MM_SETUP \
  int t = threadIdx.x; \
  int lane = t & 63, wvi = t >> 6; \
  i64 px0 = (i64)blockIdx.x*256 + wvi*64; \
  int b = (int)(px0 >> 16); \
  int p0 = (int)(px0 & (HW_-1)); \
  i64 ibase = ((i64)b<<22) + p0; \
  int lm = lane & 15, kg = lane >> 4;

// ---------------- fused: high/low DFT recon + conv1x1, MFMA ----------------
// Each lane computes its own B-fragment elements (8 ch x 4 px) pointwise -> no transpose.
template<int WHICH>   // 0 = high, 1 = low
__global__ __launch_bounds__(256) void k_mm_convq(const float* __restrict__ xc, const float* __restrict__ coeff,
      const float* __restrict__ flag, const float* __restrict__ qw, float* __restrict__ out){
  MM_SETUP
  float fl = flag[b];
  int y = p0 >> 8;
  int xb = (p0 & 255) + 4*lm;
  float angr = TWO_PI * ((float)y/256.0f);
  float crow = cosf(angr), srow = sinf(angr);
  float cx[4], sx[4], cd[4], sd[4];
  #pragma unroll
  for (int e=0;e<4;e++){
    int xx = xb + e;
    float a1 = TWO_PI * ((float)xx/256.0f);
    cx[e]=cosf(a1); sx[e]=sinf(a1);
    int d = (xx + y) & 255;
    float a2 = TWO_PI * ((float)d/256.0f);
    cd[e]=cosf(a2); sd[e]=sinf(a2);
  }
  bf16x8 bf[2][4];
  #pragma unroll
  for (int s=0;s<2;s++){
    bf16x8 f0,f1,f2,f3;
    #pragma unroll
    for (int j=0;j<8;j++){
      int ch = s*32 + kg*8 + j;
      const float* cf = coeff + ((b<<6)+ch)*8;
      float4 ca = *(const float4*)cf;
      float4 cb = *(const float4*)(cf+4);
      float F00=ca.x, cR=ca.y, cI=ca.z, rR=ca.w, rI=cb.x, dR=cb.y, dI=cb.z;
      float4 xr;
      if (WHICH==0) xr = *(const float4*)(xc + ibase + ((i64)ch<<16) + 4*lm);
      float vv[4];
      #pragma unroll
      for (int e=0;e<4;e++){
        float re = F00 + cR*cx[e] + cI*sx[e] + rR*crow + rI*srow + dR*cd[e] + dI*sd[e];
        float im =       cI*cx[e] - cR*sx[e] + rI*crow - rR*srow + dI*cd[e] - dR*sd[e];
        re*=fl; im*=fl;
        if (WHICH==1){ vv[e] = sqrtf(re*re+im*im); }
        else { float hr = ((WHICH==0)?((const float*)&xr)[e]:0.f) - re; vv[e] = sqrtf(hr*hr + im*im); }
      }
      f0[j]=(__bf16)vv[0]; f1[j]=(__bf16)vv[1]; f2[j]=(__bf16)vv[2]; f3[j]=(__bf16)vv[3];
    }
    bf[s][0]=f0; bf[s][1]=f1; bf[s][2]=f2; bf[s][3]=f3;
  }
  MM_COMPUTE(qw)
  #pragma unroll
  for (int m=0;m<4;m++){
    #pragma unroll
    for (int r=0;r<4;r++){
      int oc = m*16 + kg*4 + r;
      float4 st = make_float4(acc[m][0][r], acc[m][1][r], acc[m][2][r], acc[m][3][r]);
      *(float4*)(out + ibase + ((i64)oc<<16) + 4*lm) = st;
    }
  }
}

// ---------------- conv1x1 64->128 (k and v pre-tensors), MFMA ----------------
__global__ __launch_bounds__(256) void k_mm_kv(const float* __restrict__ in, const float* __restrict__ w,
      float* __restrict__ kout, float* __restrict__ vout){
  MM_SETUP
  MM_LOAD_B(in + ibase)
  #pragma unroll
  for (int half=0; half<2; half++){
    float* outp = half ? vout : kout;
    const float* Wb = w + half*4096;
    MM_COMPUTE(Wb)
    #pragma unroll
    for (int m=0;m<4;m++){
      #pragma unroll
      for (int r=0;r<4;r++){
        int oc = m*16 + kg*4 + r;
        float4 st = make_float4(acc[m][0][r], acc[m][1][r], acc[m][2][r], acc[m][3][r]);
        *(float4*)(outp + ibase + ((i64)oc<<16) + 4*lm) = st;
      }
    }
  }
}

// ---------------- plain conv1x1 64->64, MFMA ----------------
__global__ __launch_bounds__(256) void k_mm_64(const float* __restrict__ in, const float* __restrict__ w,
      float* __restrict__ out){
  MM_SETUP
  MM_LOAD_B(in + ibase)
  MM_COMPUTE(w)
  #pragma unroll
  for (int m=0;m<4;m++){
    #pragma unroll
    for (int r=0;r<4;r++){
      int oc = m*16 + kg*4 + r;
      float4 st = make_float4(acc[m][0][r], acc[m][1][r], acc[m][2][r], acc[m][3][r]);
      *(float4*)(out + ibase + ((i64)oc<<16) + 4*lm) = st;
    }
  }
}

// ---------------- mconv high: M x v + per-px channel max/mean, MFMA ----------------
__global__ __launch_bounds__(256) void k_mm_hi(const float* __restrict__ v, const float* __restrict__ M,
        float* __restrict__ mx, float* __restrict__ mn, float* __restrict__ out){
  MM_SETUP
  MM_LOAD_B(v + ibase)
  const float* Wb = M + ((i64)b<<12);
  MM_COMPUTE(Wb)
  float pmx[4] = {-1e30f,-1e30f,-1e30f,-1e30f};
  float ps[4]  = {0.f,0.f,0.f,0.f};
  #pragma unroll
  for (int m=0;m<4;m++){
    #pragma unroll
    for (int r=0;r<4;r++){
      int oc = m*16 + kg*4 + r;
      float4 st = make_float4(acc[m][0][r], acc[m][1][r], acc[m][2][r], acc[m][3][r]);
      *(float4*)(out + ibase + ((i64)oc<<16) + 4*lm) = st;
      pmx[0]=fmaxf(pmx[0],st.x); ps[0]+=st.x;
      pmx[1]=fmaxf(pmx[1],st.y); ps[1]+=st.y;
      pmx[2]=fmaxf(pmx[2],st.z); ps[2]+=st.z;
      pmx[3]=fmaxf(pmx[3],st.w); ps[3]+=st.w;
    }
  }
  // reduce across kg groups (lanes lm, lm+16, lm+32, lm+48) -> full 64-channel reduce
  #pragma unroll
  for (int e=0;e<4;e++){
    pmx[e] = fmaxf(pmx[e], __shfl_xor(pmx[e],16));
    pmx[e] = fmaxf(pmx[e], __shfl_xor(pmx[e],32));
    ps[e] += __shfl_xor(ps[e],16);
    ps[e] += __shfl_xor(ps[e],32);
  }
  if (kg==0){
    i64 pbase = ((i64)b<<16) + p0 + 4*lm;
    *(float4*)(mx+pbase) = make_float4(pmx[0],pmx[1],pmx[2],pmx[3]);
    *(float4*)(mn+pbase) = make_float4(ps[0]*(1.0f/64.0f),ps[1]*(1.0f/64.0f),
                                       ps[2]*(1.0f/64.0f),ps[3]*(1.0f/64.0f));
  }
}

// ---------------- mconv low: M x v + per-channel sum/max partials, MFMA ----------------
__global__ __launch_bounds__(256) void k_mm_lo(const float* __restrict__ v, const float* __restrict__ M,
        float* __restrict__ out, float* __restrict__ spart){
  __shared__ float ls[4][64], lmx[4][64];
  MM_SETUP
  MM_LOAD_B(v + ibase)
  const float* Wb = M + ((i64)b<<12);
  MM_COMPUTE(Wb)
  #pragma unroll
  for (int m=0;m<4;m++){
    #pragma unroll
    for (int r=0;r<4;r++){
      int oc = m*16 + kg*4 + r;
      float4 st = make_float4(acc[m][0][r], acc[m][1][r], acc[m][2][r], acc[m][3][r]);
      *(float4*)(out + ibase + ((i64)oc<<16) + 4*lm) = st;
      float s = st.x+st.y+st.z+st.w;
      float mm = fmaxf(fmaxf(st.x,st.y),fmaxf(st.z,st.w));
      // reduce across lm within the 16-lane kg group (pixel dim)
      #pragma unroll
      for (int off=8; off; off>>=1){ s += __shfl_xor(s,off); mm = fmaxf(mm,__shfl_xor(mm,off)); }
      if (lm==0){ ls[wvi][oc]=s; lmx[wvi][oc]=mm; }
    }
  }
  __syncthreads();
  if (t<64){
    float s = ls[0][t]+ls[1][t]+ls[2][t]+ls[3][t];
    float mm = fmaxf(fmaxf(lmx[0][t],lmx[1][t]),fmaxf(lmx[2][t],lmx[3][t]));
    spart[(i64)blockIdx.x*128 + t*2]   = s;
    spart[(i64)blockIdx.x*128 + t*2+1] = mm;
  }
}

// ---------------- fused comb + refine conv1x1, MFMA ----------------
__global__ __launch_bounds__(256) void k_mm_comb(const float* __restrict__ lo2, const float* __restrict__ hi2,
        const float* __restrict__ swb, const float* __restrict__ cwv,
        const float* __restrict__ w, const float* __restrict__ bias, float* __restrict__ out){
  MM_SETUP
  float4 sw4 = *(const float4*)(swb + ((i64)b<<16) + p0 + 4*lm);
  bf16x8 bf[2][4];
  #pragma unroll
  for (int s=0;s<2;s++){
    bf16x8 f0,f1,f2,f3;
    #pragma unroll
    for (int j=0;j<8;j++){
      int ch = s*32 + kg*8 + j;
      float4 l4 = *(const float4*)(lo2 + ibase + ((i64)ch<<16) + 4*lm);
      float4 h4 = *(const float4*)(hi2 + ibase + ((i64)ch<<16) + 4*lm);
      float cw = cwv[(b<<6) + ch];
      f0[j]=(__bf16)(l4.x*sw4.x + h4.x*cw);
      f1[j]=(__bf16)(l4.y*sw4.y + h4.y*cw);
      f2[j]=(__bf16)(l4.z*sw4.z + h4.z*cw);
      f3[j]=(__bf16)(l4.w*sw4.w + h4.w*cw);
    }
    bf[s][0]=f0; bf[s][1]=f1; bf[s][2]=f2; bf[s][3]=f3;
  }
  MM_COMPUTE(w)
  #pragma unroll
  for (int m=0;m<4;m++){
    #pragma unroll
    for (int r=0;r<4;r++){
      int oc = m*16 + kg*4 + r;
      float bv = bias[oc];
      float4 st = make_float4(acc[m][0][r]+bv, acc[m][1][r]+bv, acc[m][2][r]+bv, acc[m][3][r]+bv);
      *(float4*)(out + ibase + ((i64)oc<<16) + 4*lm) = st;
    }
  }
}

// ---------------- final mconv: M x v, *para1 + y*para2, MFMA ----------------
__global__ __launch_bounds__(256) void k_mm_fin(const float* __restrict__ v, const float* __restrict__ M,
      const float* __restrict__ para1, const float* __restrict__ para2,
      const float* __restrict__ yin, float* __restrict__ out){
  MM_SETUP
  MM_LOAD_B(v + ibase)
  const float* Wb = M + ((i64)b<<12);
  MM_COMPUTE(Wb)
  #pragma unroll
  for (int m=0;m<4;m++){
    #pragma unroll
    for (int r=0;r<4;r++){
      int oc = m*16 + kg*4 + r;
      float p1 = para1[oc], p2 = para2[oc];
      float4 yv = *(const float4*)(yin + ibase + ((i64)oc<<16) + 4*lm);
      float4 st = make_float4(acc[m][0][r]*p1 + yv.x*p2,
                              acc[m][1][r]*p1 + yv.y*p2,
                              acc[m][2][r]*p1 + yv.z*p2,
                              acc[m][3][r]*p1 + yv.w*p2);
      *(float4*)(out + ibase + ((i64)oc<<16) + 4*lm) = st;
    }
  }
}

// ---------------- fused dw3x3(q)+dw3x3(k)+stats, k-split: per (b,head,chunk16rows,dg) ----------------
// Each block handles 2 of 8 k-channels (dg in 0..3): per-thread state drops to
// dot[8][2]+rolling -> ~100 VGPR -> 4-5 waves/SIMD (R3 was dot[8][8] @172 VGPR, 2 waves).
// q-conv recomputed x4 across dg-blocks (L2-resident). Disjoint part-slots per dg.
__global__ __launch_bounds__(256) void k_statsdw(const float* __restrict__ qpre, const float* __restrict__ kpre,
        const float* __restrict__ qdw, const float* __restrict__ kdw, float* __restrict__ part){
  __shared__ float wql[8][12], wkl[2][12];   // padded to 12 for float4 reads
  __shared__ float red[4][26];
  int blk = blockIdx.x;                      // (bc * 4 + dg), bc = bh*NCHUNK+chunk
  int dg = blk & 3;
  int bc = blk >> 2;
  int chunk = bc & (NCHUNK-1);
  int bh = bc / NCHUNK;
  int h = bh & 7, b = bh >> 3;
  int x = threadIdx.x;
  if (x < 72){ int a = x/9, j = x - a*9; wql[a][j] = qdw[h*72+x]; }
  if (x < 18){ int a = x/9, j = x - a*9; wkl[a][j] = kdw[h*72 + (dg*2+a)*9 + j]; }
  __syncthreads();
  const float* qp = qpre + (((i64)((b<<6) + (h<<3)))<<16);
  const float* kp = kpre + (((i64)((b<<6) + (h<<3) + dg*2))<<16);
  const bool doqn = (dg==0);
  float dot[8][2], qn[8], kn[2];
  float q0[8], q1[8], k0[2], k1[2];
  #pragma unroll
  for (int a=0;a<8;a++){ qn[a]=0.f; q0[a]=0.f; q1[a]=0.f; dot[a][0]=0.f; dot[a][1]=0.f; }
  kn[0]=kn[1]=0.f; k0[0]=k0[1]=0.f; k1[0]=k1[1]=0.f;
  int y0 = chunk*16;
  bool xl = (x>0), xr = (x<255);
  for (int r = y0-1; r <= y0+16; r++){
    bool rok = ((unsigned)r < 256u);
    bool dostats = (r > y0);                 // finalizes output row r-1 in [y0, y0+15]
    float kv[2];
    #pragma unroll
    for (int a=0;a<2;a++){
      const float* rp = kp + ((i64)a<<16) + r*256;
      float vm = (rok&&xl)? rp[x-1]:0.f;
      float vc =  rok     ? rp[x]  :0.f;
      float vp = (rok&&xr)? rp[x+1]:0.f;
      float4 wA = *(const float4*)&wkl[a][0];
      float4 wB = *(const float4*)&wkl[a][4];
      float w8 = wkl[a][8];
      float t0 = wA.x*vm + wA.y*vc + wA.z*vp;
      float t1 = wA.w*vm + wB.x*vc + wB.y*vp;
      float t2 = wB.z*vm + wB.w*vc + w8*vp;
      kv[a] = k0[a] + t2;
      k0[a] = k1[a] + t1;
      k1[a] = t0;
    }
    #pragma unroll
    for (int a=0;a<8;a++){
      const float* rp = qp + ((i64)a<<16) + r*256;
      float vm = (rok&&xl)? rp[x-1]:0.f;
      float vc =  rok     ? rp[x]  :0.f;
      float vp = (rok&&xr)? rp[x+1]:0.f;
      float4 wA = *(const float4*)&wql[a][0];
      float4 wB = *(const float4*)&wql[a][4];
      float w8 = wql[a][8];
      float t0 = wA.x*vm + wA.y*vc + wA.z*vp;
      float t1 = wA.w*vm + wB.x*vc + wB.y*vp;
      float t2 = wB.z*vm + wB.w*vc + w8*vp;
      float qv = q0[a] + t2;
      q0[a] = q1[a] + t1;
      q1[a] = t0;
      if (dostats){
        if (doqn) qn[a] += qv*qv;
        dot[a][0] += qv*kv[0];
        dot[a][1] += qv*kv[1];
      }
    }
    if (dostats){ kn[0] += kv[0]*kv[0]; kn[1] += kv[1]*kv[1]; }
  }
  int lane = x & 63, wv = x >> 6;
  #pragma unroll
  for (int j=0;j<26;j++){
    float v;
    if (j<16) v = dot[j>>1][j&1];
    else if (j<18) v = kn[j-16];
    else v = qn[j-18];
    #pragma unroll
    for (int off=32; off; off>>=1) v += __shfl_down(v, off);
    if (lane==0) red[wv][j] = v;
  }
  __syncthreads();
  if (x < 26 && (x < 18 || dg==0)){
    float s = red[0][x]+red[1][x]+red[2][x]+red[3][x];
    int slot;
    if (x < 16)      slot = (x>>1)*8 + dg*2 + (x&1);
    else if (x < 18) slot = 72 + dg*2 + (x-16);
    else             slot = 64 + (x-18);
    part[(i64)bc*80 + slot] = s;
  }
}

__global__ __launch_bounds__(128) void k_stats_fin(const float* __restrict__ part, float* __restrict__ stats){
  int bh = blockIdx.x; int t = threadIdx.x;
  if (t < 80){
    float s=0.f;
    for (int c=0;c<NCHUNK;c++) s += part[((i64)bh*NCHUNK+c)*80 + t];
    stats[bh*80+t] = s;
  }
}

// ---------------- softmax + fold attn into per-batch 64x64 M ----------------
__global__ __launch_bounds__(64) void k_attn_m(const float* __restrict__ stats, const float* __restrict__ temp,
                         const float* __restrict__ projw, float* __restrict__ M){
  __shared__ float attn[8][8][8];
  int b = blockIdx.x; int t = threadIdx.x;
  int h = t >> 3, cc = t & 7;
  const float* st = stats + (b*8+h)*80;
  float nq = fmaxf(sqrtf(st[64+cc]), 1e-12f);
  float tmp = temp[h];
  float s[8];
  float mx = -1e30f;
  #pragma unroll
  for (int d=0;d<8;d++){
    float nk = fmaxf(sqrtf(st[72+d]), 1e-12f);
    s[d] = st[cc*8+d]/(nq*nk)*tmp;
    mx = fmaxf(mx, s[d]);
  }
  float sum=0.f;
  #pragma unroll
  for (int d=0;d<8;d++){ s[d]=expf(s[d]-mx); sum+=s[d]; }
  float inv = 1.0f/sum;
  #pragma unroll
  for (int d=0;d<8;d++) attn[h][cc][d] = s[d]*inv;
  __syncthreads();
  int o = t;
  for (int hh=0; hh<8; hh++){
    #pragma unroll
    for (int d=0; d<8; d++){
      float acc=0.f;
      #pragma unroll
      for (int c2=0;c2<8;c2++) acc += projw[o*64 + hh*8 + c2]*attn[hh][c2][d];
      M[((i64)b*64 + o)*64 + hh*8 + d] = acc;
    }
  }
}

// ---------------- depthwise 3x3 (v path): row-swept, 16 rows/thread-column ----------------
__global__ __launch_bounds__(256) void k_dw(const float* __restrict__ in, const float* __restrict__ wd,
                                            float* __restrict__ out){
  int blk = blockIdx.x;              // ((b*64+c)*16 + yt)
  int yt = blk & 15; int c = (blk>>4)&63; int b = blk>>10;
  int x = threadIdx.x;
  const float* ip = in + (((i64)((b<<6)+c))<<16);
  float* op = out + (((i64)((b<<6)+c))<<16);
  const float* wp = wd + c*9;
  int y0 = yt*16;
  float a0,a1,a2, b0,b1,b2;
  {
    int yy = y0-1;
    if ((unsigned)yy<256u){ const float* rp = ip + yy*256;
      a0 = (x>0)? rp[x-1]:0.f; a1 = rp[x]; a2 = (x<255)? rp[x+1]:0.f;
    } else { a0=a1=a2=0.f; }
    const float* rp = ip + y0*256;
    b0 = (x>0)? rp[x-1]:0.f; b1 = rp[x]; b2 = (x<255)? rp[x+1]:0.f;
  }
  for (int rr=0;rr<16;rr++){
    float d0,d1,d2;
    int yy = y0+rr+1;
    if ((unsigned)yy<256u){ const float* rp = ip + yy*256;
      d0 = (x>0)? rp[x-1]:0.f; d1 = rp[x]; d2 = (x<255)? rp[x+1]:0.f;
    } else { d0=d1=d2=0.f; }
    float acc = wp[0]*a0+wp[1]*a1+wp[2]*a2 + wp[3]*b0+wp[4]*b1+wp[5]*b2 + wp[6]*d0+wp[7]*d1+wp[8]*d2;
    op[(y0+rr)*256 + x] = acc;
    a0=b0;a1=b1;a2=b2; b0=d0;b1=d1;b2=d2;
  }
}

// ---------------- refine small kernels ----------------
__global__ __launch_bounds__(64) void k_spatfin(const float* __restrict__ spart, float* __restrict__ lmean, float* __restrict__ lmax){
  int b = blockIdx.x; int c = threadIdx.x;
  float s=0.f, m=-1e30f;
  for (int r=0;r<256;r++){
    s += spart[(i64)(b*256+r)*128 + c*2];
    m = fmaxf(m, spart[(i64)(b*256+r)*128 + c*2+1]);
  }
  lmean[b*64+c] = s*(1.0f/65536.0f);
  lmax[b*64+c]  = m;
}

__global__ __launch_bounds__(64) void k_cw(const float* __restrict__ mean, const float* __restrict__ mxv,
                     const float* __restrict__ w1, const float* __restrict__ w2, float* __restrict__ cw){
  __shared__ float ha[4], hm[4];
  int b = blockIdx.x; int t = threadIdx.x;
  if (t < 4){
    float sa=0.f, sm_=0.f;
    for (int c=0;c<64;c++){ sa += w1[t*64+c]*mean[b*64+c]; sm_ += w1[t*64+c]*mxv[b*64+c]; }
    ha[t] = fmaxf(sa, 0.f); hm[t] = fmaxf(sm_, 0.f);
  }
  __syncthreads();
  float a=0.f;
  #pragma unroll
  for (int j=0;j<4;j++) a += w2[t*4+j]*(ha[j]+hm[j]);
  cw[b*64+t] = sigm(a);
}

__global__ __launch_bounds__(256) void k_sw(const float* __restrict__ mx, const float* __restrict__ mn,
                     const float* __restrict__ w, float* __restrict__ sw){
  int row = blockIdx.x & 255; int b = blockIdx.x >> 8; int t = threadIdx.x;
  const float* m0 = mx + ((i64)b<<16);
  const float* m1 = mn + ((i64)b<<16);
  float acc=0.f;
  for (int ky=0;ky<7;ky++){
    int yy = row+ky-3; if ((unsigned)yy>255u) continue;
    for (int kx=0;kx<7;kx++){
      int xx = t+kx-3; if ((unsigned)xx>255u) continue;
      acc += w[ky*7+kx]*m0[yy*256+xx] + w[49+ky*7+kx]*m1[yy*256+xx];
    }
  }
  sw[((i64)b<<16) + row*256 + t] = sigm(acc);
}

// =====================================================================================
extern "C" void kernel_launch(void* const* d_in, const int* in_sizes, int n_in,
                              void* d_out, int out_size, void* d_ws, size_t ws_size,
                              hipStream_t stream){
  const float* x      = (const float*)d_in[0];
  const float* y      = (const float*)d_in[1];
  const float* conv1w = (const float*)d_in[2];
  const float* ratew1 = (const float*)d_in[3];
  const float* ratew2 = (const float*)d_in[4];
  const float* temp   = (const float*)d_in[5];
  const float* qw     = (const float*)d_in[6];
  const float* qdw    = (const float*)d_in[7];
  const float* kvw    = (const float*)d_in[8];
  const float* kvdw   = (const float*)d_in[9];
  const float* projw  = (const float*)d_in[10];
  const float* spw    = (const float*)d_in[11];
  const float* cgw1   = (const float*)d_in[12];
  const float* cgw2   = (const float*)d_in[13];
  const float* rprojw = (const float*)d_in[14];
  const float* rprojb = (const float*)d_in[15];
  const float* para1  = (const float*)d_in[16];
  const float* para2  = (const float*)d_in[17];
  float* D = (float*)d_out;

  // pick largest batch-group size whose footprint fits: 3 big units + pool
  int nb = 8;
  for (;;){
    size_t unit = (size_t)nb*64*HW_;
    size_t pool = (size_t)nb*3*HW_            // Rbuf
                + (size_t)nb*512 + (size_t)nb*64 + 64
                + (size_t)nb*8*NCHUNK*80      // part
                + (size_t)nb*8*80             // stats
                + (size_t)nb*64*64            // M
                + 3*(size_t)nb*HW_            // mxmap, mnmap, swb
                + (size_t)nb*256*128          // spart
                + 3*(size_t)nb*64;            // lmean, lmax, cwb
    if ((3*unit + pool)*sizeof(float) <= ws_size || nb==1) break;
    nb >>= 1;
  }

  size_t unit = (size_t)nb*64*HW_;
  float* U0 = (float*)d_ws;
  float* U1 = U0 + unit;
  float* U2 = U1 + unit;
  float* sm = U2 + unit;
  float* Rbuf  = sm;  sm += (size_t)nb*3*HW_;
  float* coeff = sm;  sm += (size_t)nb*512;
  float* pooled= sm;  sm += (size_t)nb*64;
  float* flagb = sm;  sm += 64;
  float* part  = sm;  sm += (size_t)nb*8*NCHUNK*80;
  float* stats = sm;  sm += (size_t)nb*8*80;
  float* Mb    = sm;  sm += (size_t)nb*64*64;
  float* mxmap = sm;  sm += (size_t)nb*HW_;
  float* mnmap = sm;  sm += (size_t)nb*HW_;
  float* swb   = sm;  sm += (size_t)nb*HW_;
  float* spart = sm;  sm += (size_t)nb*256*128;
  float* lmean = sm;  sm += (size_t)nb*64;
  float* lmax  = sm;  sm += (size_t)nb*64;
  float* cwb   = sm;  sm += (size_t)nb*64;

  for (int b0 = 0; b0 < 8; b0 += nb){
    const float* yg = y + (i64)b0*64*HW_;
    float*       Dg = D + (i64)b0*64*HW_;

    // frontend
    k_resize <<<nb*3*256, 256,0,stream>>>(x, Rbuf, b0);
    k_conv3  <<<nb*256,   256,0,stream>>>(Rbuf, conv1w, U0);           // xc = U0
    k_dft    <<<nb*64,    256,0,stream>>>(U0, coeff, pooled);
    k_thr    <<<nb,       64, 0,stream>>>(pooled, ratew1, ratew2, flagb);

    // cca0 (a = high, from xc)
    k_mm_convq<0><<<nb*256,256,0,stream>>>(U0, coeff, flagb, qw + 0*4096, U1);    // qpre=U1
    k_mm_kv  <<<nb*256,256,0,stream>>>(yg, kvw + 0*8192, U2, Dg);                 // kpre=U2, vpre=Dg
    k_statsdw <<<nb*8*NCHUNK*4,256,0,stream>>>(U1, U2, qdw + 0*576, kvdw + 0*1152, part);
    k_stats_fin<<<nb*8,  128,0,stream>>>(part, stats);
    k_dw      <<<nb*1024,256,0,stream>>>(Dg, kvdw + 0*1152 + 576, U1);            // v=U1
    k_attn_m  <<<nb,     64, 0,stream>>>(stats, temp + 0*8, projw + 0*4096, Mb);
    k_mm_hi  <<<nb*256, 256,0,stream>>>(U1, Mb, mxmap, mnmap, U2);                // high2=U2

    // cca1 (a = low, from xc)  [xc dead after this conv]
    k_mm_convq<1><<<nb*256,256,0,stream>>>(U0, coeff, flagb, qw + 1*4096, U1);    // qpre=U1
    k_mm_kv  <<<nb*256,256,0,stream>>>(yg, kvw + 1*8192, U0, Dg);                 // kpre=U0, vpre=Dg
    k_statsdw <<<nb*8*NCHUNK*4,256,0,stream>>>(U1, U0, qdw + 1*576, kvdw + 1*1152, part);
    k_stats_fin<<<nb*8,  128,0,stream>>>(part, stats);
    k_dw      <<<nb*1024,256,0,stream>>>(Dg, kvdw + 1*1152 + 576, U1);            // v=U1
    k_attn_m  <<<nb,     64, 0,stream>>>(stats, temp + 1*8, projw + 1*4096, Mb);
    k_mm_lo  <<<nb*256, 256,0,stream>>>(U1, Mb, Dg, spart);                       // low2=Dg

    // refine: high2=U2, low2=Dg -> agg=U0
    k_spatfin <<<nb,     64, 0,stream>>>(spart, lmean, lmax);
    k_cw      <<<nb,     64, 0,stream>>>(lmean, lmax, cgw1, cgw2, cwb);
    k_sw      <<<nb*256, 256,0,stream>>>(mxmap, mnmap, spw, swb);
    k_mm_comb<<<nb*256,256,0,stream>>>(Dg, U2, swb, cwb, rprojw, rprojb, U0);     // agg=U0

    // cca2 (q from y, kv from agg=U0)
    k_mm_64  <<<nb*256,256,0,stream>>>(yg, qw + 2*4096, U1);                      // qpre=U1
    k_mm_kv  <<<nb*256,256,0,stream>>>(U0, kvw + 2*8192, U2, Dg);                 // kpre=U2, vpre=Dg
    k_statsdw <<<nb*8*NCHUNK*4,256,0,stream>>>(U1, U2, qdw + 2*576, kvdw + 2*1152, part);
    k_stats_fin<<<nb*8,  128,0,stream>>>(part, stats);
    k_dw      <<<nb*1024,256,0,stream>>>(Dg, kvdw + 2*1152 + 576, U1);            // v=U1
    k_attn_m  <<<nb,     64, 0,stream>>>(stats, temp + 2*8, projw + 2*4096, Mb);
    k_mm_fin <<<nb*256,256,0,stream>>>(U1, Mb, para1, para2, yg, Dg);             // out
  }
}

// Round 5
// 1510.638 us; speedup vs baseline: 3.5008x; 1.3258x over previous
//
#include <hip/hip_runtime.h>
#include <math.h>

#define HW_ 65536
#define NCHUNK 16
typedef long long i64;
#define TWO_PI 6.283185307179586476925f

typedef __bf16 bf16x8 __attribute__((ext_vector_type(8)));
typedef float f32x4 __attribute__((ext_vector_type(4)));

#define MFMA16(A,B,C) __builtin_amdgcn_mfma_f32_16x16x32_bf16(A,B,C,0,0,0)

__device__ __forceinline__ float sigm(float x){ return 1.0f/(1.0f+expf(-x)); }

// convert 8 consecutive fp32 to a bf16x8 A-fragment
__device__ __forceinline__ bf16x8 cvt_w8(const float* wp){
  float4 w0 = *(const float4*)wp;
  float4 w1 = *(const float4*)(wp+4);
  bf16x8 r;
  r[0]=(__bf16)w0.x; r[1]=(__bf16)w0.y; r[2]=(__bf16)w0.z; r[3]=(__bf16)w0.w;
  r[4]=(__bf16)w1.x; r[5]=(__bf16)w1.y; r[6]=(__bf16)w1.z; r[7]=(__bf16)w1.w;
  return r;
}

// ---------------- resize (nb,3,128,128) -> (nb,3,256,256) bilinear half-pixel ----------------
__global__ __launch_bounds__(256) void k_resize(const float* __restrict__ x, float* __restrict__ R, int b0){
  int idx = blockIdx.x*256 + threadIdx.x;
  int ox = idx & 255;
  int oy = (idx >> 8) & 255;
  int bc = idx >> 16;                               // lb*3 + c
  int lb = bc/3; int c = bc - lb*3;
  float sx = ox*0.5f - 0.25f;
  float sy = oy*0.5f - 0.25f;
  int x0 = (int)floorf(sx); float fx = sx - (float)x0;
  int y0 = (int)floorf(sy); float fy = sy - (float)y0;
  int x1 = min(x0+1,127); int y1 = min(y0+1,127);
  x0 = max(x0,0); y0 = max(y0,0);
  const float* p = x + ((i64)(b0+lb)*3 + c)*16384;
  float v00=p[y0*128+x0], v01=p[y0*128+x1], v10=p[y1*128+x0], v11=p[y1*128+x1];
  R[idx] = (1.0f-fy)*((1.0f-fx)*v00 + fx*v01) + fy*((1.0f-fx)*v10 + fx*v11);
}

// ---------------- conv3x3 3->64: block per (b,row), all 64 outs per thread ----------------
__global__ __launch_bounds__(256) void k_conv3(const float* __restrict__ R, const float* __restrict__ w, float* __restrict__ out){
  int y = blockIdx.x & 255; int b = blockIdx.x >> 8; int t = threadIdx.x;
  float win[27];
  #pragma unroll
  for (int ci=0;ci<3;ci++){
    #pragma unroll
    for (int ky=0;ky<3;ky++){
      int yy = y+ky-1;
      const float* ip = R + (((i64)(b*3+ci))<<16) + yy*256;
      #pragma unroll
      for (int kx=0;kx<3;kx++){
        int xx = t+kx-1;
        float v = 0.f;
        if ((unsigned)yy<256u && (unsigned)xx<256u) v = ip[xx];
        win[ci*9+ky*3+kx] = v;
      }
    }
  }
  i64 obase = ((i64)b<<22) + (y<<8) + t;
  for (int o=0;o<64;o++){
    const float* wp = w + o*27;
    float acc=0.f;
    #pragma unroll
    for (int j=0;j<27;j++) acc += wp[j]*win[j];
    out[obase + ((i64)o<<16)] = acc;
  }
}

// ---------------- DFT coeffs (7 reals incl. DC) + pooled mean per (b,c) ----------------
__global__ __launch_bounds__(256) void k_dft(const float* __restrict__ xc, float* __restrict__ coeff, float* __restrict__ pooled){
  __shared__ float tc[256], ts[256];
  __shared__ float red[256];
  int t = threadIdx.x;
  float ang = TWO_PI * ((float)t/256.0f);
  tc[t] = cosf(ang); ts[t] = sinf(ang);
  __syncthreads();
  int bc = blockIdx.x;
  const float* p = xc + (i64)bc*HW_;
  float s=0, cr=0, ci=0, rr=0, ri=0, dr=0, di=0;
  for (int i=t; i<HW_; i+=256){
    float v = p[i];
    int col = i & 255, row = i >> 8, ds = (row+col)&255;
    s  += v;
    cr += v*tc[col]; ci += v*ts[col];
    rr += v*tc[row]; ri += v*ts[row];
    dr += v*tc[ds];  di += v*ts[ds];
  }
  float vals[7] = {s,cr,ci,rr,ri,dr,di};
  for (int j=0;j<7;j++){
    red[t] = vals[j]; __syncthreads();
    for (int st=128; st>0; st>>=1){ if (t<st) red[t]+=red[t+st]; __syncthreads(); }
    if (t==0) vals[j] = red[0];
    __syncthreads();
  }
  if (t==0){
    const float sc = 1.0f/65536.0f;
    for (int j=0;j<7;j++) coeff[bc*8+j] = vals[j]*sc;
    pooled[bc] = vals[0]*sc;
  }
}

// ---------------- threshold MLP -> per-batch mask flag ----------------
__global__ __launch_bounds__(64) void k_thr(const float* __restrict__ pooled, const float* __restrict__ w1,
                      const float* __restrict__ w2, float* __restrict__ flag){
  __shared__ float hid[8];
  int b = blockIdx.x; int t = threadIdx.x;
  if (t < 8){
    float a = 0.f;
    for (int c=0;c<64;c++) a += pooled[b*64+c]*w1[t*64+c];
    hid[t] = 0.5f*a*(1.0f+erff(a*0.70710678118654752440f));
  }
  __syncthreads();
  if (t==0){
    float t0=0,t1=0;
    for (int k=0;k<8;k++){ t0 += hid[k]*w2[k]; t1 += hid[k]*w2[8+k]; }
    int h_ = (int)(2.0f*sigm(t0));
    int w_ = (int)(2.0f*sigm(t1));
    flag[b] = (h_>0 && w_>0) ? 1.0f : 0.0f;
  }
}

// =====================================================================================
// MFMA pixel-matmul family: per wave, one 64px x 64out strip.
// A-frag (weights, row-major [O][64] fp32): lane holds row = m*16+(lane&15),
//   k = s*32 + (lane>>4)*8 + j  (8 consecutive fp32 -> bf16x8).
// B-frag (input planes [c][px]): col = lane&15 -> px = p0 + 4*(lane&15) + e (e=0..3 via
//   float4 components -> 4 parity fragments), k = s*32 + (lane>>4)*8 + j (per-plane loads).
// C/D: col(px)=lane&15, row(out)=(lane>>4)*4+reg  [verified m89 layout].
// =====================================================================================

// loads B for one strip: bq[s][j] float4 (4 px per lane); builds bf[s][e] frags
#define MM_LOAD_B(in_ptr) \
  float4 bq[2][8]; \
  _Pragma("unroll") \
  for (int s=0;s<2;s++){ \
    const float* bp = (in_ptr) + ((i64)(s*32 + kg*8)<<16) + 4*lm; \
    _Pragma("unroll") \
    for (int j=0;j<8;j++) bq[s][j] = *(const float4*)(bp + ((i64)j<<16)); \
  } \
  bf16x8 bf[2][4]; \
  _Pragma("unroll") \
  for (int s=0;s<2;s++){ \
    bf16x8 f0,f1,f2,f3; \
    _Pragma("unroll") \
    for (int j=0;j<8;j++){ \
      f0[j]=(__bf16)bq[s][j].x; f1[j]=(__bf16)bq[s][j].y; \
      f2[j]=(__bf16)bq[s][j].z; f3[j]=(__bf16)bq[s][j].w; \
    } \
    bf[s][0]=f0; bf[s][1]=f1; bf[s][2]=f2; bf[s][3]=f3; \
  }

#define MM_COMPUTE(Wbase) \
  bf16x8 af[4][2]; \
  _Pragma("unroll") \
  for (int m=0;m<4;m++){ \
    _Pragma("unroll") \
    for (int s=0;s<2;s++) af[m][s] = cvt_w8((Wbase) + (m*16 + lm)*64 + s*32 + kg*8); \
  } \
  f32x4 acc[4][4]; \
  _Pragma("unroll") \
  for (int m=0;m<4;m++){ \
    _Pragma("unroll") \
    for (int e=0;e<4;e++){ f32x4 z = {0.f,0.f,0.f,0.f}; acc[m][e]=z; } \
  } \
  _Pragma("unroll") \
  for (int m=0;m<4;m++){ \
    _Pragma("unroll") \
    for (int e=0;e<4;e++){ \
      _Pragma("unroll") \
      for (int s=0;s<2;s++) acc[m][e] = MFMA16(af[m][s], bf[s][e], acc[m][e]); \
    } \
  }

#define MM_SETUP \
  int t = threadIdx.x; \
  int lane = t & 63, wvi = t >> 6; \
  i64 px0 = (i64)blockIdx.x*256 + wvi*64; \
  int b = (int)(px0 >> 16); \
  int p0 = (int)(px0 & (HW_-1)); \
  i64 ibase = ((i64)b<<22) + p0; \
  int lm = lane & 15, kg = lane >> 4;

// ---------------- fused: high/low DFT recon + conv1x1, MFMA ----------------
// Each lane computes its own B-fragment elements (8 ch x 4 px) pointwise -> no transpose.
template<int WHICH>   // 0 = high, 1 = low
__global__ __launch_bounds__(256) void k_mm_convq(const float* __restrict__ xc, const float* __restrict__ coeff,
      const float* __restrict__ flag, const float* __restrict__ qw, float* __restrict__ out){
  MM_SETUP
  float fl = flag[b];
  int y = p0 >> 8;
  int xb = (p0 & 255) + 4*lm;
  float angr = TWO_PI * ((float)y/256.0f);
  float crow = cosf(angr), srow = sinf(angr);
  float cx[4], sx[4], cd[4], sd[4];
  #pragma unroll
  for (int e=0;e<4;e++){
    int xx = xb + e;
    float a1 = TWO_PI * ((float)xx/256.0f);
    cx[e]=cosf(a1); sx[e]=sinf(a1);
    int d = (xx + y) & 255;
    float a2 = TWO_PI * ((float)d/256.0f);
    cd[e]=cosf(a2); sd[e]=sinf(a2);
  }
  bf16x8 bf[2][4];
  #pragma unroll
  for (int s=0;s<2;s++){
    bf16x8 f0,f1,f2,f3;
    #pragma unroll
    for (int j=0;j<8;j++){
      int ch = s*32 + kg*8 + j;
      const float* cf = coeff + ((b<<6)+ch)*8;
      float4 ca = *(const float4*)cf;
      float4 cb = *(const float4*)(cf+4);
      float F00=ca.x, cR=ca.y, cI=ca.z, rR=ca.w, rI=cb.x, dR=cb.y, dI=cb.z;
      float4 xr;
      if (WHICH==0) xr = *(const float4*)(xc + ibase + ((i64)ch<<16) + 4*lm);
      float vv[4];
      #pragma unroll
      for (int e=0;e<4;e++){
        float re = F00 + cR*cx[e] + cI*sx[e] + rR*crow + rI*srow + dR*cd[e] + dI*sd[e];
        float im =       cI*cx[e] - cR*sx[e] + rI*crow - rR*srow + dI*cd[e] - dR*sd[e];
        re*=fl; im*=fl;
        if (WHICH==1){ vv[e] = sqrtf(re*re+im*im); }
        else { float hr = ((WHICH==0)?((const float*)&xr)[e]:0.f) - re; vv[e] = sqrtf(hr*hr + im*im); }
      }
      f0[j]=(__bf16)vv[0]; f1[j]=(__bf16)vv[1]; f2[j]=(__bf16)vv[2]; f3[j]=(__bf16)vv[3];
    }
    bf[s][0]=f0; bf[s][1]=f1; bf[s][2]=f2; bf[s][3]=f3;
  }
  MM_COMPUTE(qw)
  #pragma unroll
  for (int m=0;m<4;m++){
    #pragma unroll
    for (int r=0;r<4;r++){
      int oc = m*16 + kg*4 + r;
      float4 st = make_float4(acc[m][0][r], acc[m][1][r], acc[m][2][r], acc[m][3][r]);
      *(float4*)(out + ibase + ((i64)oc<<16) + 4*lm) = st;
    }
  }
}

// ---------------- conv1x1 64->128 (k and v pre-tensors), MFMA ----------------
__global__ __launch_bounds__(256) void k_mm_kv(const float* __restrict__ in, const float* __restrict__ w,
      float* __restrict__ kout, float* __restrict__ vout){
  MM_SETUP
  MM_LOAD_B(in + ibase)
  #pragma unroll
  for (int half=0; half<2; half++){
    float* outp = half ? vout : kout;
    const float* Wb = w + half*4096;
    MM_COMPUTE(Wb)
    #pragma unroll
    for (int m=0;m<4;m++){
      #pragma unroll
      for (int r=0;r<4;r++){
        int oc = m*16 + kg*4 + r;
        float4 st = make_float4(acc[m][0][r], acc[m][1][r], acc[m][2][r], acc[m][3][r]);
        *(float4*)(outp + ibase + ((i64)oc<<16) + 4*lm) = st;
      }
    }
  }
}

// ---------------- plain conv1x1 64->64, MFMA ----------------
__global__ __launch_bounds__(256) void k_mm_64(const float* __restrict__ in, const float* __restrict__ w,
      float* __restrict__ out){
  MM_SETUP
  MM_LOAD_B(in + ibase)
  MM_COMPUTE(w)
  #pragma unroll
  for (int m=0;m<4;m++){
    #pragma unroll
    for (int r=0;r<4;r++){
      int oc = m*16 + kg*4 + r;
      float4 st = make_float4(acc[m][0][r], acc[m][1][r], acc[m][2][r], acc[m][3][r]);
      *(float4*)(out + ibase + ((i64)oc<<16) + 4*lm) = st;
    }
  }
}

// ---------------- mconv high: M x v + per-px channel max/mean, MFMA ----------------
__global__ __launch_bounds__(256) void k_mm_hi(const float* __restrict__ v, const float* __restrict__ M,
        float* __restrict__ mx, float* __restrict__ mn, float* __restrict__ out){
  MM_SETUP
  MM_LOAD_B(v + ibase)
  const float* Wb = M + ((i64)b<<12);
  MM_COMPUTE(Wb)
  float pmx[4] = {-1e30f,-1e30f,-1e30f,-1e30f};
  float ps[4]  = {0.f,0.f,0.f,0.f};
  #pragma unroll
  for (int m=0;m<4;m++){
    #pragma unroll
    for (int r=0;r<4;r++){
      int oc = m*16 + kg*4 + r;
      float4 st = make_float4(acc[m][0][r], acc[m][1][r], acc[m][2][r], acc[m][3][r]);
      *(float4*)(out + ibase + ((i64)oc<<16) + 4*lm) = st;
      pmx[0]=fmaxf(pmx[0],st.x); ps[0]+=st.x;
      pmx[1]=fmaxf(pmx[1],st.y); ps[1]+=st.y;
      pmx[2]=fmaxf(pmx[2],st.z); ps[2]+=st.z;
      pmx[3]=fmaxf(pmx[3],st.w); ps[3]+=st.w;
    }
  }
  // reduce across kg groups (lanes lm, lm+16, lm+32, lm+48) -> full 64-channel reduce
  #pragma unroll
  for (int e=0;e<4;e++){
    pmx[e] = fmaxf(pmx[e], __shfl_xor(pmx[e],16));
    pmx[e] = fmaxf(pmx[e], __shfl_xor(pmx[e],32));
    ps[e] += __shfl_xor(ps[e],16);
    ps[e] += __shfl_xor(ps[e],32);
  }
  if (kg==0){
    i64 pbase = ((i64)b<<16) + p0 + 4*lm;
    *(float4*)(mx+pbase) = make_float4(pmx[0],pmx[1],pmx[2],pmx[3]);
    *(float4*)(mn+pbase) = make_float4(ps[0]*(1.0f/64.0f),ps[1]*(1.0f/64.0f),
                                       ps[2]*(1.0f/64.0f),ps[3]*(1.0f/64.0f));
  }
}

// ---------------- mconv low: M x v + per-channel sum/max partials, MFMA ----------------
__global__ __launch_bounds__(256) void k_mm_lo(const float* __restrict__ v, const float* __restrict__ M,
        float* __restrict__ out, float* __restrict__ spart){
  __shared__ float ls[4][64], lmx[4][64];
  MM_SETUP
  MM_LOAD_B(v + ibase)
  const float* Wb = M + ((i64)b<<12);
  MM_COMPUTE(Wb)
  #pragma unroll
  for (int m=0;m<4;m++){
    #pragma unroll
    for (int r=0;r<4;r++){
      int oc = m*16 + kg*4 + r;
      float4 st = make_float4(acc[m][0][r], acc[m][1][r], acc[m][2][r], acc[m][3][r]);
      *(float4*)(out + ibase + ((i64)oc<<16) + 4*lm) = st;
      float s = st.x+st.y+st.z+st.w;
      float mm = fmaxf(fmaxf(st.x,st.y),fmaxf(st.z,st.w));
      // reduce across lm within the 16-lane kg group (pixel dim)
      #pragma unroll
      for (int off=8; off; off>>=1){ s += __shfl_xor(s,off); mm = fmaxf(mm,__shfl_xor(mm,off)); }
      if (lm==0){ ls[wvi][oc]=s; lmx[wvi][oc]=mm; }
    }
  }
  __syncthreads();
  if (t<64){
    float s = ls[0][t]+ls[1][t]+ls[2][t]+ls[3][t];
    float mm = fmaxf(fmaxf(lmx[0][t],lmx[1][t]),fmaxf(lmx[2][t],lmx[3][t]));
    spart[(i64)blockIdx.x*128 + t*2]   = s;
    spart[(i64)blockIdx.x*128 + t*2+1] = mm;
  }
}

// ---------------- fused comb + refine conv1x1, MFMA ----------------
__global__ __launch_bounds__(256) void k_mm_comb(const float* __restrict__ lo2, const float* __restrict__ hi2,
        const float* __restrict__ swb, const float* __restrict__ cwv,
        const float* __restrict__ w, const float* __restrict__ bias, float* __restrict__ out){
  MM_SETUP
  float4 sw4 = *(const float4*)(swb + ((i64)b<<16) + p0 + 4*lm);
  bf16x8 bf[2][4];
  #pragma unroll
  for (int s=0;s<2;s++){
    bf16x8 f0,f1,f2,f3;
    #pragma unroll
    for (int j=0;j<8;j++){
      int ch = s*32 + kg*8 + j;
      float4 l4 = *(const float4*)(lo2 + ibase + ((i64)ch<<16) + 4*lm);
      float4 h4 = *(const float4*)(hi2 + ibase + ((i64)ch<<16) + 4*lm);
      float cw = cwv[(b<<6) + ch];
      f0[j]=(__bf16)(l4.x*sw4.x + h4.x*cw);
      f1[j]=(__bf16)(l4.y*sw4.y + h4.y*cw);
      f2[j]=(__bf16)(l4.z*sw4.z + h4.z*cw);
      f3[j]=(__bf16)(l4.w*sw4.w + h4.w*cw);
    }
    bf[s][0]=f0; bf[s][1]=f1; bf[s][2]=f2; bf[s][3]=f3;
  }
  MM_COMPUTE(w)
  #pragma unroll
  for (int m=0;m<4;m++){
    #pragma unroll
    for (int r=0;r<4;r++){
      int oc = m*16 + kg*4 + r;
      float bv = bias[oc];
      float4 st = make_float4(acc[m][0][r]+bv, acc[m][1][r]+bv, acc[m][2][r]+bv, acc[m][3][r]+bv);
      *(float4*)(out + ibase + ((i64)oc<<16) + 4*lm) = st;
    }
  }
}

// ---------------- final mconv: M x v, *para1 + y*para2, MFMA ----------------
__global__ __launch_bounds__(256) void k_mm_fin(const float* __restrict__ v, const float* __restrict__ M,
      const float* __restrict__ para1, const float* __restrict__ para2,
      const float* __restrict__ yin, float* __restrict__ out){
  MM_SETUP
  MM_LOAD_B(v + ibase)
  const float* Wb = M + ((i64)b<<12);
  MM_COMPUTE(Wb)
  #pragma unroll
  for (int m=0;m<4;m++){
    #pragma unroll
    for (int r=0;r<4;r++){
      int oc = m*16 + kg*4 + r;
      float p1 = para1[oc], p2 = para2[oc];
      float4 yv = *(const float4*)(yin + ibase + ((i64)oc<<16) + 4*lm);
      float4 st = make_float4(acc[m][0][r]*p1 + yv.x*p2,
                              acc[m][1][r]*p1 + yv.y*p2,
                              acc[m][2][r]*p1 + yv.z*p2,
                              acc[m][3][r]*p1 + yv.w*p2);
      *(float4*)(out + ibase + ((i64)oc<<16) + 4*lm) = st;
    }
  }
}

// ---------------- Gram-MFMA stats: dw3x3(q) & dw3x3(k) -> 16x16 Gram via MFMA ----------------
// X = [q'0..q'7, k'0..k'7] (16 ch x px). G = X X^T contains all 80 stats:
// dot[a][d]=G[a][8+d], qn[a]=G[a][a], kn[d]=G[8+d][8+d].
// A-frag and B-frag of mfma_16x16x32 have IDENTICAL per-lane content for a Gram
// (A: row=lane&15,k=(lane>>4)*8+j; B: col=lane&15, same k) -> acc = MFMA(xf, xf, acc).
// Each lane: conv for channel lane&15 at 8 consecutive px (k-slice), row-rolling.
// Block = 4 waves; wave wvi covers chunks {2wvi, 2wvi+1} (64 px) x 16 rows.
__global__ __launch_bounds__(256) void k_gram(const float* __restrict__ qpre, const float* __restrict__ kpre,
        const float* __restrict__ qdw, const float* __restrict__ kdw, float* __restrict__ part){
  __shared__ float red[4][16][16];
  int blk = blockIdx.x;                 // bh*16 + rowblk
  int rowblk = blk & 15;
  int bh = blk >> 4;
  int h = bh & 7, b = bh >> 3;
  int t = threadIdx.x;
  int lane = t & 63, wvi = t >> 6;
  int lm = lane & 15, kg = lane >> 4;
  int a = lm & 7;
  const float* plane = (lm < 8 ? qpre : kpre) + (((i64)((b<<6)+(h<<3)+a))<<16);
  const float* wp = (lm < 8 ? qdw : kdw) + h*72 + a*9;
  float w0=wp[0],w1=wp[1],w2=wp[2],w3=wp[3],w4=wp[4],w5=wp[5],w6=wp[6],w7=wp[7],w8=wp[8];
  int R0 = rowblk*16;
  f32x4 acc = {0.f,0.f,0.f,0.f};
  #pragma unroll
  for (int cc=0; cc<2; cc++){
    int chunk = wvi*2 + cc;
    int xb = chunk*32 + kg*8;
    bool left = (xb==0), right = (xb==248);
    float h0[8], h1[8];
    #pragma unroll
    for (int e=0;e<8;e++){ h0[e]=0.f; h1[e]=0.f; }
    for (int ir = R0-1; ir <= R0+16; ir++){
      bool rok = ((unsigned)ir < 256u);
      float win[10];
      if (rok){
        const float* rp = plane + ir*256 + xb;
        win[0] = left ? 0.f : rp[-1];
        #pragma unroll
        for (int w=1; w<9; w++) win[w] = rp[w-1];
        win[9] = right ? 0.f : rp[8];
      } else {
        #pragma unroll
        for (int w=0; w<10; w++) win[w] = 0.f;
      }
      float o[8];
      #pragma unroll
      for (int e=0;e<8;e++){
        float t0 = w0*win[e] + w1*win[e+1] + w2*win[e+2];
        float t1 = w3*win[e] + w4*win[e+1] + w5*win[e+2];
        float t2 = w6*win[e] + w7*win[e+1] + w8*win[e+2];
        o[e] = h0[e] + t2;
        h0[e] = h1[e] + t1;
        h1[e] = t0;
      }
      if (ir > R0){
        bf16x8 xf;
        #pragma unroll
        for (int e=0;e<8;e++) xf[e] = (__bf16)o[e];
        acc = MFMA16(xf, xf, acc);
      }
    }
  }
  #pragma unroll
  for (int r=0;r<4;r++) red[wvi][kg*4+r][lm] = acc[r];
  __syncthreads();
  if (t < 80){
    int r, c;
    if (t < 64){ r = t>>3; c = 8 + (t&7); }
    else if (t < 72){ r = t-64; c = r; }
    else { r = 8 + (t-72); c = r; }
    float s = red[0][r][c]+red[1][r][c]+red[2][r][c]+red[3][r][c];
    part[(i64)blk*80 + t] = s;
  }
}

__global__ __launch_bounds__(128) void k_stats_fin(const float* __restrict__ part, float* __restrict__ stats){
  int bh = blockIdx.x; int t = threadIdx.x;
  if (t < 80){
    float s=0.f;
    for (int c=0;c<NCHUNK;c++) s += part[((i64)bh*NCHUNK+c)*80 + t];
    stats[bh*80+t] = s;
  }
}

// ---------------- softmax + fold attn into per-batch 64x64 M ----------------
__global__ __launch_bounds__(64) void k_attn_m(const float* __restrict__ stats, const float* __restrict__ temp,
                         const float* __restrict__ projw, float* __restrict__ M){
  __shared__ float attn[8][8][8];
  int b = blockIdx.x; int t = threadIdx.x;
  int h = t >> 3, cc = t & 7;
  const float* st = stats + (b*8+h)*80;
  float nq = fmaxf(sqrtf(st[64+cc]), 1e-12f);
  float tmp = temp[h];
  float s[8];
  float mx = -1e30f;
  #pragma unroll
  for (int d=0;d<8;d++){
    float nk = fmaxf(sqrtf(st[72+d]), 1e-12f);
    s[d] = st[cc*8+d]/(nq*nk)*tmp;
    mx = fmaxf(mx, s[d]);
  }
  float sum=0.f;
  #pragma unroll
  for (int d=0;d<8;d++){ s[d]=expf(s[d]-mx); sum+=s[d]; }
  float inv = 1.0f/sum;
  #pragma unroll
  for (int d=0;d<8;d++) attn[h][cc][d] = s[d]*inv;
  __syncthreads();
  int o = t;
  for (int hh=0; hh<8; hh++){
    #pragma unroll
    for (int d=0; d<8; d++){
      float acc=0.f;
      #pragma unroll
      for (int c2=0;c2<8;c2++) acc += projw[o*64 + hh*8 + c2]*attn[hh][c2][d];
      M[((i64)b*64 + o)*64 + hh*8 + d] = acc;
    }
  }
}

// ---------------- depthwise 3x3 (v path): row-swept, 16 rows/thread-column ----------------
__global__ __launch_bounds__(256) void k_dw(const float* __restrict__ in, const float* __restrict__ wd,
                                            float* __restrict__ out){
  int blk = blockIdx.x;              // ((b*64+c)*16 + yt)
  int yt = blk & 15; int c = (blk>>4)&63; int b = blk>>10;
  int x = threadIdx.x;
  const float* ip = in + (((i64)((b<<6)+c))<<16);
  float* op = out + (((i64)((b<<6)+c))<<16);
  const float* wp = wd + c*9;
  int y0 = yt*16;
  float a0,a1,a2, b0,b1,b2;
  {
    int yy = y0-1;
    if ((unsigned)yy<256u){ const float* rp = ip + yy*256;
      a0 = (x>0)? rp[x-1]:0.f; a1 = rp[x]; a2 = (x<255)? rp[x+1]:0.f;
    } else { a0=a1=a2=0.f; }
    const float* rp = ip + y0*256;
    b0 = (x>0)? rp[x-1]:0.f; b1 = rp[x]; b2 = (x<255)? rp[x+1]:0.f;
  }
  for (int rr=0;rr<16;rr++){
    float d0,d1,d2;
    int yy = y0+rr+1;
    if ((unsigned)yy<256u){ const float* rp = ip + yy*256;
      d0 = (x>0)? rp[x-1]:0.f; d1 = rp[x]; d2 = (x<255)? rp[x+1]:0.f;
    } else { d0=d1=d2=0.f; }
    float acc = wp[0]*a0+wp[1]*a1+wp[2]*a2 + wp[3]*b0+wp[4]*b1+wp[5]*b2 + wp[6]*d0+wp[7]*d1+wp[8]*d2;
    op[(y0+rr)*256 + x] = acc;
    a0=b0;a1=b1;a2=b2; b0=d0;b1=d1;b2=d2;
  }
}

// ---------------- refine small kernels ----------------
__global__ __launch_bounds__(64) void k_spatfin(const float* __restrict__ spart, float* __restrict__ lmean, float* __restrict__ lmax){
  int b = blockIdx.x; int c = threadIdx.x;
  float s=0.f, m=-1e30f;
  for (int r=0;r<256;r++){
    s += spart[(i64)(b*256+r)*128 + c*2];
    m = fmaxf(m, spart[(i64)(b*256+r)*128 + c*2+1]);
  }
  lmean[b*64+c] = s*(1.0f/65536.0f);
  lmax[b*64+c]  = m;
}

__global__ __launch_bounds__(64) void k_cw(const float* __restrict__ mean, const float* __restrict__ mxv,
                     const float* __restrict__ w1, const float* __restrict__ w2, float* __restrict__ cw){
  __shared__ float ha[4], hm[4];
  int b = blockIdx.x; int t = threadIdx.x;
  if (t < 4){
    float sa=0.f, sm_=0.f;
    for (int c=0;c<64;c++){ sa += w1[t*64+c]*mean[b*64+c]; sm_ += w1[t*64+c]*mxv[b*64+c]; }
    ha[t] = fmaxf(sa, 0.f); hm[t] = fmaxf(sm_, 0.f);
  }
  __syncthreads();
  float a=0.f;
  #pragma unroll
  for (int j=0;j<4;j++) a += w2[t*4+j]*(ha[j]+hm[j]);
  cw[b*64+t] = sigm(a);
}

__global__ __launch_bounds__(256) void k_sw(const float* __restrict__ mx, const float* __restrict__ mn,
                     const float* __restrict__ w, float* __restrict__ sw){
  int row = blockIdx.x & 255; int b = blockIdx.x >> 8; int t = threadIdx.x;
  const float* m0 = mx + ((i64)b<<16);
  const float* m1 = mn + ((i64)b<<16);
  float acc=0.f;
  for (int ky=0;ky<7;ky++){
    int yy = row+ky-3; if ((unsigned)yy>255u) continue;
    for (int kx=0;kx<7;kx++){
      int xx = t+kx-3; if ((unsigned)xx>255u) continue;
      acc += w[ky*7+kx]*m0[yy*256+xx] + w[49+ky*7+kx]*m1[yy*256+xx];
    }
  }
  sw[((i64)b<<16) + row*256 + t] = sigm(acc);
}

// =====================================================================================
extern "C" void kernel_launch(void* const* d_in, const int* in_sizes, int n_in,
                              void* d_out, int out_size, void* d_ws, size_t ws_size,
                              hipStream_t stream){
  const float* x      = (const float*)d_in[0];
  const float* y      = (const float*)d_in[1];
  const float* conv1w = (const float*)d_in[2];
  const float* ratew1 = (const float*)d_in[3];
  const float* ratew2 = (const float*)d_in[4];
  const float* temp   = (const float*)d_in[5];
  const float* qw     = (const float*)d_in[6];
  const float* qdw    = (const float*)d_in[7];
  const float* kvw    = (const float*)d_in[8];
  const float* kvdw   = (const float*)d_in[9];
  const float* projw  = (const float*)d_in[10];
  const float* spw    = (const float*)d_in[11];
  const float* cgw1   = (const float*)d_in[12];
  const float* cgw2   = (const float*)d_in[13];
  const float* rprojw = (const float*)d_in[14];
  const float* rprojb = (const float*)d_in[15];
  const float* para1  = (const float*)d_in[16];
  const float* para2  = (const float*)d_in[17];
  float* D = (float*)d_out;

  // pick largest batch-group size whose footprint fits: 3 big units + pool
  int nb = 8;
  for (;;){
    size_t unit = (size_t)nb*64*HW_;
    size_t pool = (size_t)nb*3*HW_            // Rbuf
                + (size_t)nb*512 + (size_t)nb*64 + 64
                + (size_t)nb*8*NCHUNK*80      // part
                + (size_t)nb*8*80             // stats
                + (size_t)nb*64*64            // M
                + 3*(size_t)nb*HW_            // mxmap, mnmap, swb
                + (size_t)nb*256*128          // spart
                + 3*(size_t)nb*64;            // lmean, lmax, cwb
    if ((3*unit + pool)*sizeof(float) <= ws_size || nb==1) break;
    nb >>= 1;
  }

  size_t unit = (size_t)nb*64*HW_;
  float* U0 = (float*)d_ws;
  float* U1 = U0 + unit;
  float* U2 = U1 + unit;
  float* sm = U2 + unit;
  float* Rbuf  = sm;  sm += (size_t)nb*3*HW_;
  float* coeff = sm;  sm += (size_t)nb*512;
  float* pooled= sm;  sm += (size_t)nb*64;
  float* flagb = sm;  sm += 64;
  float* part  = sm;  sm += (size_t)nb*8*NCHUNK*80;
  float* stats = sm;  sm += (size_t)nb*8*80;
  float* Mb    = sm;  sm += (size_t)nb*64*64;
  float* mxmap = sm;  sm += (size_t)nb*HW_;
  float* mnmap = sm;  sm += (size_t)nb*HW_;
  float* swb   = sm;  sm += (size_t)nb*HW_;
  float* spart = sm;  sm += (size_t)nb*256*128;
  float* lmean = sm;  sm += (size_t)nb*64;
  float* lmax  = sm;  sm += (size_t)nb*64;
  float* cwb   = sm;  sm += (size_t)nb*64;

  for (int b0 = 0; b0 < 8; b0 += nb){
    const float* yg = y + (i64)b0*64*HW_;
    float*       Dg = D + (i64)b0*64*HW_;

    // frontend
    k_resize <<<nb*3*256, 256,0,stream>>>(x, Rbuf, b0);
    k_conv3  <<<nb*256,   256,0,stream>>>(Rbuf, conv1w, U0);           // xc = U0
    k_dft    <<<nb*64,    256,0,stream>>>(U0, coeff, pooled);
    k_thr    <<<nb,       64, 0,stream>>>(pooled, ratew1, ratew2, flagb);

    // cca0 (a = high, from xc)
    k_mm_convq<0><<<nb*256,256,0,stream>>>(U0, coeff, flagb, qw + 0*4096, U1);    // qpre=U1
    k_mm_kv  <<<nb*256,256,0,stream>>>(yg, kvw + 0*8192, U2, Dg);                 // kpre=U2, vpre=Dg
    k_gram   <<<nb*8*NCHUNK,256,0,stream>>>(U1, U2, qdw + 0*576, kvdw + 0*1152, part);
    k_stats_fin<<<nb*8,  128,0,stream>>>(part, stats);
    k_dw      <<<nb*1024,256,0,stream>>>(Dg, kvdw + 0*1152 + 576, U1);            // v=U1
    k_attn_m  <<<nb,     64, 0,stream>>>(stats, temp + 0*8, projw + 0*4096, Mb);
    k_mm_hi  <<<nb*256, 256,0,stream>>>(U1, Mb, mxmap, mnmap, U2);                // high2=U2

    // cca1 (a = low, from xc)  [xc dead after this conv]
    k_mm_convq<1><<<nb*256,256,0,stream>>>(U0, coeff, flagb, qw + 1*4096, U1);    // qpre=U1
    k_mm_kv  <<<nb*256,256,0,stream>>>(yg, kvw + 1*8192, U0, Dg);                 // kpre=U0, vpre=Dg
    k_gram   <<<nb*8*NCHUNK,256,0,stream>>>(U1, U0, qdw + 1*576, kvdw + 1*1152, part);
    k_stats_fin<<<nb*8,  128,0,stream>>>(part, stats);
    k_dw      <<<nb*1024,256,0,stream>>>(Dg, kvdw + 1*1152 + 576, U1);            // v=U1
    k_attn_m  <<<nb,     64, 0,stream>>>(stats, temp + 1*8, projw + 1*4096, Mb);
    k_mm_lo  <<<nb*256, 256,0,stream>>>(U1, Mb, Dg, spart);                       // low2=Dg

    // refine: high2=U2, low2=Dg -> agg=U0
    k_spatfin <<<nb,     64, 0,stream>>>(spart, lmean, lmax);
    k_cw      <<<nb,     64, 0,stream>>>(lmean, lmax, cgw1, cgw2, cwb);
    k_sw      <<<nb*256, 256,0,stream>>>(mxmap, mnmap, spw, swb);
    k_mm_comb<<<nb*256,256,0,stream>>>(Dg, U2, swb, cwb, rprojw, rprojb, U0);     // agg=U0

    // cca2 (q from y, kv from agg=U0)
    k_mm_64  <<<nb*256,256,0,stream>>>(yg, qw + 2*4096, U1);                      // qpre=U1
    k_mm_kv  <<<nb*256,256,0,stream>>>(U0, kvw + 2*8192, U2, Dg);                 // kpre=U2, vpre=Dg
    k_gram   <<<nb*8*NCHUNK,256,0,stream>>>(U1, U2, qdw + 2*576, kvdw + 2*1152, part);
    k_stats_fin<<<nb*8,  128,0,stream>>>(part, stats);
    k_dw      <<<nb*1024,256,0,stream>>>(Dg, kvdw + 2*1152 + 576, U1);            // v=U1
    k_attn_m  <<<nb,     64, 0,stream>>>(stats, temp + 2*8, projw + 2*4096, Mb);
    k_mm_fin <<<nb*256,256,0,stream>>>(U1, Mb, para1, para2, yg, Dg);             // out
  }
}

// Round 6
// 1111.172 us; speedup vs baseline: 4.7593x; 1.3595x over previous
//
#include <hip/hip_runtime.h>
#include <math.h>

#define HW_ 65536
#define NCHUNK 16
typedef long long i64;
#define TWO_PI 6.283185307179586476925f

typedef __bf16 bf16x8 __attribute__((ext_vector_type(8)));
typedef __bf16 bf16x4 __attribute__((ext_vector_type(4)));
typedef float f32x4 __attribute__((ext_vector_type(4)));

#define MFMA16(A,B,C) __builtin_amdgcn_mfma_f32_16x16x32_bf16(A,B,C,0,0,0)

__device__ __forceinline__ float sigm(float x){ return 1.0f/(1.0f+expf(-x)); }

// convert 8 consecutive fp32 to a bf16x8 A-fragment
__device__ __forceinline__ bf16x8 cvt_w8(const float* wp){
  float4 w0 = *(const float4*)wp;
  float4 w1 = *(const float4*)(wp+4);
  bf16x8 r;
  r[0]=(__bf16)w0.x; r[1]=(__bf16)w0.y; r[2]=(__bf16)w0.z; r[3]=(__bf16)w0.w;
  r[4]=(__bf16)w1.x; r[5]=(__bf16)w1.y; r[6]=(__bf16)w1.z; r[7]=(__bf16)w1.w;
  return r;
}

__device__ __forceinline__ void st_bf4(__bf16* p, float a, float b, float c, float d){
  bf16x4 v; v[0]=(__bf16)a; v[1]=(__bf16)b; v[2]=(__bf16)c; v[3]=(__bf16)d;
  *(bf16x4*)p = v;
}

// ---------------- resize (nb,3,128,128) -> (nb,3,256,256) bilinear half-pixel ----------------
__global__ __launch_bounds__(256) void k_resize(const float* __restrict__ x, float* __restrict__ R, int b0){
  int idx = blockIdx.x*256 + threadIdx.x;
  int ox = idx & 255;
  int oy = (idx >> 8) & 255;
  int bc = idx >> 16;                               // lb*3 + c
  int lb = bc/3; int c = bc - lb*3;
  float sx = ox*0.5f - 0.25f;
  float sy = oy*0.5f - 0.25f;
  int x0 = (int)floorf(sx); float fx = sx - (float)x0;
  int y0 = (int)floorf(sy); float fy = sy - (float)y0;
  int x1 = min(x0+1,127); int y1 = min(y0+1,127);
  x0 = max(x0,0); y0 = max(y0,0);
  const float* p = x + ((i64)(b0+lb)*3 + c)*16384;
  float v00=p[y0*128+x0], v01=p[y0*128+x1], v10=p[y1*128+x0], v11=p[y1*128+x1];
  R[idx] = (1.0f-fy)*((1.0f-fx)*v00 + fx*v01) + fy*((1.0f-fx)*v10 + fx*v11);
}

// ---------------- conv3x3 3->64: block per (b,row), all 64 outs per thread ----------------
__global__ __launch_bounds__(256) void k_conv3(const float* __restrict__ R, const float* __restrict__ w, float* __restrict__ out){
  int y = blockIdx.x & 255; int b = blockIdx.x >> 8; int t = threadIdx.x;
  float win[27];
  #pragma unroll
  for (int ci=0;ci<3;ci++){
    #pragma unroll
    for (int ky=0;ky<3;ky++){
      int yy = y+ky-1;
      const float* ip = R + (((i64)(b*3+ci))<<16) + yy*256;
      #pragma unroll
      for (int kx=0;kx<3;kx++){
        int xx = t+kx-1;
        float v = 0.f;
        if ((unsigned)yy<256u && (unsigned)xx<256u) v = ip[xx];
        win[ci*9+ky*3+kx] = v;
      }
    }
  }
  i64 obase = ((i64)b<<22) + (y<<8) + t;
  for (int o=0;o<64;o++){
    const float* wp = w + o*27;
    float acc=0.f;
    #pragma unroll
    for (int j=0;j<27;j++) acc += wp[j]*win[j];
    out[obase + ((i64)o<<16)] = acc;
  }
}

// ---------------- DFT coeffs (7 reals incl. DC) + pooled mean per (b,c) ----------------
__global__ __launch_bounds__(256) void k_dft(const float* __restrict__ xc, float* __restrict__ coeff, float* __restrict__ pooled){
  __shared__ float tc[256], ts[256];
  __shared__ float red[256];
  int t = threadIdx.x;
  float ang = TWO_PI * ((float)t/256.0f);
  tc[t] = cosf(ang); ts[t] = sinf(ang);
  __syncthreads();
  int bc = blockIdx.x;
  const float* p = xc + (i64)bc*HW_;
  float s=0, cr=0, ci=0, rr=0, ri=0, dr=0, di=0;
  for (int i=t; i<HW_; i+=256){
    float v = p[i];
    int col = i & 255, row = i >> 8, ds = (row+col)&255;
    s  += v;
    cr += v*tc[col]; ci += v*ts[col];
    rr += v*tc[row]; ri += v*ts[row];
    dr += v*tc[ds];  di += v*ts[ds];
  }
  float vals[7] = {s,cr,ci,rr,ri,dr,di};
  for (int j=0;j<7;j++){
    red[t] = vals[j]; __syncthreads();
    for (int st=128; st>0; st>>=1){ if (t<st) red[t]+=red[t+st]; __syncthreads(); }
    if (t==0) vals[j] = red[0];
    __syncthreads();
  }
  if (t==0){
    const float sc = 1.0f/65536.0f;
    for (int j=0;j<7;j++) coeff[bc*8+j] = vals[j]*sc;
    pooled[bc] = vals[0]*sc;
  }
}

// ---------------- threshold MLP -> per-batch mask flag ----------------
__global__ __launch_bounds__(64) void k_thr(const float* __restrict__ pooled, const float* __restrict__ w1,
                      const float* __restrict__ w2, float* __restrict__ flag){
  __shared__ float hid[8];
  int b = blockIdx.x; int t = threadIdx.x;
  if (t < 8){
    float a = 0.f;
    for (int c=0;c<64;c++) a += pooled[b*64+c]*w1[t*64+c];
    hid[t] = 0.5f*a*(1.0f+erff(a*0.70710678118654752440f));
  }
  __syncthreads();
  if (t==0){
    float t0=0,t1=0;
    for (int k=0;k<8;k++){ t0 += hid[k]*w2[k]; t1 += hid[k]*w2[8+k]; }
    int h_ = (int)(2.0f*sigm(t0));
    int w_ = (int)(2.0f*sigm(t1));
    flag[b] = (h_>0 && w_>0) ? 1.0f : 0.0f;
  }
}

// =====================================================================================
// MFMA pixel-matmul family: per wave, one 64px x 64out strip.
// A-frag (weights, row-major [O][64] fp32): lane holds row = m*16+(lane&15),
//   k = s*32 + (lane>>4)*8 + j.  B-frag: col = lane&15 -> px = p0 + 4*(lane&15) + e.
// C/D: col(px)=lane&15, row(out)=(lane>>4)*4+reg  [verified m89 layout].
// Intermediates stored bf16 (they are consumed as bf16 B-fragments anyway).
// =====================================================================================

#define MM_FILL_B_F32(in_ptr) \
  _Pragma("unroll") \
  for (int s=0;s<2;s++){ \
    _Pragma("unroll") \
    for (int j=0;j<8;j++){ \
      float4 q = *(const float4*)((in_ptr) + ((i64)(s*32 + kg*8 + j)<<16) + 4*lm); \
      bf[s][0][j]=(__bf16)q.x; bf[s][1][j]=(__bf16)q.y; \
      bf[s][2][j]=(__bf16)q.z; bf[s][3][j]=(__bf16)q.w; \
    } \
  }

#define MM_FILL_B_BF(in_ptr) \
  _Pragma("unroll") \
  for (int s=0;s<2;s++){ \
    _Pragma("unroll") \
    for (int j=0;j<8;j++){ \
      bf16x4 u = *(const bf16x4*)((in_ptr) + ((i64)(s*32 + kg*8 + j)<<16) + 4*lm); \
      bf[s][0][j]=u[0]; bf[s][1][j]=u[1]; bf[s][2][j]=u[2]; bf[s][3][j]=u[3]; \
    } \
  }

#define MM_COMPUTE(Wbase) \
  bf16x8 af[4][2]; \
  _Pragma("unroll") \
  for (int m=0;m<4;m++){ \
    _Pragma("unroll") \
    for (int s=0;s<2;s++) af[m][s] = cvt_w8((Wbase) + (m*16 + lm)*64 + s*32 + kg*8); \
  } \
  f32x4 acc[4][4]; \
  _Pragma("unroll") \
  for (int m=0;m<4;m++){ \
    _Pragma("unroll") \
    for (int e=0;e<4;e++){ f32x4 z = {0.f,0.f,0.f,0.f}; acc[m][e]=z; } \
  } \
  _Pragma("unroll") \
  for (int m=0;m<4;m++){ \
    _Pragma("unroll") \
    for (int e=0;e<4;e++){ \
      _Pragma("unroll") \
      for (int s=0;s<2;s++) acc[m][e] = MFMA16(af[m][s], bf[s][e], acc[m][e]); \
    } \
  }

#define MM_SETUP \
  int t = threadIdx.x; \
  int lane = t & 63, wvi = t >> 6; \
  i64 px0 = (i64)blockIdx.x*256 + wvi*64; \
  int b = (int)(px0 >> 16); \
  int p0 = (int)(px0 & (HW_-1)); \
  i64 ibase = ((i64)b<<22) + p0; \
  int lm = lane & 15, kg = lane >> 4;

// ---------------- fused: high/low DFT recon + conv1x1, MFMA, bf16 out ----------------
template<int WHICH>   // 0 = high, 1 = low
__global__ __launch_bounds__(256) void k_mm_convq(const float* __restrict__ xc, const float* __restrict__ coeff,
      const float* __restrict__ flag, const float* __restrict__ qw, __bf16* __restrict__ out){
  MM_SETUP
  float fl = flag[b];
  int y = p0 >> 8;
  int xb = (p0 & 255) + 4*lm;
  float angr = TWO_PI * ((float)y/256.0f);
  float crow = cosf(angr), srow = sinf(angr);
  float cx[4], sx[4], cd[4], sd[4];
  #pragma unroll
  for (int e=0;e<4;e++){
    int xx = xb + e;
    float a1 = TWO_PI * ((float)xx/256.0f);
    cx[e]=cosf(a1); sx[e]=sinf(a1);
    int d = (xx + y) & 255;
    float a2 = TWO_PI * ((float)d/256.0f);
    cd[e]=cosf(a2); sd[e]=sinf(a2);
  }
  bf16x8 bf[2][4];
  #pragma unroll
  for (int s=0;s<2;s++){
    #pragma unroll
    for (int j=0;j<8;j++){
      int ch = s*32 + kg*8 + j;
      const float* cf = coeff + ((b<<6)+ch)*8;
      float4 ca = *(const float4*)cf;
      float4 cb = *(const float4*)(cf+4);
      float F00=ca.x, cR=ca.y, cI=ca.z, rR=ca.w, rI=cb.x, dR=cb.y, dI=cb.z;
      float4 xr;
      if (WHICH==0) xr = *(const float4*)(xc + ibase + ((i64)ch<<16) + 4*lm);
      #pragma unroll
      for (int e=0;e<4;e++){
        float re = F00 + cR*cx[e] + cI*sx[e] + rR*crow + rI*srow + dR*cd[e] + dI*sd[e];
        float im =       cI*cx[e] - cR*sx[e] + rI*crow - rR*srow + dI*cd[e] - dR*sd[e];
        re*=fl; im*=fl;
        float v;
        if (WHICH==1){ v = sqrtf(re*re+im*im); }
        else { float hr = ((const float*)&xr)[e] - re; v = sqrtf(hr*hr + im*im); }
        bf[s][e][j] = (__bf16)v;
      }
    }
  }
  MM_COMPUTE(qw)
  #pragma unroll
  for (int m=0;m<4;m++){
    #pragma unroll
    for (int r=0;r<4;r++){
      int oc = m*16 + kg*4 + r;
      st_bf4(out + ibase + ((i64)oc<<16) + 4*lm, acc[m][0][r], acc[m][1][r], acc[m][2][r], acc[m][3][r]);
    }
  }
}

// ---------------- conv1x1 64->128 (k and v pre-tensors), MFMA, bf16 out ----------------
template<int BFIN>   // 0: fp32 input (y), 1: bf16 input (agg)
__global__ __launch_bounds__(256) void k_mm_kv(const void* __restrict__ inv, const float* __restrict__ w,
      __bf16* __restrict__ kout, __bf16* __restrict__ vout){
  MM_SETUP
  bf16x8 bf[2][4];
  if constexpr (BFIN){ const __bf16* in = (const __bf16*)inv; MM_FILL_B_BF(in + ibase) }
  else               { const float*  in = (const float*)inv;  MM_FILL_B_F32(in + ibase) }
  #pragma unroll
  for (int half=0; half<2; half++){
    __bf16* outp = half ? vout : kout;
    const float* Wb = w + half*4096;
    MM_COMPUTE(Wb)
    #pragma unroll
    for (int m=0;m<4;m++){
      #pragma unroll
      for (int r=0;r<4;r++){
        int oc = m*16 + kg*4 + r;
        st_bf4(outp + ibase + ((i64)oc<<16) + 4*lm, acc[m][0][r], acc[m][1][r], acc[m][2][r], acc[m][3][r]);
      }
    }
  }
}

// ---------------- plain conv1x1 64->64 (fp32 in, bf16 out), MFMA ----------------
__global__ __launch_bounds__(256) void k_mm_64(const float* __restrict__ in, const float* __restrict__ w,
      __bf16* __restrict__ out){
  MM_SETUP
  bf16x8 bf[2][4];
  MM_FILL_B_F32(in + ibase)
  MM_COMPUTE(w)
  #pragma unroll
  for (int m=0;m<4;m++){
    #pragma unroll
    for (int r=0;r<4;r++){
      int oc = m*16 + kg*4 + r;
      st_bf4(out + ibase + ((i64)oc<<16) + 4*lm, acc[m][0][r], acc[m][1][r], acc[m][2][r], acc[m][3][r]);
    }
  }
}

// ---------------- mconv high: M x v + per-px channel max/mean (fp32 stats from acc) ----------------
__global__ __launch_bounds__(256) void k_mm_hi(const __bf16* __restrict__ v, const float* __restrict__ M,
        float* __restrict__ mx, float* __restrict__ mn, __bf16* __restrict__ out){
  MM_SETUP
  bf16x8 bf[2][4];
  MM_FILL_B_BF(v + ibase)
  const float* Wb = M + ((i64)b<<12);
  MM_COMPUTE(Wb)
  float pmx[4] = {-1e30f,-1e30f,-1e30f,-1e30f};
  float ps[4]  = {0.f,0.f,0.f,0.f};
  #pragma unroll
  for (int m=0;m<4;m++){
    #pragma unroll
    for (int r=0;r<4;r++){
      int oc = m*16 + kg*4 + r;
      float ax=acc[m][0][r], ay=acc[m][1][r], az=acc[m][2][r], aw=acc[m][3][r];
      st_bf4(out + ibase + ((i64)oc<<16) + 4*lm, ax, ay, az, aw);
      pmx[0]=fmaxf(pmx[0],ax); ps[0]+=ax;
      pmx[1]=fmaxf(pmx[1],ay); ps[1]+=ay;
      pmx[2]=fmaxf(pmx[2],az); ps[2]+=az;
      pmx[3]=fmaxf(pmx[3],aw); ps[3]+=aw;
    }
  }
  #pragma unroll
  for (int e=0;e<4;e++){
    pmx[e] = fmaxf(pmx[e], __shfl_xor(pmx[e],16));
    pmx[e] = fmaxf(pmx[e], __shfl_xor(pmx[e],32));
    ps[e] += __shfl_xor(ps[e],16);
    ps[e] += __shfl_xor(ps[e],32);
  }
  if (kg==0){
    i64 pbase = ((i64)b<<16) + p0 + 4*lm;
    *(float4*)(mx+pbase) = make_float4(pmx[0],pmx[1],pmx[2],pmx[3]);
    *(float4*)(mn+pbase) = make_float4(ps[0]*(1.0f/64.0f),ps[1]*(1.0f/64.0f),
                                       ps[2]*(1.0f/64.0f),ps[3]*(1.0f/64.0f));
  }
}

// ---------------- mconv low: M x v + per-channel sum/max partials (fp32 from acc) ----------------
__global__ __launch_bounds__(256) void k_mm_lo(const __bf16* __restrict__ v, const float* __restrict__ M,
        __bf16* __restrict__ out, float* __restrict__ spart){
  __shared__ float ls[4][64], lmx[4][64];
  MM_SETUP
  bf16x8 bf[2][4];
  MM_FILL_B_BF(v + ibase)
  const float* Wb = M + ((i64)b<<12);
  MM_COMPUTE(Wb)
  #pragma unroll
  for (int m=0;m<4;m++){
    #pragma unroll
    for (int r=0;r<4;r++){
      int oc = m*16 + kg*4 + r;
      float ax=acc[m][0][r], ay=acc[m][1][r], az=acc[m][2][r], aw=acc[m][3][r];
      st_bf4(out + ibase + ((i64)oc<<16) + 4*lm, ax, ay, az, aw);
      float s = ax+ay+az+aw;
      float mm = fmaxf(fmaxf(ax,ay),fmaxf(az,aw));
      #pragma unroll
      for (int off=8; off; off>>=1){ s += __shfl_xor(s,off); mm = fmaxf(mm,__shfl_xor(mm,off)); }
      if (lm==0){ ls[wvi][oc]=s; lmx[wvi][oc]=mm; }
    }
  }
  __syncthreads();
  if (t<64){
    float s = ls[0][t]+ls[1][t]+ls[2][t]+ls[3][t];
    float mm = fmaxf(fmaxf(lmx[0][t],lmx[1][t]),fmaxf(lmx[2][t],lmx[3][t]));
    spart[(i64)blockIdx.x*128 + t*2]   = s;
    spart[(i64)blockIdx.x*128 + t*2+1] = mm;
  }
}

// ---------------- fused comb + refine conv1x1 (bf16 in/out), MFMA ----------------
__global__ __launch_bounds__(256) void k_mm_comb(const __bf16* __restrict__ lo2, const __bf16* __restrict__ hi2,
        const float* __restrict__ swb, const float* __restrict__ cwv,
        const float* __restrict__ w, const float* __restrict__ bias, __bf16* __restrict__ out){
  MM_SETUP
  float4 sw4 = *(const float4*)(swb + ((i64)b<<16) + p0 + 4*lm);
  bf16x8 bf[2][4];
  #pragma unroll
  for (int s=0;s<2;s++){
    #pragma unroll
    for (int j=0;j<8;j++){
      int ch = s*32 + kg*8 + j;
      bf16x4 l4 = *(const bf16x4*)(lo2 + ibase + ((i64)ch<<16) + 4*lm);
      bf16x4 h4 = *(const bf16x4*)(hi2 + ibase + ((i64)ch<<16) + 4*lm);
      float cw = cwv[(b<<6) + ch];
      bf[s][0][j]=(__bf16)((float)l4[0]*sw4.x + (float)h4[0]*cw);
      bf[s][1][j]=(__bf16)((float)l4[1]*sw4.y + (float)h4[1]*cw);
      bf[s][2][j]=(__bf16)((float)l4[2]*sw4.z + (float)h4[2]*cw);
      bf[s][3][j]=(__bf16)((float)l4[3]*sw4.w + (float)h4[3]*cw);
    }
  }
  MM_COMPUTE(w)
  #pragma unroll
  for (int m=0;m<4;m++){
    #pragma unroll
    for (int r=0;r<4;r++){
      int oc = m*16 + kg*4 + r;
      float bv = bias[oc];
      st_bf4(out + ibase + ((i64)oc<<16) + 4*lm, acc[m][0][r]+bv, acc[m][1][r]+bv, acc[m][2][r]+bv, acc[m][3][r]+bv);
    }
  }
}

// ---------------- final mconv: M x v, *para1 + y*para2 (fp32 out) ----------------
__global__ __launch_bounds__(256) void k_mm_fin(const __bf16* __restrict__ v, const float* __restrict__ M,
      const float* __restrict__ para1, const float* __restrict__ para2,
      const float* __restrict__ yin, float* __restrict__ out){
  MM_SETUP
  bf16x8 bf[2][4];
  MM_FILL_B_BF(v + ibase)
  const float* Wb = M + ((i64)b<<12);
  MM_COMPUTE(Wb)
  #pragma unroll
  for (int m=0;m<4;m++){
    #pragma unroll
    for (int r=0;r<4;r++){
      int oc = m*16 + kg*4 + r;
      float p1 = para1[oc], p2 = para2[oc];
      float4 yv = *(const float4*)(yin + ibase + ((i64)oc<<16) + 4*lm);
      float4 st = make_float4(acc[m][0][r]*p1 + yv.x*p2,
                              acc[m][1][r]*p1 + yv.y*p2,
                              acc[m][2][r]*p1 + yv.z*p2,
                              acc[m][3][r]*p1 + yv.w*p2);
      *(float4*)(out + ibase + ((i64)oc<<16) + 4*lm) = st;
    }
  }
}

// ---------------- Gram-MFMA stats (bf16 inputs): dw3x3(q)&dw3x3(k) -> 16x16 Gram ----------------
// acc = MFMA(xf, xf, acc): A-frag and B-frag have identical per-lane content for a Gram.
__global__ __launch_bounds__(256) void k_gram(const __bf16* __restrict__ qpre, const __bf16* __restrict__ kpre,
        const float* __restrict__ qdw, const float* __restrict__ kdw, float* __restrict__ part){
  __shared__ float red[4][16][16];
  int blk = blockIdx.x;                 // bh*16 + rowblk
  int rowblk = blk & 15;
  int bh = blk >> 4;
  int h = bh & 7, b = bh >> 3;
  int t = threadIdx.x;
  int lane = t & 63, wvi = t >> 6;
  int lm = lane & 15, kg = lane >> 4;
  int a = lm & 7;
  const __bf16* plane = (lm < 8 ? qpre : kpre) + (((i64)((b<<6)+(h<<3)+a))<<16);
  const float* wp = (lm < 8 ? qdw : kdw) + h*72 + a*9;
  float w0=wp[0],w1=wp[1],w2=wp[2],w3=wp[3],w4=wp[4],w5=wp[5],w6=wp[6],w7=wp[7],w8=wp[8];
  int R0 = rowblk*16;
  f32x4 acc = {0.f,0.f,0.f,0.f};
  #pragma unroll
  for (int cc=0; cc<2; cc++){
    int chunk = wvi*2 + cc;
    int xb = chunk*32 + kg*8;
    bool left = (xb==0), right = (xb==248);
    float h0[8], h1[8];
    #pragma unroll
    for (int e=0;e<8;e++){ h0[e]=0.f; h1[e]=0.f; }
    for (int ir = R0-1; ir <= R0+16; ir++){
      bool rok = ((unsigned)ir < 256u);
      float win[10];
      if (rok){
        const __bf16* rp = plane + ir*256 + xb;
        bf16x8 mid = *(const bf16x8*)rp;
        win[0] = left ? 0.f : (float)rp[-1];
        #pragma unroll
        for (int w=1; w<9; w++) win[w] = (float)mid[w-1];
        win[9] = right ? 0.f : (float)rp[8];
      } else {
        #pragma unroll
        for (int w=0; w<10; w++) win[w] = 0.f;
      }
      float o[8];
      #pragma unroll
      for (int e=0;e<8;e++){
        float t0 = w0*win[e] + w1*win[e+1] + w2*win[e+2];
        float t1 = w3*win[e] + w4*win[e+1] + w5*win[e+2];
        float t2 = w6*win[e] + w7*win[e+1] + w8*win[e+2];
        o[e] = h0[e] + t2;
        h0[e] = h1[e] + t1;
        h1[e] = t0;
      }
      if (ir > R0){
        bf16x8 xf;
        #pragma unroll
        for (int e=0;e<8;e++) xf[e] = (__bf16)o[e];
        acc = MFMA16(xf, xf, acc);
      }
    }
  }
  #pragma unroll
  for (int r=0;r<4;r++) red[wvi][kg*4+r][lm] = acc[r];
  __syncthreads();
  if (t < 80){
    int r, c;
    if (t < 64){ r = t>>3; c = 8 + (t&7); }
    else if (t < 72){ r = t-64; c = r; }
    else { r = 8 + (t-72); c = r; }
    float s = red[0][r][c]+red[1][r][c]+red[2][r][c]+red[3][r][c];
    part[(i64)blk*80 + t] = s;
  }
}

__global__ __launch_bounds__(128) void k_stats_fin(const float* __restrict__ part, float* __restrict__ stats){
  int bh = blockIdx.x; int t = threadIdx.x;
  if (t < 80){
    float s=0.f;
    for (int c=0;c<NCHUNK;c++) s += part[((i64)bh*NCHUNK+c)*80 + t];
    stats[bh*80+t] = s;
  }
}

// ---------------- softmax + fold attn into per-batch 64x64 M ----------------
__global__ __launch_bounds__(64) void k_attn_m(const float* __restrict__ stats, const float* __restrict__ temp,
                         const float* __restrict__ projw, float* __restrict__ M){
  __shared__ float attn[8][8][8];
  int b = blockIdx.x; int t = threadIdx.x;
  int h = t >> 3, cc = t & 7;
  const float* st = stats + (b*8+h)*80;
  float nq = fmaxf(sqrtf(st[64+cc]), 1e-12f);
  float tmp = temp[h];
  float s[8];
  float mx = -1e30f;
  #pragma unroll
  for (int d=0;d<8;d++){
    float nk = fmaxf(sqrtf(st[72+d]), 1e-12f);
    s[d] = st[cc*8+d]/(nq*nk)*tmp;
    mx = fmaxf(mx, s[d]);
  }
  float sum=0.f;
  #pragma unroll
  for (int d=0;d<8;d++){ s[d]=expf(s[d]-mx); sum+=s[d]; }
  float inv = 1.0f/sum;
  #pragma unroll
  for (int d=0;d<8;d++) attn[h][cc][d] = s[d]*inv;
  __syncthreads();
  int o = t;
  for (int hh=0; hh<8; hh++){
    #pragma unroll
    for (int d=0; d<8; d++){
      float acc=0.f;
      #pragma unroll
      for (int c2=0;c2<8;c2++) acc += projw[o*64 + hh*8 + c2]*attn[hh][c2][d];
      M[((i64)b*64 + o)*64 + hh*8 + d] = acc;
    }
  }
}

// ---------------- depthwise 3x3 (v path), bf16 in/out, rolling 16-row slabs, 8px/thread ----------------
__global__ __launch_bounds__(256) void k_dwb(const __bf16* __restrict__ in, const float* __restrict__ wd,
                                             __bf16* __restrict__ out){
  int blk = blockIdx.x;              // b*128 + c*2 + half
  int half = blk & 1; int c = (blk>>1)&63; int b = blk>>7;
  int t = threadIdx.x;
  int strip = t & 31, rg = t >> 5;
  const __bf16* ip = in + (((i64)((b<<6)+c))<<16);
  __bf16* op = out + (((i64)((b<<6)+c))<<16);
  const float* wp = wd + c*9;
  float w0=wp[0],w1=wp[1],w2=wp[2],w3=wp[3],w4=wp[4],w5=wp[5],w6=wp[6],w7=wp[7],w8=wp[8];
  int R0 = half*128 + rg*16;
  int xb = strip*8;
  bool left = (xb==0), right = (xb==248);
  float h0[8], h1[8];
  #pragma unroll
  for (int e=0;e<8;e++){ h0[e]=0.f; h1[e]=0.f; }
  for (int ir = R0-1; ir <= R0+16; ir++){
    bool rok = ((unsigned)ir < 256u);
    float win[10];
    if (rok){
      const __bf16* rp = ip + ir*256 + xb;
      bf16x8 mid = *(const bf16x8*)rp;
      win[0] = left ? 0.f : (float)rp[-1];
      #pragma unroll
      for (int w=1; w<9; w++) win[w] = (float)mid[w-1];
      win[9] = right ? 0.f : (float)rp[8];
    } else {
      #pragma unroll
      for (int w=0; w<10; w++) win[w] = 0.f;
    }
    float o[8];
    #pragma unroll
    for (int e=0;e<8;e++){
      float t0 = w0*win[e] + w1*win[e+1] + w2*win[e+2];
      float t1 = w3*win[e] + w4*win[e+1] + w5*win[e+2];
      float t2 = w6*win[e] + w7*win[e+1] + w8*win[e+2];
      o[e] = h0[e] + t2;
      h0[e] = h1[e] + t1;
      h1[e] = t0;
    }
    if (ir > R0){
      bf16x8 ov;
      #pragma unroll
      for (int e=0;e<8;e++) ov[e] = (__bf16)o[e];
      *(bf16x8*)(op + (ir-1)*256 + xb) = ov;
    }
  }
}

// ---------------- refine small kernels ----------------
__global__ __launch_bounds__(64) void k_spatfin(const float* __restrict__ spart, float* __restrict__ lmean, float* __restrict__ lmax){
  int b = blockIdx.x; int c = threadIdx.x;
  float s=0.f, m=-1e30f;
  for (int r=0;r<256;r++){
    s += spart[(i64)(b*256+r)*128 + c*2];
    m = fmaxf(m, spart[(i64)(b*256+r)*128 + c*2+1]);
  }
  lmean[b*64+c] = s*(1.0f/65536.0f);
  lmax[b*64+c]  = m;
}

__global__ __launch_bounds__(64) void k_cw(const float* __restrict__ mean, const float* __restrict__ mxv,
                     const float* __restrict__ w1, const float* __restrict__ w2, float* __restrict__ cw){
  __shared__ float ha[4], hm[4];
  int b = blockIdx.x; int t = threadIdx.x;
  if (t < 4){
    float sa=0.f, sm_=0.f;
    for (int c=0;c<64;c++){ sa += w1[t*64+c]*mean[b*64+c]; sm_ += w1[t*64+c]*mxv[b*64+c]; }
    ha[t] = fmaxf(sa, 0.f); hm[t] = fmaxf(sm_, 0.f);
  }
  __syncthreads();
  float a=0.f;
  #pragma unroll
  for (int j=0;j<4;j++) a += w2[t*4+j]*(ha[j]+hm[j]);
  cw[b*64+t] = sigm(a);
}

__global__ __launch_bounds__(256) void k_sw(const float* __restrict__ mx, const float* __restrict__ mn,
                     const float* __restrict__ w, float* __restrict__ sw){
  int row = blockIdx.x & 255; int b = blockIdx.x >> 8; int t = threadIdx.x;
  const float* m0 = mx + ((i64)b<<16);
  const float* m1 = mn + ((i64)b<<16);
  float acc=0.f;
  for (int ky=0;ky<7;ky++){
    int yy = row+ky-3; if ((unsigned)yy>255u) continue;
    for (int kx=0;kx<7;kx++){
      int xx = t+kx-3; if ((unsigned)xx>255u) continue;
      acc += w[ky*7+kx]*m0[yy*256+xx] + w[49+ky*7+kx]*m1[yy*256+xx];
    }
  }
  sw[((i64)b<<16) + row*256 + t] = sigm(acc);
}

// =====================================================================================
extern "C" void kernel_launch(void* const* d_in, const int* in_sizes, int n_in,
                              void* d_out, int out_size, void* d_ws, size_t ws_size,
                              hipStream_t stream){
  const float* x      = (const float*)d_in[0];
  const float* y      = (const float*)d_in[1];
  const float* conv1w = (const float*)d_in[2];
  const float* ratew1 = (const float*)d_in[3];
  const float* ratew2 = (const float*)d_in[4];
  const float* temp   = (const float*)d_in[5];
  const float* qw     = (const float*)d_in[6];
  const float* qdw    = (const float*)d_in[7];
  const float* kvw    = (const float*)d_in[8];
  const float* kvdw   = (const float*)d_in[9];
  const float* projw  = (const float*)d_in[10];
  const float* spw    = (const float*)d_in[11];
  const float* cgw1   = (const float*)d_in[12];
  const float* cgw2   = (const float*)d_in[13];
  const float* rprojw = (const float*)d_in[14];
  const float* rprojb = (const float*)d_in[15];
  const float* para1  = (const float*)d_in[16];
  const float* para2  = (const float*)d_in[17];
  float* D = (float*)d_out;

  // pick largest batch-group size whose footprint fits: 3 big units + pool
  int nb = 8;
  for (;;){
    size_t unit = (size_t)nb*64*HW_;
    size_t pool = (size_t)nb*3*HW_            // Rbuf
                + (size_t)nb*512 + (size_t)nb*64 + 64
                + (size_t)nb*8*NCHUNK*80      // part
                + (size_t)nb*8*80             // stats
                + (size_t)nb*64*64            // M
                + 3*(size_t)nb*HW_            // mxmap, mnmap, swb
                + (size_t)nb*256*128          // spart
                + 3*(size_t)nb*64;            // lmean, lmax, cwb
    if ((3*unit + pool)*sizeof(float) <= ws_size || nb==1) break;
    nb >>= 1;
  }

  size_t unit = (size_t)nb*64*HW_;
  float* U0 = (float*)d_ws;
  float* U1 = U0 + unit;
  float* U2 = U1 + unit;
  float* sm = U2 + unit;
  float* Rbuf  = sm;  sm += (size_t)nb*3*HW_;
  float* coeff = sm;  sm += (size_t)nb*512;
  float* pooled= sm;  sm += (size_t)nb*64;
  float* flagb = sm;  sm += 64;
  float* part  = sm;  sm += (size_t)nb*8*NCHUNK*80;
  float* stats = sm;  sm += (size_t)nb*8*80;
  float* Mb    = sm;  sm += (size_t)nb*64*64;
  float* mxmap = sm;  sm += (size_t)nb*HW_;
  float* mnmap = sm;  sm += (size_t)nb*HW_;
  float* swb   = sm;  sm += (size_t)nb*HW_;
  float* spart = sm;  sm += (size_t)nb*256*128;
  float* lmean = sm;  sm += (size_t)nb*64;
  float* lmax  = sm;  sm += (size_t)nb*64;
  float* cwb   = sm;  sm += (size_t)nb*64;

  for (int b0 = 0; b0 < 8; b0 += nb){
    const float* yg = y + (i64)b0*64*HW_;
    float*       Dg = D + (i64)b0*64*HW_;
    __bf16* U0b = (__bf16*)U0;
    __bf16* U1b = (__bf16*)U1;
    __bf16* U2b = (__bf16*)U2;
    __bf16* Dgb = (__bf16*)Dg;

    // frontend
    k_resize <<<nb*3*256, 256,0,stream>>>(x, Rbuf, b0);
    k_conv3  <<<nb*256,   256,0,stream>>>(Rbuf, conv1w, U0);           // xc = U0 (fp32)
    k_dft    <<<nb*64,    256,0,stream>>>(U0, coeff, pooled);
    k_thr    <<<nb,       64, 0,stream>>>(pooled, ratew1, ratew2, flagb);

    // cca0 (a = high, from xc)
    k_mm_convq<0><<<nb*256,256,0,stream>>>(U0, coeff, flagb, qw + 0*4096, U1b);   // qpre=U1 (bf16)
    k_mm_kv<0><<<nb*256,256,0,stream>>>(yg, kvw + 0*8192, U2b, Dgb);              // kpre=U2, vpre=Dg (bf16)
    k_gram   <<<nb*8*NCHUNK,256,0,stream>>>(U1b, U2b, qdw + 0*576, kvdw + 0*1152, part);
    k_stats_fin<<<nb*8,  128,0,stream>>>(part, stats);
    k_dwb    <<<nb*128,256,0,stream>>>(Dgb, kvdw + 0*1152 + 576, U1b);            // v=U1 (bf16)
    k_attn_m  <<<nb,     64, 0,stream>>>(stats, temp + 0*8, projw + 0*4096, Mb);
    k_mm_hi  <<<nb*256, 256,0,stream>>>(U1b, Mb, mxmap, mnmap, U2b);              // high2=U2 (bf16)

    // cca1 (a = low, from xc)  [xc dead after this conv]
    k_mm_convq<1><<<nb*256,256,0,stream>>>(U0, coeff, flagb, qw + 1*4096, U1b);   // qpre=U1
    k_mm_kv<0><<<nb*256,256,0,stream>>>(yg, kvw + 1*8192, U0b, Dgb);              // kpre=U0, vpre=Dg
    k_gram   <<<nb*8*NCHUNK,256,0,stream>>>(U1b, U0b, qdw + 1*576, kvdw + 1*1152, part);
    k_stats_fin<<<nb*8,  128,0,stream>>>(part, stats);
    k_dwb    <<<nb*128,256,0,stream>>>(Dgb, kvdw + 1*1152 + 576, U1b);            // v=U1
    k_attn_m  <<<nb,     64, 0,stream>>>(stats, temp + 1*8, projw + 1*4096, Mb);
    k_mm_lo  <<<nb*256, 256,0,stream>>>(U1b, Mb, Dgb, spart);                     // low2=Dg (bf16)

    // refine: high2=U2, low2=Dg -> agg=U0 (bf16)
    k_spatfin <<<nb,     64, 0,stream>>>(spart, lmean, lmax);
    k_cw      <<<nb,     64, 0,stream>>>(lmean, lmax, cgw1, cgw2, cwb);
    k_sw      <<<nb*256, 256,0,stream>>>(mxmap, mnmap, spw, swb);
    k_mm_comb<<<nb*256,256,0,stream>>>(Dgb, U2b, swb, cwb, rprojw, rprojb, U0b);  // agg=U0

    // cca2 (q from y, kv from agg=U0)
    k_mm_64  <<<nb*256,256,0,stream>>>(yg, qw + 2*4096, U1b);                     // qpre=U1
    k_mm_kv<1><<<nb*256,256,0,stream>>>(U0b, kvw + 2*8192, U2b, Dgb);             // kpre=U2, vpre=Dg
    k_gram   <<<nb*8*NCHUNK,256,0,stream>>>(U1b, U2b, qdw + 2*576, kvdw + 2*1152, part);
    k_stats_fin<<<nb*8,  128,0,stream>>>(part, stats);
    k_dwb    <<<nb*128,256,0,stream>>>(Dgb, kvdw + 2*1152 + 576, U1b);            // v=U1
    k_attn_m  <<<nb,     64, 0,stream>>>(stats, temp + 2*8, projw + 2*4096, Mb);
    k_mm_fin <<<nb*256,256,0,stream>>>(U1b, Mb, para1, para2, yg, Dg);            // out fp32
  }
}

// Round 7
// 957.701 us; speedup vs baseline: 5.5220x; 1.1602x over previous
//
#include <hip/hip_runtime.h>
#include <math.h>

#define HW_ 65536
#define NCHUNK 16
typedef long long i64;
#define TWO_PI 6.283185307179586476925f

typedef __bf16 bf16x8 __attribute__((ext_vector_type(8)));
typedef __bf16 bf16x4 __attribute__((ext_vector_type(4)));
typedef float f32x4 __attribute__((ext_vector_type(4)));

#define MFMA16(A,B,C) __builtin_amdgcn_mfma_f32_16x16x32_bf16(A,B,C,0,0,0)

__device__ __forceinline__ float sigm(float x){ return 1.0f/(1.0f+expf(-x)); }

// convert 8 consecutive fp32 to a bf16x8 A-fragment
__device__ __forceinline__ bf16x8 cvt_w8(const float* wp){
  float4 w0 = *(const float4*)wp;
  float4 w1 = *(const float4*)(wp+4);
  bf16x8 r;
  r[0]=(__bf16)w0.x; r[1]=(__bf16)w0.y; r[2]=(__bf16)w0.z; r[3]=(__bf16)w0.w;
  r[4]=(__bf16)w1.x; r[5]=(__bf16)w1.y; r[6]=(__bf16)w1.z; r[7]=(__bf16)w1.w;
  return r;
}

__device__ __forceinline__ void st_bf4(__bf16* p, float a, float b, float c, float d){
  bf16x4 v; v[0]=(__bf16)a; v[1]=(__bf16)b; v[2]=(__bf16)c; v[3]=(__bf16)d;
  *(bf16x4*)p = v;
}

// ---------------- resize (nb,3,128,128) -> (nb,3,256,256) bilinear half-pixel ----------------
__global__ __launch_bounds__(256) void k_resize(const float* __restrict__ x, float* __restrict__ R, int b0){
  int idx = blockIdx.x*256 + threadIdx.x;
  int ox = idx & 255;
  int oy = (idx >> 8) & 255;
  int bc = idx >> 16;                               // lb*3 + c
  int lb = bc/3; int c = bc - lb*3;
  float sx = ox*0.5f - 0.25f;
  float sy = oy*0.5f - 0.25f;
  int x0 = (int)floorf(sx); float fx = sx - (float)x0;
  int y0 = (int)floorf(sy); float fy = sy - (float)y0;
  int x1 = min(x0+1,127); int y1 = min(y0+1,127);
  x0 = max(x0,0); y0 = max(y0,0);
  const float* p = x + ((i64)(b0+lb)*3 + c)*16384;
  float v00=p[y0*128+x0], v01=p[y0*128+x1], v10=p[y1*128+x0], v11=p[y1*128+x1];
  R[idx] = (1.0f-fy)*((1.0f-fx)*v00 + fx*v01) + fy*((1.0f-fx)*v10 + fx*v11);
}

// ---------------- conv3x3 3->64: block per (b,row), all 64 outs per thread ----------------
__global__ __launch_bounds__(256) void k_conv3(const float* __restrict__ R, const float* __restrict__ w, float* __restrict__ out){
  int y = blockIdx.x & 255; int b = blockIdx.x >> 8; int t = threadIdx.x;
  float win[27];
  #pragma unroll
  for (int ci=0;ci<3;ci++){
    #pragma unroll
    for (int ky=0;ky<3;ky++){
      int yy = y+ky-1;
      const float* ip = R + (((i64)(b*3+ci))<<16) + yy*256;
      #pragma unroll
      for (int kx=0;kx<3;kx++){
        int xx = t+kx-1;
        float v = 0.f;
        if ((unsigned)yy<256u && (unsigned)xx<256u) v = ip[xx];
        win[ci*9+ky*3+kx] = v;
      }
    }
  }
  i64 obase = ((i64)b<<22) + (y<<8) + t;
  for (int o=0;o<64;o++){
    const float* wp = w + o*27;
    float acc=0.f;
    #pragma unroll
    for (int j=0;j<27;j++) acc += wp[j]*win[j];
    out[obase + ((i64)o<<16)] = acc;
  }
}

// ---------------- DFT coeffs (7 reals incl. DC) + pooled mean per (b,c) ----------------
__global__ __launch_bounds__(256) void k_dft(const float* __restrict__ xc, float* __restrict__ coeff, float* __restrict__ pooled){
  __shared__ float tc[256], ts[256];
  __shared__ float red[256];
  int t = threadIdx.x;
  float ang = TWO_PI * ((float)t/256.0f);
  tc[t] = cosf(ang); ts[t] = sinf(ang);
  __syncthreads();
  int bc = blockIdx.x;
  const float* p = xc + (i64)bc*HW_;
  float s=0, cr=0, ci=0, rr=0, ri=0, dr=0, di=0;
  for (int i=t; i<HW_; i+=256){
    float v = p[i];
    int col = i & 255, row = i >> 8, ds = (row+col)&255;
    s  += v;
    cr += v*tc[col]; ci += v*ts[col];
    rr += v*tc[row]; ri += v*ts[row];
    dr += v*tc[ds];  di += v*ts[ds];
  }
  float vals[7] = {s,cr,ci,rr,ri,dr,di};
  for (int j=0;j<7;j++){
    red[t] = vals[j]; __syncthreads();
    for (int st=128; st>0; st>>=1){ if (t<st) red[t]+=red[t+st]; __syncthreads(); }
    if (t==0) vals[j] = red[0];
    __syncthreads();
  }
  if (t==0){
    const float sc = 1.0f/65536.0f;
    for (int j=0;j<7;j++) coeff[bc*8+j] = vals[j]*sc;
    pooled[bc] = vals[0]*sc;
  }
}

// ---------------- threshold MLP -> per-batch mask flag ----------------
__global__ __launch_bounds__(64) void k_thr(const float* __restrict__ pooled, const float* __restrict__ w1,
                      const float* __restrict__ w2, float* __restrict__ flag){
  __shared__ float hid[8];
  int b = blockIdx.x; int t = threadIdx.x;
  if (t < 8){
    float a = 0.f;
    for (int c=0;c<64;c++) a += pooled[b*64+c]*w1[t*64+c];
    hid[t] = 0.5f*a*(1.0f+erff(a*0.70710678118654752440f));
  }
  __syncthreads();
  if (t==0){
    float t0=0,t1=0;
    for (int k=0;k<8;k++){ t0 += hid[k]*w2[k]; t1 += hid[k]*w2[8+k]; }
    int h_ = (int)(2.0f*sigm(t0));
    int w_ = (int)(2.0f*sigm(t1));
    flag[b] = (h_>0 && w_>0) ? 1.0f : 0.0f;
  }
}

// =====================================================================================
// MFMA pixel-matmul family: per wave, one 64px x 64out strip.
// A-frag (weights, row-major [O][64] fp32): lane holds row = m*16+(lane&15),
//   k = s*32 + (lane>>4)*8 + j.  B-frag: col = lane&15 -> px = p0 + 4*(lane&15) + e.
// C/D: col(px)=lane&15, row(out)=(lane>>4)*4+reg  [verified m89 layout].
// Intermediates stored bf16 (consumed as bf16 B-fragments anyway).
// =====================================================================================

#define MM_FILL_B_F32(in_ptr) \
  _Pragma("unroll") \
  for (int s=0;s<2;s++){ \
    _Pragma("unroll") \
    for (int j=0;j<8;j++){ \
      float4 q = *(const float4*)((in_ptr) + ((i64)(s*32 + kg*8 + j)<<16) + 4*lm); \
      bf[s][0][j]=(__bf16)q.x; bf[s][1][j]=(__bf16)q.y; \
      bf[s][2][j]=(__bf16)q.z; bf[s][3][j]=(__bf16)q.w; \
    } \
  }

#define MM_FILL_B_BF(in_ptr) \
  _Pragma("unroll") \
  for (int s=0;s<2;s++){ \
    _Pragma("unroll") \
    for (int j=0;j<8;j++){ \
      bf16x4 u = *(const bf16x4*)((in_ptr) + ((i64)(s*32 + kg*8 + j)<<16) + 4*lm); \
      bf[s][0][j]=u[0]; bf[s][1][j]=u[1]; bf[s][2][j]=u[2]; bf[s][3][j]=u[3]; \
    } \
  }

// compute from fragment array BF (scoped: declares af, acc)
#define MM_COMPUTE2(Wbase, BF) \
  bf16x8 af[4][2]; \
  _Pragma("unroll") \
  for (int m=0;m<4;m++){ \
    _Pragma("unroll") \
    for (int s=0;s<2;s++) af[m][s] = cvt_w8((Wbase) + (m*16 + lm)*64 + s*32 + kg*8); \
  } \
  f32x4 acc[4][4]; \
  _Pragma("unroll") \
  for (int m=0;m<4;m++){ \
    _Pragma("unroll") \
    for (int e=0;e<4;e++){ f32x4 z = {0.f,0.f,0.f,0.f}; acc[m][e]=z; } \
  } \
  _Pragma("unroll") \
  for (int m=0;m<4;m++){ \
    _Pragma("unroll") \
    for (int e=0;e<4;e++){ \
      _Pragma("unroll") \
      for (int s=0;s<2;s++) acc[m][e] = MFMA16(af[m][s], BF[s][e], acc[m][e]); \
    } \
  }

#define MM_COMPUTE(Wbase) MM_COMPUTE2(Wbase, bf)

#define MM_STORE_BF(outp) \
  _Pragma("unroll") \
  for (int m=0;m<4;m++){ \
    _Pragma("unroll") \
    for (int r=0;r<4;r++){ \
      int oc = m*16 + kg*4 + r; \
      st_bf4((outp) + ibase + ((i64)oc<<16) + 4*lm, acc[m][0][r], acc[m][1][r], acc[m][2][r], acc[m][3][r]); \
    } \
  }

#define MM_SETUP \
  int t = threadIdx.x; \
  int lane = t & 63, wvi = t >> 6; \
  i64 px0 = (i64)blockIdx.x*256 + wvi*64; \
  int b = (int)(px0 >> 16); \
  int p0 = (int)(px0 & (HW_-1)); \
  i64 ibase = ((i64)b<<22) + p0; \
  int lm = lane & 15, kg = lane >> 4;

// ---------------- fused: DFT recon (shared) -> BOTH high & low conv1x1, MFMA, bf16 out ----------------
__global__ __launch_bounds__(256) void k_convq2(const float* __restrict__ xc, const float* __restrict__ coeff,
      const float* __restrict__ flag, const float* __restrict__ qwh, const float* __restrict__ qwl,
      __bf16* __restrict__ outh, __bf16* __restrict__ outl){
  __shared__ float tc[256], ts[256];
  {
    int tt = threadIdx.x;
    float ang = TWO_PI * ((float)tt/256.0f);
    tc[tt]=cosf(ang); ts[tt]=sinf(ang);
  }
  __syncthreads();
  MM_SETUP
  float fl = flag[b];
  int y = p0 >> 8;
  int xb = (p0 & 255) + 4*lm;
  float crow = tc[y], srow = ts[y];
  float cx[4], sx[4], cd[4], sd[4];
  #pragma unroll
  for (int e=0;e<4;e++){
    int xx = xb + e;
    cx[e]=tc[xx]; sx[e]=ts[xx];
    int d = (xx + y) & 255;
    cd[e]=tc[d]; sd[e]=ts[d];
  }
  bf16x8 bfh[2][4], bfl[2][4];
  #pragma unroll
  for (int s=0;s<2;s++){
    #pragma unroll
    for (int j=0;j<8;j++){
      int ch = s*32 + kg*8 + j;
      const float* cf = coeff + ((b<<6)+ch)*8;
      float4 ca = *(const float4*)cf;
      float4 cb = *(const float4*)(cf+4);
      float F00=ca.x, cR=ca.y, cI=ca.z, rR=ca.w, rI=cb.x, dR=cb.y, dI=cb.z;
      float4 xr = *(const float4*)(xc + ibase + ((i64)ch<<16) + 4*lm);
      float rowR = F00 + rR*crow + rI*srow;
      float rowI = rI*crow - rR*srow;
      #pragma unroll
      for (int e=0;e<4;e++){
        float re = rowR + cR*cx[e] + cI*sx[e] + dR*cd[e] + dI*sd[e];
        float im = rowI + cI*cx[e] - cR*sx[e] + dI*cd[e] - dR*sd[e];
        re*=fl; im*=fl;
        float vl = sqrtf(re*re+im*im);
        float hr = ((const float*)&xr)[e] - re;
        float vh = sqrtf(hr*hr + im*im);
        bfh[s][e][j] = (__bf16)vh;
        bfl[s][e][j] = (__bf16)vl;
      }
    }
  }
  {
    MM_COMPUTE2(qwh, bfh)
    MM_STORE_BF(outh)
  }
  {
    MM_COMPUTE2(qwl, bfl)
    MM_STORE_BF(outl)
  }
}

// ---------------- fused conv1x1 from y: kv0 (128), kv1 (128), q2 (64) -- one y read ----------------
__global__ __launch_bounds__(256) void k_kvq(const float* __restrict__ yin,
      const float* __restrict__ kvw0, const float* __restrict__ kvw1, const float* __restrict__ qw2,
      __bf16* __restrict__ k0o, __bf16* __restrict__ v0o,
      __bf16* __restrict__ k1o, __bf16* __restrict__ v1o, __bf16* __restrict__ q2o){
  MM_SETUP
  bf16x8 bf[2][4];
  MM_FILL_B_F32(yin + ibase)
  { MM_COMPUTE(kvw0)        MM_STORE_BF(k0o) }
  { MM_COMPUTE(kvw0 + 4096) MM_STORE_BF(v0o) }
  { MM_COMPUTE(kvw1)        MM_STORE_BF(k1o) }
  { MM_COMPUTE(kvw1 + 4096) MM_STORE_BF(v1o) }
  { MM_COMPUTE(qw2)         MM_STORE_BF(q2o) }
}

// ---------------- conv1x1 64->128 (k and v), bf16 in, MFMA, bf16 out (cca2 only) ----------------
__global__ __launch_bounds__(256) void k_mm_kvb(const __bf16* __restrict__ in, const float* __restrict__ w,
      __bf16* __restrict__ kout, __bf16* __restrict__ vout){
  MM_SETUP
  bf16x8 bf[2][4];
  MM_FILL_B_BF(in + ibase)
  { MM_COMPUTE(w)        MM_STORE_BF(kout) }
  { MM_COMPUTE(w + 4096) MM_STORE_BF(vout) }
}

// ---------------- mconv high: M x v + per-px channel max/mean (fp32 stats from acc) ----------------
__global__ __launch_bounds__(256) void k_mm_hi(const __bf16* __restrict__ v, const float* __restrict__ M,
        float* __restrict__ mx, float* __restrict__ mn, __bf16* __restrict__ out){
  MM_SETUP
  bf16x8 bf[2][4];
  MM_FILL_B_BF(v + ibase)
  const float* Wb = M + ((i64)b<<12);
  MM_COMPUTE(Wb)
  float pmx[4] = {-1e30f,-1e30f,-1e30f,-1e30f};
  float ps[4]  = {0.f,0.f,0.f,0.f};
  #pragma unroll
  for (int m=0;m<4;m++){
    #pragma unroll
    for (int r=0;r<4;r++){
      int oc = m*16 + kg*4 + r;
      float ax=acc[m][0][r], ay=acc[m][1][r], az=acc[m][2][r], aw=acc[m][3][r];
      st_bf4(out + ibase + ((i64)oc<<16) + 4*lm, ax, ay, az, aw);
      pmx[0]=fmaxf(pmx[0],ax); ps[0]+=ax;
      pmx[1]=fmaxf(pmx[1],ay); ps[1]+=ay;
      pmx[2]=fmaxf(pmx[2],az); ps[2]+=az;
      pmx[3]=fmaxf(pmx[3],aw); ps[3]+=aw;
    }
  }
  #pragma unroll
  for (int e=0;e<4;e++){
    pmx[e] = fmaxf(pmx[e], __shfl_xor(pmx[e],16));
    pmx[e] = fmaxf(pmx[e], __shfl_xor(pmx[e],32));
    ps[e] += __shfl_xor(ps[e],16);
    ps[e] += __shfl_xor(ps[e],32);
  }
  if (kg==0){
    i64 pbase = ((i64)b<<16) + p0 + 4*lm;
    *(float4*)(mx+pbase) = make_float4(pmx[0],pmx[1],pmx[2],pmx[3]);
    *(float4*)(mn+pbase) = make_float4(ps[0]*(1.0f/64.0f),ps[1]*(1.0f/64.0f),
                                       ps[2]*(1.0f/64.0f),ps[3]*(1.0f/64.0f));
  }
}

// ---------------- mconv low: M x v + per-channel sum/max partials (fp32 from acc) ----------------
__global__ __launch_bounds__(256) void k_mm_lo(const __bf16* __restrict__ v, const float* __restrict__ M,
        __bf16* __restrict__ out, float* __restrict__ spart){
  __shared__ float ls[4][64], lmx[4][64];
  MM_SETUP
  bf16x8 bf[2][4];
  MM_FILL_B_BF(v + ibase)
  const float* Wb = M + ((i64)b<<12);
  MM_COMPUTE(Wb)
  #pragma unroll
  for (int m=0;m<4;m++){
    #pragma unroll
    for (int r=0;r<4;r++){
      int oc = m*16 + kg*4 + r;
      float ax=acc[m][0][r], ay=acc[m][1][r], az=acc[m][2][r], aw=acc[m][3][r];
      st_bf4(out + ibase + ((i64)oc<<16) + 4*lm, ax, ay, az, aw);
      float s = ax+ay+az+aw;
      float mm = fmaxf(fmaxf(ax,ay),fmaxf(az,aw));
      #pragma unroll
      for (int off=8; off; off>>=1){ s += __shfl_xor(s,off); mm = fmaxf(mm,__shfl_xor(mm,off)); }
      if (lm==0){ ls[wvi][oc]=s; lmx[wvi][oc]=mm; }
    }
  }
  __syncthreads();
  if (t<64){
    float s = ls[0][t]+ls[1][t]+ls[2][t]+ls[3][t];
    float mm = fmaxf(fmaxf(lmx[0][t],lmx[1][t]),fmaxf(lmx[2][t],lmx[3][t]));
    spart[(i64)blockIdx.x*128 + t*2]   = s;
    spart[(i64)blockIdx.x*128 + t*2+1] = mm;
  }
}

// ---------------- fused comb + refine conv1x1 (bf16 in/out), MFMA ----------------
__global__ __launch_bounds__(256) void k_mm_comb(const __bf16* __restrict__ lo2, const __bf16* __restrict__ hi2,
        const float* __restrict__ swb, const float* __restrict__ cwv,
        const float* __restrict__ w, const float* __restrict__ bias, __bf16* __restrict__ out){
  MM_SETUP
  float4 sw4 = *(const float4*)(swb + ((i64)b<<16) + p0 + 4*lm);
  bf16x8 bf[2][4];
  #pragma unroll
  for (int s=0;s<2;s++){
    #pragma unroll
    for (int j=0;j<8;j++){
      int ch = s*32 + kg*8 + j;
      bf16x4 l4 = *(const bf16x4*)(lo2 + ibase + ((i64)ch<<16) + 4*lm);
      bf16x4 h4 = *(const bf16x4*)(hi2 + ibase + ((i64)ch<<16) + 4*lm);
      float cw = cwv[(b<<6) + ch];
      bf[s][0][j]=(__bf16)((float)l4[0]*sw4.x + (float)h4[0]*cw);
      bf[s][1][j]=(__bf16)((float)l4[1]*sw4.y + (float)h4[1]*cw);
      bf[s][2][j]=(__bf16)((float)l4[2]*sw4.z + (float)h4[2]*cw);
      bf[s][3][j]=(__bf16)((float)l4[3]*sw4.w + (float)h4[3]*cw);
    }
  }
  MM_COMPUTE(w)
  #pragma unroll
  for (int m=0;m<4;m++){
    #pragma unroll
    for (int r=0;r<4;r++){
      int oc = m*16 + kg*4 + r;
      float bv = bias[oc];
      st_bf4(out + ibase + ((i64)oc<<16) + 4*lm, acc[m][0][r]+bv, acc[m][1][r]+bv, acc[m][2][r]+bv, acc[m][3][r]+bv);
    }
  }
}

// ---------------- final mconv: M x v, *para1 + y*para2 (fp32 out) ----------------
__global__ __launch_bounds__(256) void k_mm_fin(const __bf16* __restrict__ v, const float* __restrict__ M,
      const float* __restrict__ para1, const float* __restrict__ para2,
      const float* __restrict__ yin, float* __restrict__ out){
  MM_SETUP
  bf16x8 bf[2][4];
  MM_FILL_B_BF(v + ibase)
  const float* Wb = M + ((i64)b<<12);
  MM_COMPUTE(Wb)
  #pragma unroll
  for (int m=0;m<4;m++){
    #pragma unroll
    for (int r=0;r<4;r++){
      int oc = m*16 + kg*4 + r;
      float p1 = para1[oc], p2 = para2[oc];
      float4 yv = *(const float4*)(yin + ibase + ((i64)oc<<16) + 4*lm);
      float4 st = make_float4(acc[m][0][r]*p1 + yv.x*p2,
                              acc[m][1][r]*p1 + yv.y*p2,
                              acc[m][2][r]*p1 + yv.z*p2,
                              acc[m][3][r]*p1 + yv.w*p2);
      *(float4*)(out + ibase + ((i64)oc<<16) + 4*lm) = st;
    }
  }
}

// ---------------- Gram-MFMA stats (bf16 inputs): dw3x3(q)&dw3x3(k) -> 16x16 Gram ----------------
__global__ __launch_bounds__(256) void k_gram(const __bf16* __restrict__ qpre, const __bf16* __restrict__ kpre,
        const float* __restrict__ qdw, const float* __restrict__ kdw, float* __restrict__ part){
  __shared__ float red[4][16][16];
  int blk = blockIdx.x;                 // bh*16 + rowblk
  int rowblk = blk & 15;
  int bh = blk >> 4;
  int h = bh & 7, b = bh >> 3;
  int t = threadIdx.x;
  int lane = t & 63, wvi = t >> 6;
  int lm = lane & 15, kg = lane >> 4;
  int a = lm & 7;
  const __bf16* plane = (lm < 8 ? qpre : kpre) + (((i64)((b<<6)+(h<<3)+a))<<16);
  const float* wp = (lm < 8 ? qdw : kdw) + h*72 + a*9;
  float w0=wp[0],w1=wp[1],w2=wp[2],w3=wp[3],w4=wp[4],w5=wp[5],w6=wp[6],w7=wp[7],w8=wp[8];
  int R0 = rowblk*16;
  f32x4 acc = {0.f,0.f,0.f,0.f};
  #pragma unroll
  for (int cc=0; cc<2; cc++){
    int chunk = wvi*2 + cc;
    int xb = chunk*32 + kg*8;
    bool left = (xb==0), right = (xb==248);
    float h0[8], h1[8];
    #pragma unroll
    for (int e=0;e<8;e++){ h0[e]=0.f; h1[e]=0.f; }
    for (int ir = R0-1; ir <= R0+16; ir++){
      bool rok = ((unsigned)ir < 256u);
      float win[10];
      if (rok){
        const __bf16* rp = plane + ir*256 + xb;
        bf16x8 mid = *(const bf16x8*)rp;
        win[0] = left ? 0.f : (float)rp[-1];
        #pragma unroll
        for (int w=1; w<9; w++) win[w] = (float)mid[w-1];
        win[9] = right ? 0.f : (float)rp[8];
      } else {
        #pragma unroll
        for (int w=0; w<10; w++) win[w] = 0.f;
      }
      float o[8];
      #pragma unroll
      for (int e=0;e<8;e++){
        float t0 = w0*win[e] + w1*win[e+1] + w2*win[e+2];
        float t1 = w3*win[e] + w4*win[e+1] + w5*win[e+2];
        float t2 = w6*win[e] + w7*win[e+1] + w8*win[e+2];
        o[e] = h0[e] + t2;
        h0[e] = h1[e] + t1;
        h1[e] = t0;
      }
      if (ir > R0){
        bf16x8 xf;
        #pragma unroll
        for (int e=0;e<8;e++) xf[e] = (__bf16)o[e];
        acc = MFMA16(xf, xf, acc);
      }
    }
  }
  #pragma unroll
  for (int r=0;r<4;r++) red[wvi][kg*4+r][lm] = acc[r];
  __syncthreads();
  if (t < 80){
    int r, c;
    if (t < 64){ r = t>>3; c = 8 + (t&7); }
    else if (t < 72){ r = t-64; c = r; }
    else { r = 8 + (t-72); c = r; }
    float s = red[0][r][c]+red[1][r][c]+red[2][r][c]+red[3][r][c];
    part[(i64)blk*80 + t] = s;
  }
}

__global__ __launch_bounds__(128) void k_stats_fin(const float* __restrict__ part, float* __restrict__ stats){
  int bh = blockIdx.x; int t = threadIdx.x;
  if (t < 80){
    float s=0.f;
    for (int c=0;c<NCHUNK;c++) s += part[((i64)bh*NCHUNK+c)*80 + t];
    stats[bh*80+t] = s;
  }
}

// ---------------- softmax + fold attn into per-batch 64x64 M ----------------
__global__ __launch_bounds__(64) void k_attn_m(const float* __restrict__ stats, const float* __restrict__ temp,
                         const float* __restrict__ projw, float* __restrict__ M){
  __shared__ float attn[8][8][8];
  int b = blockIdx.x; int t = threadIdx.x;
  int h = t >> 3, cc = t & 7;
  const float* st = stats + (b*8+h)*80;
  float nq = fmaxf(sqrtf(st[64+cc]), 1e-12f);
  float tmp = temp[h];
  float s[8];
  float mx = -1e30f;
  #pragma unroll
  for (int d=0;d<8;d++){
    float nk = fmaxf(sqrtf(st[72+d]), 1e-12f);
    s[d] = st[cc*8+d]/(nq*nk)*tmp;
    mx = fmaxf(mx, s[d]);
  }
  float sum=0.f;
  #pragma unroll
  for (int d=0;d<8;d++){ s[d]=expf(s[d]-mx); sum+=s[d]; }
  float inv = 1.0f/sum;
  #pragma unroll
  for (int d=0;d<8;d++) attn[h][cc][d] = s[d]*inv;
  __syncthreads();
  int o = t;
  for (int hh=0; hh<8; hh++){
    #pragma unroll
    for (int d=0; d<8; d++){
      float acc=0.f;
      #pragma unroll
      for (int c2=0;c2<8;c2++) acc += projw[o*64 + hh*8 + c2]*attn[hh][c2][d];
      M[((i64)b*64 + o)*64 + hh*8 + d] = acc;
    }
  }
}

// ---------------- depthwise 3x3 (v path), bf16 in/out, rolling 16-row slabs, 8px/thread ----------------
__global__ __launch_bounds__(256) void k_dwb(const __bf16* __restrict__ in, const float* __restrict__ wd,
                                             __bf16* __restrict__ out){
  int blk = blockIdx.x;              // b*128 + c*2 + half
  int half = blk & 1; int c = (blk>>1)&63; int b = blk>>7;
  int t = threadIdx.x;
  int strip = t & 31, rg = t >> 5;
  const __bf16* ip = in + (((i64)((b<<6)+c))<<16);
  __bf16* op = out + (((i64)((b<<6)+c))<<16);
  const float* wp = wd + c*9;
  float w0=wp[0],w1=wp[1],w2=wp[2],w3=wp[3],w4=wp[4],w5=wp[5],w6=wp[6],w7=wp[7],w8=wp[8];
  int R0 = half*128 + rg*16;
  int xb = strip*8;
  bool left = (xb==0), right = (xb==248);
  float h0[8], h1[8];
  #pragma unroll
  for (int e=0;e<8;e++){ h0[e]=0.f; h1[e]=0.f; }
  for (int ir = R0-1; ir <= R0+16; ir++){
    bool rok = ((unsigned)ir < 256u);
    float win[10];
    if (rok){
      const __bf16* rp = ip + ir*256 + xb;
      bf16x8 mid = *(const bf16x8*)rp;
      win[0] = left ? 0.f : (float)rp[-1];
      #pragma unroll
      for (int w=1; w<9; w++) win[w] = (float)mid[w-1];
      win[9] = right ? 0.f : (float)rp[8];
    } else {
      #pragma unroll
      for (int w=0; w<10; w++) win[w] = 0.f;
    }
    float o[8];
    #pragma unroll
    for (int e=0;e<8;e++){
      float t0 = w0*win[e] + w1*win[e+1] + w2*win[e+2];
      float t1 = w3*win[e] + w4*win[e+1] + w5*win[e+2];
      float t2 = w6*win[e] + w7*win[e+1] + w8*win[e+2];
      o[e] = h0[e] + t2;
      h0[e] = h1[e] + t1;
      h1[e] = t0;
    }
    if (ir > R0){
      bf16x8 ov;
      #pragma unroll
      for (int e=0;e<8;e++) ov[e] = (__bf16)o[e];
      *(bf16x8*)(op + (ir-1)*256 + xb) = ov;
    }
  }
}

// ---------------- refine small kernels ----------------
__global__ __launch_bounds__(64) void k_spatfin(const float* __restrict__ spart, float* __restrict__ lmean, float* __restrict__ lmax){
  int b = blockIdx.x; int c = threadIdx.x;
  float s=0.f, m=-1e30f;
  for (int r=0;r<256;r++){
    s += spart[(i64)(b*256+r)*128 + c*2];
    m = fmaxf(m, spart[(i64)(b*256+r)*128 + c*2+1]);
  }
  lmean[b*64+c] = s*(1.0f/65536.0f);
  lmax[b*64+c]  = m;
}

__global__ __launch_bounds__(64) void k_cw(const float* __restrict__ mean, const float* __restrict__ mxv,
                     const float* __restrict__ w1, const float* __restrict__ w2, float* __restrict__ cw){
  __shared__ float ha[4], hm[4];
  int b = blockIdx.x; int t = threadIdx.x;
  if (t < 4){
    float sa=0.f, sm_=0.f;
    for (int c=0;c<64;c++){ sa += w1[t*64+c]*mean[b*64+c]; sm_ += w1[t*64+c]*mxv[b*64+c]; }
    ha[t] = fmaxf(sa, 0.f); hm[t] = fmaxf(sm_, 0.f);
  }
  __syncthreads();
  float a=0.f;
  #pragma unroll
  for (int j=0;j<4;j++) a += w2[t*4+j]*(ha[j]+hm[j]);
  cw[b*64+t] = sigm(a);
}

__global__ __launch_bounds__(256) void k_sw(const float* __restrict__ mx, const float* __restrict__ mn,
                     const float* __restrict__ w, float* __restrict__ sw){
  int row = blockIdx.x & 255; int b = blockIdx.x >> 8; int t = threadIdx.x;
  const float* m0 = mx + ((i64)b<<16);
  const float* m1 = mn + ((i64)b<<16);
  float acc=0.f;
  for (int ky=0;ky<7;ky++){
    int yy = row+ky-3; if ((unsigned)yy>255u) continue;
    for (int kx=0;kx<7;kx++){
      int xx = t+kx-3; if ((unsigned)xx>255u) continue;
      acc += w[ky*7+kx]*m0[yy*256+xx] + w[49+ky*7+kx]*m1[yy*256+xx];
    }
  }
  sw[((i64)b<<16) + row*256 + t] = sigm(acc);
}

// =====================================================================================
extern "C" void kernel_launch(void* const* d_in, const int* in_sizes, int n_in,
                              void* d_out, int out_size, void* d_ws, size_t ws_size,
                              hipStream_t stream){
  const float* x      = (const float*)d_in[0];
  const float* y      = (const float*)d_in[1];
  const float* conv1w = (const float*)d_in[2];
  const float* ratew1 = (const float*)d_in[3];
  const float* ratew2 = (const float*)d_in[4];
  const float* temp   = (const float*)d_in[5];
  const float* qw     = (const float*)d_in[6];
  const float* qdw    = (const float*)d_in[7];
  const float* kvw    = (const float*)d_in[8];
  const float* kvdw   = (const float*)d_in[9];
  const float* projw  = (const float*)d_in[10];
  const float* spw    = (const float*)d_in[11];
  const float* cgw1   = (const float*)d_in[12];
  const float* cgw2   = (const float*)d_in[13];
  const float* rprojw = (const float*)d_in[14];
  const float* rprojb = (const float*)d_in[15];
  const float* para1  = (const float*)d_in[16];
  const float* para2  = (const float*)d_in[17];
  float* D = (float*)d_out;

  // pick largest batch-group size whose footprint fits: 3 big units + pool
  int nb = 8;
  for (;;){
    size_t unit = (size_t)nb*64*HW_;
    size_t pool = (size_t)nb*3*HW_            // Rbuf
                + (size_t)nb*512 + (size_t)nb*64 + 64
                + (size_t)nb*8*NCHUNK*80      // part
                + (size_t)nb*8*80             // stats
                + (size_t)nb*64*64            // M
                + 3*(size_t)nb*HW_            // mxmap, mnmap, swb
                + (size_t)nb*256*128          // spart
                + 3*(size_t)nb*64;            // lmean, lmax, cwb
    if ((3*unit + pool)*sizeof(float) <= ws_size || nb==1) break;
    nb >>= 1;
  }

  size_t unit = (size_t)nb*64*HW_;
  float* U0 = (float*)d_ws;
  float* U1 = U0 + unit;
  float* U2 = U1 + unit;
  float* sm = U2 + unit;
  float* Rbuf  = sm;  sm += (size_t)nb*3*HW_;
  float* coeff = sm;  sm += (size_t)nb*512;
  float* pooled= sm;  sm += (size_t)nb*64;
  float* flagb = sm;  sm += 64;
  float* part  = sm;  sm += (size_t)nb*8*NCHUNK*80;
  float* stats = sm;  sm += (size_t)nb*8*80;
  float* Mb    = sm;  sm += (size_t)nb*64*64;
  float* mxmap = sm;  sm += (size_t)nb*HW_;
  float* mnmap = sm;  sm += (size_t)nb*HW_;
  float* swb   = sm;  sm += (size_t)nb*HW_;
  float* spart = sm;  sm += (size_t)nb*256*128;
  float* lmean = sm;  sm += (size_t)nb*64;
  float* lmax  = sm;  sm += (size_t)nb*64;
  float* cwb   = sm;  sm += (size_t)nb*64;

  for (int b0 = 0; b0 < 8; b0 += nb){
    const float* yg = y + (i64)b0*64*HW_;
    float*       Dg = D + (i64)b0*64*HW_;
    // bf16 tensor slots: each fp32 unit region holds TWO bf16 tensors of `unit` elements.
    __bf16* U0a = (__bf16*)U0; __bf16* U0c = U0a + unit;
    __bf16* U1a = (__bf16*)U1; __bf16* U1c = U1a + unit;
    __bf16* U2a = (__bf16*)U2; __bf16* U2c = U2a + unit;
    __bf16* Dga = (__bf16*)Dg; __bf16* Dgc = Dga + unit;

    // frontend
    k_resize <<<nb*3*256, 256,0,stream>>>(x, Rbuf, b0);
    k_conv3  <<<nb*256,   256,0,stream>>>(Rbuf, conv1w, U0);           // xc = U0 (fp32, full region)
    k_dft    <<<nb*64,    256,0,stream>>>(U0, coeff, pooled);
    k_thr    <<<nb,       64, 0,stream>>>(pooled, ratew1, ratew2, flagb);

    // fused q-recon (both cca0-high and cca1-low q-pre); xc dead after
    k_convq2 <<<nb*256,256,0,stream>>>(U0, coeff, flagb, qw + 0*4096, qw + 1*4096, U1a, U1c); // qh=U1a, ql=U1c
    // fused y-matmuls: kv0, kv1, q2-pre (one read of y)
    k_kvq    <<<nb*256,256,0,stream>>>(yg, kvw + 0*8192, kvw + 1*8192, qw + 2*4096,
                                       U2a, Dga, U2c, Dgc, U0c);       // k0,v0,k1,v1,q2

    // cca0 (high)
    k_gram   <<<nb*8*NCHUNK,256,0,stream>>>(U1a, U2a, qdw + 0*576, kvdw + 0*1152, part);   // [qh,k0 dead]
    k_stats_fin<<<nb*8,  128,0,stream>>>(part, stats);
    k_dwb    <<<nb*128,256,0,stream>>>(Dga, kvdw + 0*1152 + 576, U0a);                     // v0'=U0a [v0 dead]
    k_attn_m  <<<nb,     64, 0,stream>>>(stats, temp + 0*8, projw + 0*4096, Mb);
    k_mm_hi  <<<nb*256, 256,0,stream>>>(U0a, Mb, mxmap, mnmap, U1a);                       // high2=U1a

    // cca1 (low)
    k_gram   <<<nb*8*NCHUNK,256,0,stream>>>(U1c, U2c, qdw + 1*576, kvdw + 1*1152, part);   // [ql,k1 dead]
    k_stats_fin<<<nb*8,  128,0,stream>>>(part, stats);
    k_dwb    <<<nb*128,256,0,stream>>>(Dgc, kvdw + 1*1152 + 576, U1c);                     // v1'=U1c [v1 dead]
    k_attn_m  <<<nb,     64, 0,stream>>>(stats, temp + 1*8, projw + 1*4096, Mb);
    k_mm_lo  <<<nb*256, 256,0,stream>>>(U1c, Mb, Dga, spart);                              // low2=Dga

    // refine: high2=U1a, low2=Dga -> agg=U2a
    k_spatfin <<<nb,     64, 0,stream>>>(spart, lmean, lmax);
    k_cw      <<<nb,     64, 0,stream>>>(lmean, lmax, cgw1, cgw2, cwb);
    k_sw      <<<nb*256, 256,0,stream>>>(mxmap, mnmap, spw, swb);
    k_mm_comb<<<nb*256,256,0,stream>>>(Dga, U1a, swb, cwb, rprojw, rprojb, U2a);           // agg=U2a

    // cca2 (q2 from y precomputed=U0c, kv from agg=U2a)
    k_mm_kvb <<<nb*256,256,0,stream>>>(U2a, kvw + 2*8192, U2c, Dga);                       // kpre=U2c, vpre=Dga
    k_gram   <<<nb*8*NCHUNK,256,0,stream>>>(U0c, U2c, qdw + 2*576, kvdw + 2*1152, part);   // [q2,kpre dead]
    k_stats_fin<<<nb*8,  128,0,stream>>>(part, stats);
    k_dwb    <<<nb*128,256,0,stream>>>(Dga, kvdw + 2*1152 + 576, U1a);                     // v=U1a [vpre dead]
    k_attn_m  <<<nb,     64, 0,stream>>>(stats, temp + 2*8, projw + 2*4096, Mb);
    k_mm_fin <<<nb*256,256,0,stream>>>(U1a, Mb, para1, para2, yg, Dg);                     // out fp32
  }
}

// Round 8
// 889.741 us; speedup vs baseline: 5.9437x; 1.0764x over previous
//
#include <hip/hip_runtime.h>
#include <math.h>

#define HW_ 65536
#define NCHUNK 16
typedef long long i64;
#define TWO_PI 6.283185307179586476925f

typedef __bf16 bf16x8 __attribute__((ext_vector_type(8)));
typedef __bf16 bf16x4 __attribute__((ext_vector_type(4)));
typedef float f32x4 __attribute__((ext_vector_type(4)));

#define MFMA16(A,B,C) __builtin_amdgcn_mfma_f32_16x16x32_bf16(A,B,C,0,0,0)

__device__ __forceinline__ float sigm(float x){ return 1.0f/(1.0f+expf(-x)); }

// convert 8 consecutive fp32 to a bf16x8 A-fragment
__device__ __forceinline__ bf16x8 cvt_w8(const float* wp){
  float4 w0 = *(const float4*)wp;
  float4 w1 = *(const float4*)(wp+4);
  bf16x8 r;
  r[0]=(__bf16)w0.x; r[1]=(__bf16)w0.y; r[2]=(__bf16)w0.z; r[3]=(__bf16)w0.w;
  r[4]=(__bf16)w1.x; r[5]=(__bf16)w1.y; r[6]=(__bf16)w1.z; r[7]=(__bf16)w1.w;
  return r;
}

__device__ __forceinline__ void st_bf4(__bf16* p, float a, float b, float c, float d){
  bf16x4 v; v[0]=(__bf16)a; v[1]=(__bf16)b; v[2]=(__bf16)c; v[3]=(__bf16)d;
  *(bf16x4*)p = v;
}

// ---------------- resize (nb,3,128,128) -> (nb,3,256,256) bilinear half-pixel ----------------
__global__ __launch_bounds__(256) void k_resize(const float* __restrict__ x, float* __restrict__ R, int b0){
  int idx = blockIdx.x*256 + threadIdx.x;
  int ox = idx & 255;
  int oy = (idx >> 8) & 255;
  int bc = idx >> 16;                               // lb*3 + c
  int lb = bc/3; int c = bc - lb*3;
  float sx = ox*0.5f - 0.25f;
  float sy = oy*0.5f - 0.25f;
  int x0 = (int)floorf(sx); float fx = sx - (float)x0;
  int y0 = (int)floorf(sy); float fy = sy - (float)y0;
  int x1 = min(x0+1,127); int y1 = min(y0+1,127);
  x0 = max(x0,0); y0 = max(y0,0);
  const float* p = x + ((i64)(b0+lb)*3 + c)*16384;
  float v00=p[y0*128+x0], v01=p[y0*128+x1], v10=p[y1*128+x0], v11=p[y1*128+x1];
  R[idx] = (1.0f-fy)*((1.0f-fx)*v00 + fx*v01) + fy*((1.0f-fx)*v10 + fx*v11);
}

// ---------------- conv3x3 3->64: block per (b,row), all 64 outs per thread ----------------
__global__ __launch_bounds__(256) void k_conv3(const float* __restrict__ R, const float* __restrict__ w, float* __restrict__ out){
  int y = blockIdx.x & 255; int b = blockIdx.x >> 8; int t = threadIdx.x;
  float win[27];
  #pragma unroll
  for (int ci=0;ci<3;ci++){
    #pragma unroll
    for (int ky=0;ky<3;ky++){
      int yy = y+ky-1;
      const float* ip = R + (((i64)(b*3+ci))<<16) + yy*256;
      #pragma unroll
      for (int kx=0;kx<3;kx++){
        int xx = t+kx-1;
        float v = 0.f;
        if ((unsigned)yy<256u && (unsigned)xx<256u) v = ip[xx];
        win[ci*9+ky*3+kx] = v;
      }
    }
  }
  i64 obase = ((i64)b<<22) + (y<<8) + t;
  for (int o=0;o<64;o++){
    const float* wp = w + o*27;
    float acc=0.f;
    #pragma unroll
    for (int j=0;j<27;j++) acc += wp[j]*win[j];
    out[obase + ((i64)o<<16)] = acc;
  }
}

// ---------------- DFT coeffs (7 reals incl. DC) + pooled mean per (b,c) ----------------
__global__ __launch_bounds__(256) void k_dft(const float* __restrict__ xc, float* __restrict__ coeff, float* __restrict__ pooled){
  __shared__ float tc[256], ts[256];
  __shared__ float red[256];
  int t = threadIdx.x;
  float ang = TWO_PI * ((float)t/256.0f);
  tc[t] = cosf(ang); ts[t] = sinf(ang);
  __syncthreads();
  int bc = blockIdx.x;
  const float* p = xc + (i64)bc*HW_;
  float s=0, cr=0, ci=0, rr=0, ri=0, dr=0, di=0;
  for (int i=t; i<HW_; i+=256){
    float v = p[i];
    int col = i & 255, row = i >> 8, ds = (row+col)&255;
    s  += v;
    cr += v*tc[col]; ci += v*ts[col];
    rr += v*tc[row]; ri += v*ts[row];
    dr += v*tc[ds];  di += v*ts[ds];
  }
  float vals[7] = {s,cr,ci,rr,ri,dr,di};
  for (int j=0;j<7;j++){
    red[t] = vals[j]; __syncthreads();
    for (int st=128; st>0; st>>=1){ if (t<st) red[t]+=red[t+st]; __syncthreads(); }
    if (t==0) vals[j] = red[0];
    __syncthreads();
  }
  if (t==0){
    const float sc = 1.0f/65536.0f;
    for (int j=0;j<7;j++) coeff[bc*8+j] = vals[j]*sc;
    pooled[bc] = vals[0]*sc;
  }
}

// ---------------- threshold MLP -> per-batch mask flag ----------------
__global__ __launch_bounds__(64) void k_thr(const float* __restrict__ pooled, const float* __restrict__ w1,
                      const float* __restrict__ w2, float* __restrict__ flag){
  __shared__ float hid[8];
  int b = blockIdx.x; int t = threadIdx.x;
  if (t < 8){
    float a = 0.f;
    for (int c=0;c<64;c++) a += pooled[b*64+c]*w1[t*64+c];
    hid[t] = 0.5f*a*(1.0f+erff(a*0.70710678118654752440f));
  }
  __syncthreads();
  if (t==0){
    float t0=0,t1=0;
    for (int k=0;k<8;k++){ t0 += hid[k]*w2[k]; t1 += hid[k]*w2[8+k]; }
    int h_ = (int)(2.0f*sigm(t0));
    int w_ = (int)(2.0f*sigm(t1));
    flag[b] = (h_>0 && w_>0) ? 1.0f : 0.0f;
  }
}

// =====================================================================================
// MM (4px/lane) macros -- retained for k_convq2 only.
// =====================================================================================
#define MM_COMPUTE2(Wbase, BF) \
  bf16x8 af[4][2]; \
  _Pragma("unroll") \
  for (int m=0;m<4;m++){ \
    _Pragma("unroll") \
    for (int s=0;s<2;s++) af[m][s] = cvt_w8((Wbase) + (m*16 + lm)*64 + s*32 + kg*8); \
  } \
  f32x4 acc[4][4]; \
  _Pragma("unroll") \
  for (int m=0;m<4;m++){ \
    _Pragma("unroll") \
    for (int e=0;e<4;e++){ f32x4 z = {0.f,0.f,0.f,0.f}; acc[m][e]=z; } \
  } \
  _Pragma("unroll") \
  for (int m=0;m<4;m++){ \
    _Pragma("unroll") \
    for (int e=0;e<4;e++){ \
      _Pragma("unroll") \
      for (int s=0;s<2;s++) acc[m][e] = MFMA16(af[m][s], BF[s][e], acc[m][e]); \
    } \
  }

#define MM_STORE_BF(outp) \
  _Pragma("unroll") \
  for (int m=0;m<4;m++){ \
    _Pragma("unroll") \
    for (int r=0;r<4;r++){ \
      int oc = m*16 + kg*4 + r; \
      st_bf4((outp) + ibase + ((i64)oc<<16) + 4*lm, acc[m][0][r], acc[m][1][r], acc[m][2][r], acc[m][3][r]); \
    } \
  }

#define MM_SETUP \
  int t = threadIdx.x; \
  int lane = t & 63, wvi = t >> 6; \
  i64 px0 = (i64)blockIdx.x*256 + wvi*64; \
  int b = (int)(px0 >> 16); \
  int p0 = (int)(px0 & (HW_-1)); \
  i64 ibase = ((i64)b<<22) + p0; \
  int lm = lane & 15, kg = lane >> 4;

// =====================================================================================
// X8 MM family: 8 px/lane, 128 px/wave, 16B loads+stores, per-m acc (32 VGPR).
// B-frag e (0..7): px = p0 + 8*lm + e; k = s*32 + kg*8 + j. C/D col=lm, row=kg*4+r.
// Same MFMA accumulation order as MM_ (s=0 then s=1) -> bit-identical results.
// Grid: nb*128 blocks (4 waves x 128 px = 512 px/block).
// =====================================================================================
#define X8_SETUP \
  int t = threadIdx.x; \
  int lane = t & 63, wvi = t >> 6; \
  i64 px0 = (i64)blockIdx.x*512 + (i64)wvi*128; \
  int b = (int)(px0 >> 16); \
  int p0 = (int)(px0 & (HW_-1)); \
  i64 ibase = ((i64)b<<22) + p0; \
  int lm = lane & 15, kg = lane >> 4;

#define X8_FILL_F32(in_ptr) \
  _Pragma("unroll") \
  for (int s=0;s<2;s++){ \
    _Pragma("unroll") \
    for (int j=0;j<8;j++){ \
      const float* p_ = (in_ptr) + ((i64)(s*32 + kg*8 + j)<<16) + 8*lm; \
      float4 a_ = *(const float4*)p_; \
      float4 c_ = *(const float4*)(p_+4); \
      bf[s][0][j]=(__bf16)a_.x; bf[s][1][j]=(__bf16)a_.y; bf[s][2][j]=(__bf16)a_.z; bf[s][3][j]=(__bf16)a_.w; \
      bf[s][4][j]=(__bf16)c_.x; bf[s][5][j]=(__bf16)c_.y; bf[s][6][j]=(__bf16)c_.z; bf[s][7][j]=(__bf16)c_.w; \
    } \
  }

#define X8_FILL_BF(in_ptr) \
  _Pragma("unroll") \
  for (int s=0;s<2;s++){ \
    _Pragma("unroll") \
    for (int j=0;j<8;j++){ \
      bf16x8 u_ = *(const bf16x8*)((in_ptr) + ((i64)(s*32 + kg*8 + j)<<16) + 8*lm); \
      _Pragma("unroll") \
      for (int e=0;e<8;e++) bf[s][e][j] = u_[e]; \
    } \
  }

// per-m compute: declares af0/af1/acc (use inside a braces scope within the m loop)
#define X8_ACC_M(Wbase, BF) \
  bf16x8 af0 = cvt_w8((Wbase) + (m*16 + lm)*64 + kg*8); \
  bf16x8 af1 = cvt_w8((Wbase) + (m*16 + lm)*64 + 32 + kg*8); \
  f32x4 acc[8]; \
  _Pragma("unroll") \
  for (int e=0;e<8;e++){ f32x4 z_ = {0.f,0.f,0.f,0.f}; acc[e]=z_; } \
  _Pragma("unroll") \
  for (int e=0;e<8;e++){ acc[e]=MFMA16(af0,BF[0][e],acc[e]); acc[e]=MFMA16(af1,BF[1][e],acc[e]); }

#define X8_ST_BF(outp) \
  _Pragma("unroll") \
  for (int r=0;r<4;r++){ \
    int oc = m*16 + kg*4 + r; \
    bf16x8 ov; \
    _Pragma("unroll") \
    for (int e=0;e<8;e++) ov[e]=(__bf16)acc[e][r]; \
    *(bf16x8*)((outp) + ibase + ((i64)oc<<16) + 8*lm) = ov; \
  }

#define X8_MM_BF(Wbase, BF, outp) \
  _Pragma("unroll") \
  for (int m=0;m<4;m++){ X8_ACC_M(Wbase, BF) X8_ST_BF(outp) }

// ---------------- fused: DFT recon (shared) -> BOTH high & low conv1x1 (4px/lane, unchanged) ----------------
__global__ __launch_bounds__(256) void k_convq2(const float* __restrict__ xc, const float* __restrict__ coeff,
      const float* __restrict__ flag, const float* __restrict__ qwh, const float* __restrict__ qwl,
      __bf16* __restrict__ outh, __bf16* __restrict__ outl){
  __shared__ float tc[256], ts[256];
  {
    int tt = threadIdx.x;
    float ang = TWO_PI * ((float)tt/256.0f);
    tc[tt]=cosf(ang); ts[tt]=sinf(ang);
  }
  __syncthreads();
  MM_SETUP
  float fl = flag[b];
  int y = p0 >> 8;
  int xb = (p0 & 255) + 4*lm;
  float crow = tc[y], srow = ts[y];
  float cx[4], sx[4], cd[4], sd[4];
  #pragma unroll
  for (int e=0;e<4;e++){
    int xx = xb + e;
    cx[e]=tc[xx]; sx[e]=ts[xx];
    int d = (xx + y) & 255;
    cd[e]=tc[d]; sd[e]=ts[d];
  }
  bf16x8 bfh[2][4], bfl[2][4];
  #pragma unroll
  for (int s=0;s<2;s++){
    #pragma unroll
    for (int j=0;j<8;j++){
      int ch = s*32 + kg*8 + j;
      const float* cf = coeff + ((b<<6)+ch)*8;
      float4 ca = *(const float4*)cf;
      float4 cb = *(const float4*)(cf+4);
      float F00=ca.x, cR=ca.y, cI=ca.z, rR=ca.w, rI=cb.x, dR=cb.y, dI=cb.z;
      float4 xr = *(const float4*)(xc + ibase + ((i64)ch<<16) + 4*lm);
      float rowR = F00 + rR*crow + rI*srow;
      float rowI = rI*crow - rR*srow;
      #pragma unroll
      for (int e=0;e<4;e++){
        float re = rowR + cR*cx[e] + cI*sx[e] + dR*cd[e] + dI*sd[e];
        float im = rowI + cI*cx[e] - cR*sx[e] + dI*cd[e] - dR*sd[e];
        re*=fl; im*=fl;
        float vl = sqrtf(re*re+im*im);
        float hr = ((const float*)&xr)[e] - re;
        float vh = sqrtf(hr*hr + im*im);
        bfh[s][e][j] = (__bf16)vh;
        bfl[s][e][j] = (__bf16)vl;
      }
    }
  }
  {
    MM_COMPUTE2(qwh, bfh)
    MM_STORE_BF(outh)
  }
  {
    MM_COMPUTE2(qwl, bfl)
    MM_STORE_BF(outl)
  }
}

// ---------------- fused conv1x1 from y (X8): kv0, kv1, q2 -- one y read, 16B stores ----------------
__global__ __launch_bounds__(256) void k_kvq(const float* __restrict__ yin,
      const float* __restrict__ kvw0, const float* __restrict__ kvw1, const float* __restrict__ qw2,
      __bf16* __restrict__ k0o, __bf16* __restrict__ v0o,
      __bf16* __restrict__ k1o, __bf16* __restrict__ v1o, __bf16* __restrict__ q2o){
  X8_SETUP
  bf16x8 bf[2][8];
  X8_FILL_F32(yin + ibase)
  X8_MM_BF(kvw0,        bf, k0o)
  X8_MM_BF(kvw0 + 4096, bf, v0o)
  X8_MM_BF(kvw1,        bf, k1o)
  X8_MM_BF(kvw1 + 4096, bf, v1o)
  X8_MM_BF(qw2,         bf, q2o)
}

// ---------------- conv1x1 64->128 (X8, bf16 in) for cca2 ----------------
__global__ __launch_bounds__(256) void k_mm_kvb(const __bf16* __restrict__ in, const float* __restrict__ w,
      __bf16* __restrict__ kout, __bf16* __restrict__ vout){
  X8_SETUP
  bf16x8 bf[2][8];
  X8_FILL_BF(in + ibase)
  X8_MM_BF(w,        bf, kout)
  X8_MM_BF(w + 4096, bf, vout)
}

// ---------------- mconv high (X8): M x v + per-px channel max/mean ----------------
__global__ __launch_bounds__(256) void k_mm_hi(const __bf16* __restrict__ v, const float* __restrict__ M,
        float* __restrict__ mx, float* __restrict__ mn, __bf16* __restrict__ out){
  X8_SETUP
  bf16x8 bf[2][8];
  X8_FILL_BF(v + ibase)
  const float* Wb = M + ((i64)b<<12);
  float smx[8], ssum[8];
  #pragma unroll
  for (int e=0;e<8;e++){ smx[e]=-1e30f; ssum[e]=0.f; }
  #pragma unroll
  for (int m=0;m<4;m++){
    X8_ACC_M(Wb, bf)
    X8_ST_BF(out)
    #pragma unroll
    for (int r=0;r<4;r++){
      #pragma unroll
      for (int e=0;e<8;e++){ smx[e]=fmaxf(smx[e],acc[e][r]); ssum[e]+=acc[e][r]; }
    }
  }
  // reduce across kg groups (channels) -> full 64-channel per-px reduce
  #pragma unroll
  for (int e=0;e<8;e++){
    smx[e] = fmaxf(smx[e], __shfl_xor(smx[e],16));
    smx[e] = fmaxf(smx[e], __shfl_xor(smx[e],32));
    ssum[e] += __shfl_xor(ssum[e],16);
    ssum[e] += __shfl_xor(ssum[e],32);
  }
  if (kg==0){
    i64 pbase = ((i64)b<<16) + p0 + 8*lm;
    *(float4*)(mx+pbase)   = make_float4(smx[0],smx[1],smx[2],smx[3]);
    *(float4*)(mx+pbase+4) = make_float4(smx[4],smx[5],smx[6],smx[7]);
    const float iv = 1.0f/64.0f;
    *(float4*)(mn+pbase)   = make_float4(ssum[0]*iv,ssum[1]*iv,ssum[2]*iv,ssum[3]*iv);
    *(float4*)(mn+pbase+4) = make_float4(ssum[4]*iv,ssum[5]*iv,ssum[6]*iv,ssum[7]*iv);
  }
}

// ---------------- mconv low (X8): M x v + per-channel sum/max partials ----------------
__global__ __launch_bounds__(256) void k_mm_lo(const __bf16* __restrict__ v, const float* __restrict__ M,
        __bf16* __restrict__ out, float* __restrict__ spart){
  __shared__ float ls[4][64], lmx[4][64];
  X8_SETUP
  bf16x8 bf[2][8];
  X8_FILL_BF(v + ibase)
  const float* Wb = M + ((i64)b<<12);
  #pragma unroll
  for (int m=0;m<4;m++){
    X8_ACC_M(Wb, bf)
    X8_ST_BF(out)
    #pragma unroll
    for (int r=0;r<4;r++){
      int oc = m*16 + kg*4 + r;
      float s = 0.f, mm = -1e30f;
      #pragma unroll
      for (int e=0;e<8;e++){ s += acc[e][r]; mm = fmaxf(mm, acc[e][r]); }
      #pragma unroll
      for (int off=8; off; off>>=1){ s += __shfl_xor(s,off); mm = fmaxf(mm,__shfl_xor(mm,off)); }
      if (lm==0){ ls[wvi][oc]=s; lmx[wvi][oc]=mm; }
    }
  }
  __syncthreads();
  if (t<64){
    float s = ls[0][t]+ls[1][t]+ls[2][t]+ls[3][t];
    float mm = fmaxf(fmaxf(lmx[0][t],lmx[1][t]),fmaxf(lmx[2][t],lmx[3][t]));
    spart[(i64)blockIdx.x*128 + t*2]   = s;
    spart[(i64)blockIdx.x*128 + t*2+1] = mm;
  }
}

// ---------------- fused comb + refine conv1x1 (X8, bf16 in/out) ----------------
__global__ __launch_bounds__(256) void k_mm_comb(const __bf16* __restrict__ lo2, const __bf16* __restrict__ hi2,
        const float* __restrict__ swb, const float* __restrict__ cwv,
        const float* __restrict__ w, const float* __restrict__ bias, __bf16* __restrict__ out){
  X8_SETUP
  const float* swp = swb + ((i64)b<<16) + p0 + 8*lm;
  float4 sw0 = *(const float4*)swp;
  float4 sw1 = *(const float4*)(swp+4);
  float swv[8] = {sw0.x,sw0.y,sw0.z,sw0.w,sw1.x,sw1.y,sw1.z,sw1.w};
  bf16x8 bf[2][8];
  #pragma unroll
  for (int s=0;s<2;s++){
    #pragma unroll
    for (int j=0;j<8;j++){
      int ch = s*32 + kg*8 + j;
      bf16x8 l8 = *(const bf16x8*)(lo2 + ibase + ((i64)ch<<16) + 8*lm);
      bf16x8 h8 = *(const bf16x8*)(hi2 + ibase + ((i64)ch<<16) + 8*lm);
      float cw = cwv[(b<<6) + ch];
      #pragma unroll
      for (int e=0;e<8;e++) bf[s][e][j] = (__bf16)((float)l8[e]*swv[e] + (float)h8[e]*cw);
    }
  }
  #pragma unroll
  for (int m=0;m<4;m++){
    X8_ACC_M(w, bf)
    #pragma unroll
    for (int r=0;r<4;r++){
      int oc = m*16 + kg*4 + r;
      float bv = bias[oc];
      bf16x8 ov;
      #pragma unroll
      for (int e=0;e<8;e++) ov[e]=(__bf16)(acc[e][r]+bv);
      *(bf16x8*)(out + ibase + ((i64)oc<<16) + 8*lm) = ov;
    }
  }
}

// ---------------- final mconv (X8): M x v, *para1 + y*para2, fp32 out ----------------
__global__ __launch_bounds__(256) void k_mm_fin(const __bf16* __restrict__ v, const float* __restrict__ M,
      const float* __restrict__ para1, const float* __restrict__ para2,
      const float* __restrict__ yin, float* __restrict__ out){
  X8_SETUP
  bf16x8 bf[2][8];
  X8_FILL_BF(v + ibase)
  const float* Wb = M + ((i64)b<<12);
  #pragma unroll
  for (int m=0;m<4;m++){
    X8_ACC_M(Wb, bf)
    #pragma unroll
    for (int r=0;r<4;r++){
      int oc = m*16 + kg*4 + r;
      float p1 = para1[oc], p2 = para2[oc];
      const float* yp = yin + ibase + ((i64)oc<<16) + 8*lm;
      float4 y0 = *(const float4*)yp;
      float4 y1 = *(const float4*)(yp+4);
      float* op = out + ibase + ((i64)oc<<16) + 8*lm;
      *(float4*)op     = make_float4(acc[0][r]*p1+y0.x*p2, acc[1][r]*p1+y0.y*p2,
                                     acc[2][r]*p1+y0.z*p2, acc[3][r]*p1+y0.w*p2);
      *(float4*)(op+4) = make_float4(acc[4][r]*p1+y1.x*p2, acc[5][r]*p1+y1.y*p2,
                                     acc[6][r]*p1+y1.z*p2, acc[7][r]*p1+y1.w*p2);
    }
  }
}

// ---------------- Gram-MFMA stats, merged double-set dispatch ----------------
// set = blockIdx >= hgrid (selects tensor/weight pair and part half).
__global__ __launch_bounds__(256) void k_gram(const __bf16* __restrict__ q0, const __bf16* __restrict__ kk0,
        const __bf16* __restrict__ q1, const __bf16* __restrict__ kk1,
        const float* __restrict__ qdw0, const float* __restrict__ kdw0,
        const float* __restrict__ qdw1, const float* __restrict__ kdw1,
        float* __restrict__ part, int hgrid){
  __shared__ float red[4][16][16];
  int bx = blockIdx.x;
  int set = (bx >= hgrid) ? 1 : 0;
  int blk = bx - set*hgrid;
  const __bf16* qpre = set ? q1 : q0;
  const __bf16* kpre = set ? kk1 : kk0;
  const float* qdw = set ? qdw1 : qdw0;
  const float* kdw = set ? kdw1 : kdw0;
  float* ppart = part + (i64)set*hgrid*80;
  int rowblk = blk & 15;
  int bh = blk >> 4;
  int h = bh & 7, b = bh >> 3;
  int t = threadIdx.x;
  int lane = t & 63, wvi = t >> 6;
  int lm = lane & 15, kg = lane >> 4;
  int a = lm & 7;
  const __bf16* plane = (lm < 8 ? qpre : kpre) + (((i64)((b<<6)+(h<<3)+a))<<16);
  const float* wp = (lm < 8 ? qdw : kdw) + h*72 + a*9;
  float w0=wp[0],w1=wp[1],w2=wp[2],w3=wp[3],w4=wp[4],w5=wp[5],w6=wp[6],w7=wp[7],w8=wp[8];
  int R0 = rowblk*16;
  f32x4 acc = {0.f,0.f,0.f,0.f};
  #pragma unroll
  for (int cc=0; cc<2; cc++){
    int chunk = wvi*2 + cc;
    int xb = chunk*32 + kg*8;
    bool left = (xb==0), right = (xb==248);
    float h0[8], h1[8];
    #pragma unroll
    for (int e=0;e<8;e++){ h0[e]=0.f; h1[e]=0.f; }
    for (int ir = R0-1; ir <= R0+16; ir++){
      bool rok = ((unsigned)ir < 256u);
      float win[10];
      if (rok){
        const __bf16* rp = plane + ir*256 + xb;
        bf16x8 mid = *(const bf16x8*)rp;
        win[0] = left ? 0.f : (float)rp[-1];
        #pragma unroll
        for (int w=1; w<9; w++) win[w] = (float)mid[w-1];
        win[9] = right ? 0.f : (float)rp[8];
      } else {
        #pragma unroll
        for (int w=0; w<10; w++) win[w] = 0.f;
      }
      float o[8];
      #pragma unroll
      for (int e=0;e<8;e++){
        float t0 = w0*win[e] + w1*win[e+1] + w2*win[e+2];
        float t1 = w3*win[e] + w4*win[e+1] + w5*win[e+2];
        float t2 = w6*win[e] + w7*win[e+1] + w8*win[e+2];
        o[e] = h0[e] + t2;
        h0[e] = h1[e] + t1;
        h1[e] = t0;
      }
      if (ir > R0){
        bf16x8 xf;
        #pragma unroll
        for (int e=0;e<8;e++) xf[e] = (__bf16)o[e];
        acc = MFMA16(xf, xf, acc);
      }
    }
  }
  #pragma unroll
  for (int r=0;r<4;r++) red[wvi][kg*4+r][lm] = acc[r];
  __syncthreads();
  if (t < 80){
    int r, c;
    if (t < 64){ r = t>>3; c = 8 + (t&7); }
    else if (t < 72){ r = t-64; c = r; }
    else { r = 8 + (t-72); c = r; }
    float s = red[0][r][c]+red[1][r][c]+red[2][r][c]+red[3][r][c];
    ppart[(i64)blk*80 + t] = s;
  }
}

__global__ __launch_bounds__(128) void k_stats_fin(const float* __restrict__ part, float* __restrict__ stats){
  int bh = blockIdx.x; int t = threadIdx.x;
  if (t < 80){
    float s=0.f;
    for (int c=0;c<NCHUNK;c++) s += part[((i64)bh*NCHUNK+c)*80 + t];
    stats[bh*80+t] = s;
  }
}

// ---------------- softmax + fold attn into 64x64 M (merged: super-b over 2 sets) ----------------
__global__ __launch_bounds__(64) void k_attn_m(const float* __restrict__ stats, const float* __restrict__ temp,
                         const float* __restrict__ projw, float* __restrict__ M, int nb){
  __shared__ float attn[8][8][8];
  int bsup = blockIdx.x; int t = threadIdx.x;
  int set = (bsup >= nb) ? 1 : 0;
  int h = t >> 3, cc = t & 7;
  const float* st = stats + (bsup*8+h)*80;
  float nq = fmaxf(sqrtf(st[64+cc]), 1e-12f);
  float tmp = temp[set*8 + h];
  const float* pw = projw + set*4096;
  float s[8];
  float mx = -1e30f;
  #pragma unroll
  for (int d=0;d<8;d++){
    float nk = fmaxf(sqrtf(st[72+d]), 1e-12f);
    s[d] = st[cc*8+d]/(nq*nk)*tmp;
    mx = fmaxf(mx, s[d]);
  }
  float sum=0.f;
  #pragma unroll
  for (int d=0;d<8;d++){ s[d]=expf(s[d]-mx); sum+=s[d]; }
  float inv = 1.0f/sum;
  #pragma unroll
  for (int d=0;d<8;d++) attn[h][cc][d] = s[d]*inv;
  __syncthreads();
  int o = t;
  for (int hh=0; hh<8; hh++){
    #pragma unroll
    for (int d=0; d<8; d++){
      float acc=0.f;
      #pragma unroll
      for (int c2=0;c2<8;c2++) acc += pw[o*64 + hh*8 + c2]*attn[hh][c2][d];
      M[((i64)bsup*64 + o)*64 + hh*8 + d] = acc;
    }
  }
}

// ---------------- depthwise 3x3 (v path), merged double-set dispatch ----------------
__global__ __launch_bounds__(256) void k_dwb(const __bf16* __restrict__ in0, const __bf16* __restrict__ in1,
        const float* __restrict__ wd0, const float* __restrict__ wd1,
        __bf16* __restrict__ out0, __bf16* __restrict__ out1, int hgrid){
  int bx = blockIdx.x;
  int set = (bx >= hgrid) ? 1 : 0;
  int blk = bx - set*hgrid;
  const __bf16* in = set ? in1 : in0;
  const float* wd = set ? wd1 : wd0;
  __bf16* out = set ? out1 : out0;
  int half = blk & 1; int c = (blk>>1)&63; int b = blk>>7;
  int t = threadIdx.x;
  int strip = t & 31, rg = t >> 5;
  const __bf16* ip = in + (((i64)((b<<6)+c))<<16);
  __bf16* op = out + (((i64)((b<<6)+c))<<16);
  const float* wp = wd + c*9;
  float w0=wp[0],w1=wp[1],w2=wp[2],w3=wp[3],w4=wp[4],w5=wp[5],w6=wp[6],w7=wp[7],w8=wp[8];
  int R0 = half*128 + rg*16;
  int xb = strip*8;
  bool left = (xb==0), right = (xb==248);
  float h0[8], h1[8];
  #pragma unroll
  for (int e=0;e<8;e++){ h0[e]=0.f; h1[e]=0.f; }
  for (int ir = R0-1; ir <= R0+16; ir++){
    bool rok = ((unsigned)ir < 256u);
    float win[10];
    if (rok){
      const __bf16* rp = ip + ir*256 + xb;
      bf16x8 mid = *(const bf16x8*)rp;
      win[0] = left ? 0.f : (float)rp[-1];
      #pragma unroll
      for (int w=1; w<9; w++) win[w] = (float)mid[w-1];
      win[9] = right ? 0.f : (float)rp[8];
    } else {
      #pragma unroll
      for (int w=0; w<10; w++) win[w] = 0.f;
    }
    float o[8];
    #pragma unroll
    for (int e=0;e<8;e++){
      float t0 = w0*win[e] + w1*win[e+1] + w2*win[e+2];
      float t1 = w3*win[e] + w4*win[e+1] + w5*win[e+2];
      float t2 = w6*win[e] + w7*win[e+1] + w8*win[e+2];
      o[e] = h0[e] + t2;
      h0[e] = h1[e] + t1;
      h1[e] = t0;
    }
    if (ir > R0){
      bf16x8 ov;
      #pragma unroll
      for (int e=0;e<8;e++) ov[e] = (__bf16)o[e];
      *(bf16x8*)(op + (ir-1)*256 + xb) = ov;
    }
  }
}

// ---------------- refine small kernels ----------------
__global__ __launch_bounds__(64) void k_spatfin(const float* __restrict__ spart, float* __restrict__ lmean, float* __restrict__ lmax){
  int b = blockIdx.x; int c = threadIdx.x;
  float s=0.f, m=-1e30f;
  for (int r=0;r<128;r++){
    s += spart[(i64)(b*128+r)*128 + c*2];
    m = fmaxf(m, spart[(i64)(b*128+r)*128 + c*2+1]);
  }
  lmean[b*64+c] = s*(1.0f/65536.0f);
  lmax[b*64+c]  = m;
}

__global__ __launch_bounds__(64) void k_cw(const float* __restrict__ mean, const float* __restrict__ mxv,
                     const float* __restrict__ w1, const float* __restrict__ w2, float* __restrict__ cw){
  __shared__ float ha[4], hm[4];
  int b = blockIdx.x; int t = threadIdx.x;
  if (t < 4){
    float sa=0.f, sm_=0.f;
    for (int c=0;c<64;c++){ sa += w1[t*64+c]*mean[b*64+c]; sm_ += w1[t*64+c]*mxv[b*64+c]; }
    ha[t] = fmaxf(sa, 0.f); hm[t] = fmaxf(sm_, 0.f);
  }
  __syncthreads();
  float a=0.f;
  #pragma unroll
  for (int j=0;j<4;j++) a += w2[t*4+j]*(ha[j]+hm[j]);
  cw[b*64+t] = sigm(a);
}

__global__ __launch_bounds__(256) void k_sw(const float* __restrict__ mx, const float* __restrict__ mn,
                     const float* __restrict__ w, float* __restrict__ sw){
  int row = blockIdx.x & 255; int b = blockIdx.x >> 8; int t = threadIdx.x;
  const float* m0 = mx + ((i64)b<<16);
  const float* m1 = mn + ((i64)b<<16);
  float acc=0.f;
  for (int ky=0;ky<7;ky++){
    int yy = row+ky-3; if ((unsigned)yy>255u) continue;
    for (int kx=0;kx<7;kx++){
      int xx = t+kx-3; if ((unsigned)xx>255u) continue;
      acc += w[ky*7+kx]*m0[yy*256+xx] + w[49+ky*7+kx]*m1[yy*256+xx];
    }
  }
  sw[((i64)b<<16) + row*256 + t] = sigm(acc);
}

// =====================================================================================
extern "C" void kernel_launch(void* const* d_in, const int* in_sizes, int n_in,
                              void* d_out, int out_size, void* d_ws, size_t ws_size,
                              hipStream_t stream){
  const float* x      = (const float*)d_in[0];
  const float* y      = (const float*)d_in[1];
  const float* conv1w = (const float*)d_in[2];
  const float* ratew1 = (const float*)d_in[3];
  const float* ratew2 = (const float*)d_in[4];
  const float* temp   = (const float*)d_in[5];
  const float* qw     = (const float*)d_in[6];
  const float* qdw    = (const float*)d_in[7];
  const float* kvw    = (const float*)d_in[8];
  const float* kvdw   = (const float*)d_in[9];
  const float* projw  = (const float*)d_in[10];
  const float* spw    = (const float*)d_in[11];
  const float* cgw1   = (const float*)d_in[12];
  const float* cgw2   = (const float*)d_in[13];
  const float* rprojw = (const float*)d_in[14];
  const float* rprojb = (const float*)d_in[15];
  const float* para1  = (const float*)d_in[16];
  const float* para2  = (const float*)d_in[17];
  float* D = (float*)d_out;

  // pick largest batch-group size whose footprint fits: 3 big units + pool
  int nb = 8;
  for (;;){
    size_t unit = (size_t)nb*64*HW_;
    size_t pool = (size_t)nb*3*HW_            // Rbuf
                + (size_t)nb*512 + (size_t)nb*64 + 64
                + 2*(size_t)nb*8*NCHUNK*80    // part (2 sets)
                + 2*(size_t)nb*8*80           // stats (2 sets)
                + 2*(size_t)nb*64*64          // M (2 sets)
                + 3*(size_t)nb*HW_            // mxmap, mnmap, swb
                + (size_t)nb*128*128          // spart
                + 3*(size_t)nb*64;            // lmean, lmax, cwb
    if ((3*unit + pool)*sizeof(float) <= ws_size || nb==1) break;
    nb >>= 1;
  }

  size_t unit = (size_t)nb*64*HW_;
  float* U0 = (float*)d_ws;
  float* U1 = U0 + unit;
  float* U2 = U1 + unit;
  float* sm = U2 + unit;
  float* Rbuf  = sm;  sm += (size_t)nb*3*HW_;
  float* coeff = sm;  sm += (size_t)nb*512;
  float* pooled= sm;  sm += (size_t)nb*64;
  float* flagb = sm;  sm += 64;
  float* part  = sm;  sm += 2*(size_t)nb*8*NCHUNK*80;
  float* stats = sm;  sm += 2*(size_t)nb*8*80;
  float* Mb    = sm;  sm += 2*(size_t)nb*64*64;
  float* mxmap = sm;  sm += (size_t)nb*HW_;
  float* mnmap = sm;  sm += (size_t)nb*HW_;
  float* swb   = sm;  sm += (size_t)nb*HW_;
  float* spart = sm;  sm += (size_t)nb*128*128;
  float* lmean = sm;  sm += (size_t)nb*64;
  float* lmax  = sm;  sm += (size_t)nb*64;
  float* cwb   = sm;  sm += (size_t)nb*64;

  int hgr = nb*8*NCHUNK;     // gram half-grid
  int hdw = nb*128;          // dwb half-grid

  for (int b0 = 0; b0 < 8; b0 += nb){
    const float* yg = y + (i64)b0*64*HW_;
    float*       Dg = D + (i64)b0*64*HW_;
    // bf16 tensor slots: each fp32 unit region holds TWO bf16 tensors of `unit` elements.
    __bf16* U0a = (__bf16*)U0; __bf16* U0c = U0a + unit;
    __bf16* U1a = (__bf16*)U1; __bf16* U1c = U1a + unit;
    __bf16* U2a = (__bf16*)U2; __bf16* U2c = U2a + unit;
    __bf16* Dga = (__bf16*)Dg; __bf16* Dgc = Dga + unit;
    float* Mb1 = Mb + (i64)nb*4096;

    // frontend
    k_resize <<<nb*3*256, 256,0,stream>>>(x, Rbuf, b0);
    k_conv3  <<<nb*256,   256,0,stream>>>(Rbuf, conv1w, U0);           // xc = U0 (fp32)
    k_dft    <<<nb*64,    256,0,stream>>>(U0, coeff, pooled);
    k_thr    <<<nb,       64, 0,stream>>>(pooled, ratew1, ratew2, flagb);

    // fused q-recon (cca0-high + cca1-low); xc dead after
    k_convq2 <<<nb*256,256,0,stream>>>(U0, coeff, flagb, qw + 0*4096, qw + 1*4096, U1a, U1c); // qh=U1a, ql=U1c
    // fused y-matmuls (X8): kv0, kv1, q2-pre
    k_kvq    <<<nb*128,256,0,stream>>>(yg, kvw + 0*8192, kvw + 1*8192, qw + 2*4096,
                                       U2a, Dga, U2c, Dgc, U0c);       // k0,v0,k1,v1,q2

    // merged cca0+cca1 stats pipeline
    k_gram   <<<2*hgr,256,0,stream>>>(U1a, U2a, U1c, U2c,
                                      qdw + 0*576, kvdw + 0*1152, qdw + 1*576, kvdw + 1*1152,
                                      part, hgr);                      // [qh,ql,k0,k1 dead]
    k_stats_fin<<<2*nb*8, 128,0,stream>>>(part, stats);
    k_dwb    <<<2*hdw,256,0,stream>>>(Dga, Dgc, kvdw + 0*1152 + 576, kvdw + 1*1152 + 576,
                                      U1a, U1c, hdw);                  // v0'=U1a, v1'=U1c [v0,v1 dead]
    k_attn_m <<<2*nb, 64,0,stream>>>(stats, temp, projw, Mb, nb);      // Mb0, Mb1

    k_mm_hi  <<<nb*128,256,0,stream>>>(U1a, Mb,  mxmap, mnmap, Dga);   // high2=Dga
    k_mm_lo  <<<nb*128,256,0,stream>>>(U1c, Mb1, Dgc, spart);          // low2=Dgc

    // refine: high2=Dga, low2=Dgc -> agg=U0a
    k_spatfin <<<nb,     64, 0,stream>>>(spart, lmean, lmax);
    k_cw      <<<nb,     64, 0,stream>>>(lmean, lmax, cgw1, cgw2, cwb);
    k_sw      <<<nb*256, 256,0,stream>>>(mxmap, mnmap, spw, swb);
    k_mm_comb<<<nb*128,256,0,stream>>>(Dgc, Dga, swb, cwb, rprojw, rprojb, U0a);  // agg=U0a

    // cca2 (q2=U0c, kv from agg=U0a)
    k_mm_kvb <<<nb*128,256,0,stream>>>(U0a, kvw + 2*8192, U2a, U2c);   // k2=U2a, v2=U2c
    k_gram   <<<hgr,256,0,stream>>>(U0c, U2a, U0c, U2a,
                                    qdw + 2*576, kvdw + 2*1152, qdw + 2*576, kvdw + 2*1152,
                                    part, hgr);
    k_stats_fin<<<nb*8, 128,0,stream>>>(part, stats);
    k_dwb    <<<hdw,256,0,stream>>>(U2c, U2c, kvdw + 2*1152 + 576, kvdw + 2*1152 + 576,
                                    U1a, U1a, hdw);                    // v'=U1a
    k_attn_m <<<nb, 64,0,stream>>>(stats, temp + 2*8, projw + 2*4096, Mb, nb);
    k_mm_fin <<<nb*128,256,0,stream>>>(U1a, Mb, para1, para2, yg, Dg); // out fp32
  }
}

// Round 9
// 774.267 us; speedup vs baseline: 6.8302x; 1.1491x over previous
//
#include <hip/hip_runtime.h>
#include <math.h>

#define HW_ 65536
#define NCHUNK 16
typedef long long i64;
#define TWO_PI 6.283185307179586476925f

typedef __bf16 bf16x8 __attribute__((ext_vector_type(8)));
typedef __bf16 bf16x4 __attribute__((ext_vector_type(4)));
typedef float f32x4 __attribute__((ext_vector_type(4)));

#define MFMA16(A,B,C) __builtin_amdgcn_mfma_f32_16x16x32_bf16(A,B,C,0,0,0)

__device__ __forceinline__ float sigm(float x){ return 1.0f/(1.0f+expf(-x)); }

// convert 8 consecutive fp32 to a bf16x8 A-fragment
__device__ __forceinline__ bf16x8 cvt_w8(const float* wp){
  float4 w0 = *(const float4*)wp;
  float4 w1 = *(const float4*)(wp+4);
  bf16x8 r;
  r[0]=(__bf16)w0.x; r[1]=(__bf16)w0.y; r[2]=(__bf16)w0.z; r[3]=(__bf16)w0.w;
  r[4]=(__bf16)w1.x; r[5]=(__bf16)w1.y; r[6]=(__bf16)w1.z; r[7]=(__bf16)w1.w;
  return r;
}

__device__ __forceinline__ void st_bf4(__bf16* p, float a, float b, float c, float d){
  bf16x4 v; v[0]=(__bf16)a; v[1]=(__bf16)b; v[2]=(__bf16)c; v[3]=(__bf16)d;
  *(bf16x4*)p = v;
}

// ---------------- resize (nb,3,128,128) -> (nb,3,256,256) bilinear half-pixel ----------------
__global__ __launch_bounds__(256) void k_resize(const float* __restrict__ x, float* __restrict__ R, int b0){
  int idx = blockIdx.x*256 + threadIdx.x;
  int ox = idx & 255;
  int oy = (idx >> 8) & 255;
  int bc = idx >> 16;                               // lb*3 + c
  int lb = bc/3; int c = bc - lb*3;
  float sx = ox*0.5f - 0.25f;
  float sy = oy*0.5f - 0.25f;
  int x0 = (int)floorf(sx); float fx = sx - (float)x0;
  int y0 = (int)floorf(sy); float fy = sy - (float)y0;
  int x1 = min(x0+1,127); int y1 = min(y0+1,127);
  x0 = max(x0,0); y0 = max(y0,0);
  const float* p = x + ((i64)(b0+lb)*3 + c)*16384;
  float v00=p[y0*128+x0], v01=p[y0*128+x1], v10=p[y1*128+x0], v11=p[y1*128+x1];
  R[idx] = (1.0f-fy)*((1.0f-fx)*v00 + fx*v01) + fy*((1.0f-fx)*v10 + fx*v11);
}

// ---------------- conv3x3 3->64 (bf16 out): block per (b,row), all 64 outs per thread ----------------
__global__ __launch_bounds__(256) void k_conv3(const float* __restrict__ R, const float* __restrict__ w, __bf16* __restrict__ out){
  int y = blockIdx.x & 255; int b = blockIdx.x >> 8; int t = threadIdx.x;
  float win[27];
  #pragma unroll
  for (int ci=0;ci<3;ci++){
    #pragma unroll
    for (int ky=0;ky<3;ky++){
      int yy = y+ky-1;
      const float* ip = R + (((i64)(b*3+ci))<<16) + yy*256;
      #pragma unroll
      for (int kx=0;kx<3;kx++){
        int xx = t+kx-1;
        float v = 0.f;
        if ((unsigned)yy<256u && (unsigned)xx<256u) v = ip[xx];
        win[ci*9+ky*3+kx] = v;
      }
    }
  }
  i64 obase = ((i64)b<<22) + (y<<8) + t;
  for (int o=0;o<64;o++){
    const float* wp = w + o*27;
    float acc=0.f;
    #pragma unroll
    for (int j=0;j<27;j++) acc += wp[j]*win[j];
    out[obase + ((i64)o<<16)] = (__bf16)acc;
  }
}

// ---------------- DFT coeffs (7 reals incl. DC) + pooled mean per (b,c), bf16 in ----------------
__global__ __launch_bounds__(256) void k_dft(const __bf16* __restrict__ xc, float* __restrict__ coeff, float* __restrict__ pooled){
  __shared__ float tc[256], ts[256];
  __shared__ float red[256];
  int t = threadIdx.x;
  float ang = TWO_PI * ((float)t/256.0f);
  tc[t] = cosf(ang); ts[t] = sinf(ang);
  __syncthreads();
  int bc = blockIdx.x;
  const __bf16* p = xc + (i64)bc*HW_;
  float s=0, cr=0, ci=0, rr=0, ri=0, dr=0, di=0;
  for (int i=t; i<HW_; i+=256){
    float v = (float)p[i];
    int col = i & 255, row = i >> 8, ds = (row+col)&255;
    s  += v;
    cr += v*tc[col]; ci += v*ts[col];
    rr += v*tc[row]; ri += v*ts[row];
    dr += v*tc[ds];  di += v*ts[ds];
  }
  float vals[7] = {s,cr,ci,rr,ri,dr,di};
  for (int j=0;j<7;j++){
    red[t] = vals[j]; __syncthreads();
    for (int st=128; st>0; st>>=1){ if (t<st) red[t]+=red[t+st]; __syncthreads(); }
    if (t==0) vals[j] = red[0];
    __syncthreads();
  }
  if (t==0){
    const float sc = 1.0f/65536.0f;
    for (int j=0;j<7;j++) coeff[bc*8+j] = vals[j]*sc;
    pooled[bc] = vals[0]*sc;
  }
}

// ---------------- threshold MLP -> per-batch mask flag ----------------
__global__ __launch_bounds__(64) void k_thr(const float* __restrict__ pooled, const float* __restrict__ w1,
                      const float* __restrict__ w2, float* __restrict__ flag){
  __shared__ float hid[8];
  int b = blockIdx.x; int t = threadIdx.x;
  if (t < 8){
    float a = 0.f;
    for (int c=0;c<64;c++) a += pooled[b*64+c]*w1[t*64+c];
    hid[t] = 0.5f*a*(1.0f+erff(a*0.70710678118654752440f));
  }
  __syncthreads();
  if (t==0){
    float t0=0,t1=0;
    for (int k=0;k<8;k++){ t0 += hid[k]*w2[k]; t1 += hid[k]*w2[8+k]; }
    int h_ = (int)(2.0f*sigm(t0));
    int w_ = (int)(2.0f*sigm(t1));
    flag[b] = (h_>0 && w_>0) ? 1.0f : 0.0f;
  }
}

// =====================================================================================
// MM (4px/lane) macros -- retained for k_convq2 only.
// =====================================================================================
#define MM_COMPUTE2(Wbase, BF) \
  bf16x8 af[4][2]; \
  _Pragma("unroll") \
  for (int m=0;m<4;m++){ \
    _Pragma("unroll") \
    for (int s=0;s<2;s++) af[m][s] = cvt_w8((Wbase) + (m*16 + lm)*64 + s*32 + kg*8); \
  } \
  f32x4 acc[4][4]; \
  _Pragma("unroll") \
  for (int m=0;m<4;m++){ \
    _Pragma("unroll") \
    for (int e=0;e<4;e++){ f32x4 z = {0.f,0.f,0.f,0.f}; acc[m][e]=z; } \
  } \
  _Pragma("unroll") \
  for (int m=0;m<4;m++){ \
    _Pragma("unroll") \
    for (int e=0;e<4;e++){ \
      _Pragma("unroll") \
      for (int s=0;s<2;s++) acc[m][e] = MFMA16(af[m][s], BF[s][e], acc[m][e]); \
    } \
  }

#define MM_STORE_BF(outp) \
  _Pragma("unroll") \
  for (int m=0;m<4;m++){ \
    _Pragma("unroll") \
    for (int r=0;r<4;r++){ \
      int oc = m*16 + kg*4 + r; \
      st_bf4((outp) + ibase + ((i64)oc<<16) + 4*lm, acc[m][0][r], acc[m][1][r], acc[m][2][r], acc[m][3][r]); \
    } \
  }

#define MM_SETUP \
  int t = threadIdx.x; \
  int lane = t & 63, wvi = t >> 6; \
  i64 px0 = (i64)blockIdx.x*256 + wvi*64; \
  int b = (int)(px0 >> 16); \
  int p0 = (int)(px0 & (HW_-1)); \
  i64 ibase = ((i64)b<<22) + p0; \
  int lm = lane & 15, kg = lane >> 4;

// =====================================================================================
// X8 MM family: 8 px/lane, 128 px/wave, 16B loads+stores, per-m acc (32 VGPR).
// =====================================================================================
#define X8_SETUP \
  int t = threadIdx.x; \
  int lane = t & 63, wvi = t >> 6; \
  i64 px0 = (i64)blockIdx.x*512 + (i64)wvi*128; \
  int b = (int)(px0 >> 16); \
  int p0 = (int)(px0 & (HW_-1)); \
  i64 ibase = ((i64)b<<22) + p0; \
  int lm = lane & 15, kg = lane >> 4;

#define X8_FILL_F32(in_ptr) \
  _Pragma("unroll") \
  for (int s=0;s<2;s++){ \
    _Pragma("unroll") \
    for (int j=0;j<8;j++){ \
      const float* p_ = (in_ptr) + ((i64)(s*32 + kg*8 + j)<<16) + 8*lm; \
      float4 a_ = *(const float4*)p_; \
      float4 c_ = *(const float4*)(p_+4); \
      bf[s][0][j]=(__bf16)a_.x; bf[s][1][j]=(__bf16)a_.y; bf[s][2][j]=(__bf16)a_.z; bf[s][3][j]=(__bf16)a_.w; \
      bf[s][4][j]=(__bf16)c_.x; bf[s][5][j]=(__bf16)c_.y; bf[s][6][j]=(__bf16)c_.z; bf[s][7][j]=(__bf16)c_.w; \
    } \
  }

#define X8_FILL_BF(in_ptr) \
  _Pragma("unroll") \
  for (int s=0;s<2;s++){ \
    _Pragma("unroll") \
    for (int j=0;j<8;j++){ \
      bf16x8 u_ = *(const bf16x8*)((in_ptr) + ((i64)(s*32 + kg*8 + j)<<16) + 8*lm); \
      _Pragma("unroll") \
      for (int e=0;e<8;e++) bf[s][e][j] = u_[e]; \
    } \
  }

#define X8_ACC_M(Wbase, BF) \
  bf16x8 af0 = cvt_w8((Wbase) + (m*16 + lm)*64 + kg*8); \
  bf16x8 af1 = cvt_w8((Wbase) + (m*16 + lm)*64 + 32 + kg*8); \
  f32x4 acc[8]; \
  _Pragma("unroll") \
  for (int e=0;e<8;e++){ f32x4 z_ = {0.f,0.f,0.f,0.f}; acc[e]=z_; } \
  _Pragma("unroll") \
  for (int e=0;e<8;e++){ acc[e]=MFMA16(af0,BF[0][e],acc[e]); acc[e]=MFMA16(af1,BF[1][e],acc[e]); }

#define X8_ST_BF(outp) \
  _Pragma("unroll") \
  for (int r=0;r<4;r++){ \
    int oc = m*16 + kg*4 + r; \
    bf16x8 ov; \
    _Pragma("unroll") \
    for (int e=0;e<8;e++) ov[e]=(__bf16)acc[e][r]; \
    *(bf16x8*)((outp) + ibase + ((i64)oc<<16) + 8*lm) = ov; \
  }

#define X8_MM_BF(Wbase, BF, outp) \
  _Pragma("unroll") \
  for (int m=0;m<4;m++){ X8_ACC_M(Wbase, BF) X8_ST_BF(outp) }

// ---------------- fused: DFT recon (shared) -> BOTH high & low conv1x1 (4px/lane, bf16 xc) ----------------
__global__ __launch_bounds__(256) void k_convq2(const __bf16* __restrict__ xc, const float* __restrict__ coeff,
      const float* __restrict__ flag, const float* __restrict__ qwh, const float* __restrict__ qwl,
      __bf16* __restrict__ outh, __bf16* __restrict__ outl){
  __shared__ float tc[256], ts[256];
  {
    int tt = threadIdx.x;
    float ang = TWO_PI * ((float)tt/256.0f);
    tc[tt]=cosf(ang); ts[tt]=sinf(ang);
  }
  __syncthreads();
  MM_SETUP
  float fl = flag[b];
  int y = p0 >> 8;
  int xb = (p0 & 255) + 4*lm;
  float crow = tc[y], srow = ts[y];
  float cx[4], sx[4], cd[4], sd[4];
  #pragma unroll
  for (int e=0;e<4;e++){
    int xx = xb + e;
    cx[e]=tc[xx]; sx[e]=ts[xx];
    int d = (xx + y) & 255;
    cd[e]=tc[d]; sd[e]=ts[d];
  }
  bf16x8 bfh[2][4], bfl[2][4];
  #pragma unroll
  for (int s=0;s<2;s++){
    #pragma unroll
    for (int j=0;j<8;j++){
      int ch = s*32 + kg*8 + j;
      const float* cf = coeff + ((b<<6)+ch)*8;
      float4 ca = *(const float4*)cf;
      float4 cb = *(const float4*)(cf+4);
      float F00=ca.x, cR=ca.y, cI=ca.z, rR=ca.w, rI=cb.x, dR=cb.y, dI=cb.z;
      bf16x4 xr4 = *(const bf16x4*)(xc + ibase + ((i64)ch<<16) + 4*lm);
      float rowR = F00 + rR*crow + rI*srow;
      float rowI = rI*crow - rR*srow;
      #pragma unroll
      for (int e=0;e<4;e++){
        float re = rowR + cR*cx[e] + cI*sx[e] + dR*cd[e] + dI*sd[e];
        float im = rowI + cI*cx[e] - cR*sx[e] + dI*cd[e] - dR*sd[e];
        re*=fl; im*=fl;
        float vl = sqrtf(re*re+im*im);
        float hr = (float)xr4[e] - re;
        float vh = sqrtf(hr*hr + im*im);
        bfh[s][e][j] = (__bf16)vh;
        bfl[s][e][j] = (__bf16)vl;
      }
    }
  }
  {
    MM_COMPUTE2(qwh, bfh)
    MM_STORE_BF(outh)
  }
  {
    MM_COMPUTE2(qwl, bfl)
    MM_STORE_BF(outl)
  }
}

// ---------------- fused conv1x1 from y (X8): kv0, kv1, q2 -- one y read ----------------
__global__ __launch_bounds__(256) void k_kvq(const float* __restrict__ yin,
      const float* __restrict__ kvw0, const float* __restrict__ kvw1, const float* __restrict__ qw2,
      __bf16* __restrict__ k0o, __bf16* __restrict__ v0o,
      __bf16* __restrict__ k1o, __bf16* __restrict__ v1o, __bf16* __restrict__ q2o){
  X8_SETUP
  bf16x8 bf[2][8];
  X8_FILL_F32(yin + ibase)
  X8_MM_BF(kvw0,        bf, k0o)
  X8_MM_BF(kvw0 + 4096, bf, v0o)
  X8_MM_BF(kvw1,        bf, k1o)
  X8_MM_BF(kvw1 + 4096, bf, v1o)
  X8_MM_BF(qw2,         bf, q2o)
}

// ---------------- conv1x1 64->128 (X8, bf16 in) for cca2 ----------------
__global__ __launch_bounds__(256) void k_mm_kvb(const __bf16* __restrict__ in, const float* __restrict__ w,
      __bf16* __restrict__ kout, __bf16* __restrict__ vout){
  X8_SETUP
  bf16x8 bf[2][8];
  X8_FILL_BF(in + ibase)
  X8_MM_BF(w,        bf, kout)
  X8_MM_BF(w + 4096, bf, vout)
}

// ---------------- mconv high (X8): M x v + per-px channel max/mean ----------------
__global__ __launch_bounds__(256) void k_mm_hi(const __bf16* __restrict__ v, const float* __restrict__ M,
        float* __restrict__ mx, float* __restrict__ mn, __bf16* __restrict__ out){
  X8_SETUP
  bf16x8 bf[2][8];
  X8_FILL_BF(v + ibase)
  const float* Wb = M + ((i64)b<<12);
  float smx[8], ssum[8];
  #pragma unroll
  for (int e=0;e<8;e++){ smx[e]=-1e30f; ssum[e]=0.f; }
  #pragma unroll
  for (int m=0;m<4;m++){
    X8_ACC_M(Wb, bf)
    X8_ST_BF(out)
    #pragma unroll
    for (int r=0;r<4;r++){
      #pragma unroll
      for (int e=0;e<8;e++){ smx[e]=fmaxf(smx[e],acc[e][r]); ssum[e]+=acc[e][r]; }
    }
  }
  #pragma unroll
  for (int e=0;e<8;e++){
    smx[e] = fmaxf(smx[e], __shfl_xor(smx[e],16));
    smx[e] = fmaxf(smx[e], __shfl_xor(smx[e],32));
    ssum[e] += __shfl_xor(ssum[e],16);
    ssum[e] += __shfl_xor(ssum[e],32);
  }
  if (kg==0){
    i64 pbase = ((i64)b<<16) + p0 + 8*lm;
    *(float4*)(mx+pbase)   = make_float4(smx[0],smx[1],smx[2],smx[3]);
    *(float4*)(mx+pbase+4) = make_float4(smx[4],smx[5],smx[6],smx[7]);
    const float iv = 1.0f/64.0f;
    *(float4*)(mn+pbase)   = make_float4(ssum[0]*iv,ssum[1]*iv,ssum[2]*iv,ssum[3]*iv);
    *(float4*)(mn+pbase+4) = make_float4(ssum[4]*iv,ssum[5]*iv,ssum[6]*iv,ssum[7]*iv);
  }
}

// ---------------- mconv low (X8): M x v + per-channel sum/max partials ----------------
__global__ __launch_bounds__(256) void k_mm_lo(const __bf16* __restrict__ v, const float* __restrict__ M,
        __bf16* __restrict__ out, float* __restrict__ spart){
  __shared__ float ls[4][64], lmx[4][64];
  X8_SETUP
  bf16x8 bf[2][8];
  X8_FILL_BF(v + ibase)
  const float* Wb = M + ((i64)b<<12);
  #pragma unroll
  for (int m=0;m<4;m++){
    X8_ACC_M(Wb, bf)
    X8_ST_BF(out)
    #pragma unroll
    for (int r=0;r<4;r++){
      int oc = m*16 + kg*4 + r;
      float s = 0.f, mm = -1e30f;
      #pragma unroll
      for (int e=0;e<8;e++){ s += acc[e][r]; mm = fmaxf(mm, acc[e][r]); }
      #pragma unroll
      for (int off=8; off; off>>=1){ s += __shfl_xor(s,off); mm = fmaxf(mm,__shfl_xor(mm,off)); }
      if (lm==0){ ls[wvi][oc]=s; lmx[wvi][oc]=mm; }
    }
  }
  __syncthreads();
  if (t<64){
    float s = ls[0][t]+ls[1][t]+ls[2][t]+ls[3][t];
    float mm = fmaxf(fmaxf(lmx[0][t],lmx[1][t]),fmaxf(lmx[2][t],lmx[3][t]));
    spart[(i64)blockIdx.x*128 + t*2]   = s;
    spart[(i64)blockIdx.x*128 + t*2+1] = mm;
  }
}

// ---------------- fused comb + refine conv1x1 (X8, bf16 in/out) ----------------
__global__ __launch_bounds__(256) void k_mm_comb(const __bf16* __restrict__ lo2, const __bf16* __restrict__ hi2,
        const float* __restrict__ swb, const float* __restrict__ cwv,
        const float* __restrict__ w, const float* __restrict__ bias, __bf16* __restrict__ out){
  X8_SETUP
  const float* swp = swb + ((i64)b<<16) + p0 + 8*lm;
  float4 sw0 = *(const float4*)swp;
  float4 sw1 = *(const float4*)(swp+4);
  float swv[8] = {sw0.x,sw0.y,sw0.z,sw0.w,sw1.x,sw1.y,sw1.z,sw1.w};
  bf16x8 bf[2][8];
  #pragma unroll
  for (int s=0;s<2;s++){
    #pragma unroll
    for (int j=0;j<8;j++){
      int ch = s*32 + kg*8 + j;
      bf16x8 l8 = *(const bf16x8*)(lo2 + ibase + ((i64)ch<<16) + 8*lm);
      bf16x8 h8 = *(const bf16x8*)(hi2 + ibase + ((i64)ch<<16) + 8*lm);
      float cw = cwv[(b<<6) + ch];
      #pragma unroll
      for (int e=0;e<8;e++) bf[s][e][j] = (__bf16)((float)l8[e]*swv[e] + (float)h8[e]*cw);
    }
  }
  #pragma unroll
  for (int m=0;m<4;m++){
    X8_ACC_M(w, bf)
    #pragma unroll
    for (int r=0;r<4;r++){
      int oc = m*16 + kg*4 + r;
      float bv = bias[oc];
      bf16x8 ov;
      #pragma unroll
      for (int e=0;e<8;e++) ov[e]=(__bf16)(acc[e][r]+bv);
      *(bf16x8*)(out + ibase + ((i64)oc<<16) + 8*lm) = ov;
    }
  }
}

// ---------------- final mconv (X8): M x v, *para1 + y*para2, fp32 out ----------------
__global__ __launch_bounds__(256) void k_mm_fin(const __bf16* __restrict__ v, const float* __restrict__ M,
      const float* __restrict__ para1, const float* __restrict__ para2,
      const float* __restrict__ yin, float* __restrict__ out){
  X8_SETUP
  bf16x8 bf[2][8];
  X8_FILL_BF(v + ibase)
  const float* Wb = M + ((i64)b<<12);
  #pragma unroll
  for (int m=0;m<4;m++){
    X8_ACC_M(Wb, bf)
    #pragma unroll
    for (int r=0;r<4;r++){
      int oc = m*16 + kg*4 + r;
      float p1 = para1[oc], p2 = para2[oc];
      const float* yp = yin + ibase + ((i64)oc<<16) + 8*lm;
      float4 y0 = *(const float4*)yp;
      float4 y1 = *(const float4*)(yp+4);
      float* op = out + ibase + ((i64)oc<<16) + 8*lm;
      *(float4*)op     = make_float4(acc[0][r]*p1+y0.x*p2, acc[1][r]*p1+y0.y*p2,
                                     acc[2][r]*p1+y0.z*p2, acc[3][r]*p1+y0.w*p2);
      *(float4*)(op+4) = make_float4(acc[4][r]*p1+y1.x*p2, acc[5][r]*p1+y1.y*p2,
                                     acc[6][r]*p1+y1.z*p2, acc[7][r]*p1+y1.w*p2);
    }
  }
}

// ---------------- Gram-MFMA stats w/ LDS row staging, merged double-set dispatch ----------------
// Block stages full rows (16 planes x 512B, coalesced 512B runs) into double-buffered
// padded LDS ([16][264] bf16, 528B stride); lanes read their channel window from LDS.
// Same conv math + MFMA order as direct version -> identical stats.
__global__ __launch_bounds__(256) void k_gram(const __bf16* __restrict__ q0, const __bf16* __restrict__ kk0,
        const __bf16* __restrict__ q1, const __bf16* __restrict__ kk1,
        const float* __restrict__ qdw0, const float* __restrict__ kdw0,
        const float* __restrict__ qdw1, const float* __restrict__ kdw1,
        float* __restrict__ part, int hgrid){
  __shared__ __bf16 lds[2][16][264];
  __shared__ float red[4][16][16];
  int bx = blockIdx.x;
  int set = (bx >= hgrid) ? 1 : 0;
  int blk = bx - set*hgrid;
  const __bf16* qpre = set ? q1 : q0;
  const __bf16* kpre = set ? kk1 : kk0;
  const float* qdw = set ? qdw1 : qdw0;
  const float* kdw = set ? kdw1 : kdw0;
  float* ppart = part + (i64)set*hgrid*80;
  int rowblk = blk & 15;
  int bh = blk >> 4;
  int h = bh & 7, b = bh >> 3;
  int t = threadIdx.x;
  int lane = t & 63, wvi = t >> 6;
  int lm = lane & 15, kg = lane >> 4;
  // compute-side weights for channel lm
  const float* wp = (lm < 8 ? qdw : kdw) + h*72 + (lm&7)*9;
  float w0=wp[0],w1=wp[1],w2=wp[2],w3=wp[3],w4=wp[4],w5=wp[5],w6=wp[6],w7=wp[7],w8=wp[8];
  // staging-side plane pointer for thread's plane p = t>>4
  int p = t >> 4, seg = t & 15;
  const __bf16* plbase = (p < 8 ? qpre : kpre) + (((i64)((b<<6)+(h<<3)+(p&7)))<<16);
  int R0 = rowblk*16;

  // rolling state per chunk (cc)
  float h0c[2][8], h1c[2][8];
  #pragma unroll
  for (int cc=0;cc<2;cc++)
    #pragma unroll
    for (int e=0;e<8;e++){ h0c[cc][e]=0.f; h1c[cc][e]=0.f; }
  f32x4 acc = {0.f,0.f,0.f,0.f};

  // stage row ir into buffer bi
  auto stage = [&](int bi, int ir){
    __bf16* dst = &lds[bi][p][seg*16];
    if ((unsigned)ir < 256u){
      const __bf16* src = plbase + ir*256 + seg*16;
      bf16x8 a = *(const bf16x8*)src;
      bf16x8 c = *(const bf16x8*)(src+8);
      *(bf16x8*)dst = a; *(bf16x8*)(dst+8) = c;
    } else {
      bf16x8 z = {};
      *(bf16x8*)dst = z; *(bf16x8*)(dst+8) = z;
    }
  };

  stage(0, R0-1);
  __syncthreads();
  int buf = 0;
  for (int ir = R0-1; ir <= R0+16; ir++){
    if (ir < R0+16) stage(buf^1, ir+1);
    const __bf16* rowp = &lds[buf][lm][0];
    #pragma unroll
    for (int cc=0; cc<2; cc++){
      int xb = (wvi*2 + cc)*32 + kg*8;
      bf16x8 mid = *(const bf16x8*)(rowp + xb);
      float win[10];
      win[0] = (xb==0)   ? 0.f : (float)rowp[xb-1];
      #pragma unroll
      for (int w=1; w<9; w++) win[w] = (float)mid[w-1];
      win[9] = (xb==248) ? 0.f : (float)rowp[xb+8];
      float o[8];
      #pragma unroll
      for (int e=0;e<8;e++){
        float t0 = w0*win[e] + w1*win[e+1] + w2*win[e+2];
        float t1 = w3*win[e] + w4*win[e+1] + w5*win[e+2];
        float t2 = w6*win[e] + w7*win[e+1] + w8*win[e+2];
        o[e] = h0c[cc][e] + t2;
        h0c[cc][e] = h1c[cc][e] + t1;
        h1c[cc][e] = t0;
      }
      if (ir > R0){
        bf16x8 xf;
        #pragma unroll
        for (int e=0;e<8;e++) xf[e] = (__bf16)o[e];
        acc = MFMA16(xf, xf, acc);
      }
    }
    __syncthreads();
    buf ^= 1;
  }
  #pragma unroll
  for (int r=0;r<4;r++) red[wvi][kg*4+r][lm] = acc[r];
  __syncthreads();
  if (t < 80){
    int r, c;
    if (t < 64){ r = t>>3; c = 8 + (t&7); }
    else if (t < 72){ r = t-64; c = r; }
    else { r = 8 + (t-72); c = r; }
    float s = red[0][r][c]+red[1][r][c]+red[2][r][c]+red[3][r][c];
    ppart[(i64)blk*80 + t] = s;
  }
}

__global__ __launch_bounds__(128) void k_stats_fin(const float* __restrict__ part, float* __restrict__ stats){
  int bh = blockIdx.x; int t = threadIdx.x;
  if (t < 80){
    float s=0.f;
    for (int c=0;c<NCHUNK;c++) s += part[((i64)bh*NCHUNK+c)*80 + t];
    stats[bh*80+t] = s;
  }
}

// ---------------- softmax + fold attn into 64x64 M (merged: super-b over 2 sets) ----------------
__global__ __launch_bounds__(64) void k_attn_m(const float* __restrict__ stats, const float* __restrict__ temp,
                         const float* __restrict__ projw, float* __restrict__ M, int nb){
  __shared__ float attn[8][8][8];
  int bsup = blockIdx.x; int t = threadIdx.x;
  int set = (bsup >= nb) ? 1 : 0;
  int h = t >> 3, cc = t & 7;
  const float* st = stats + (bsup*8+h)*80;
  float nq = fmaxf(sqrtf(st[64+cc]), 1e-12f);
  float tmp = temp[set*8 + h];
  const float* pw = projw + set*4096;
  float s[8];
  float mx = -1e30f;
  #pragma unroll
  for (int d=0;d<8;d++){
    float nk = fmaxf(sqrtf(st[72+d]), 1e-12f);
    s[d] = st[cc*8+d]/(nq*nk)*tmp;
    mx = fmaxf(mx, s[d]);
  }
  float sum=0.f;
  #pragma unroll
  for (int d=0;d<8;d++){ s[d]=expf(s[d]-mx); sum+=s[d]; }
  float inv = 1.0f/sum;
  #pragma unroll
  for (int d=0;d<8;d++) attn[h][cc][d] = s[d]*inv;
  __syncthreads();
  int o = t;
  for (int hh=0; hh<8; hh++){
    #pragma unroll
    for (int d=0; d<8; d++){
      float acc=0.f;
      #pragma unroll
      for (int c2=0;c2<8;c2++) acc += pw[o*64 + hh*8 + c2]*attn[hh][c2][d];
      M[((i64)bsup*64 + o)*64 + hh*8 + d] = acc;
    }
  }
}

// ---------------- depthwise 3x3 (v path), merged double-set dispatch ----------------
__global__ __launch_bounds__(256) void k_dwb(const __bf16* __restrict__ in0, const __bf16* __restrict__ in1,
        const float* __restrict__ wd0, const float* __restrict__ wd1,
        __bf16* __restrict__ out0, __bf16* __restrict__ out1, int hgrid){
  int bx = blockIdx.x;
  int set = (bx >= hgrid) ? 1 : 0;
  int blk = bx - set*hgrid;
  const __bf16* in = set ? in1 : in0;
  const float* wd = set ? wd1 : wd0;
  __bf16* out = set ? out1 : out0;
  int half = blk & 1; int c = (blk>>1)&63; int b = blk>>7;
  int t = threadIdx.x;
  int strip = t & 31, rg = t >> 5;
  const __bf16* ip = in + (((i64)((b<<6)+c))<<16);
  __bf16* op = out + (((i64)((b<<6)+c))<<16);
  const float* wp = wd + c*9;
  float w0=wp[0],w1=wp[1],w2=wp[2],w3=wp[3],w4=wp[4],w5=wp[5],w6=wp[6],w7=wp[7],w8=wp[8];
  int R0 = half*128 + rg*16;
  int xb = strip*8;
  bool left = (xb==0), right = (xb==248);
  float h0[8], h1[8];
  #pragma unroll
  for (int e=0;e<8;e++){ h0[e]=0.f; h1[e]=0.f; }
  for (int ir = R0-1; ir <= R0+16; ir++){
    bool rok = ((unsigned)ir < 256u);
    float win[10];
    if (rok){
      const __bf16* rp = ip + ir*256 + xb;
      bf16x8 mid = *(const bf16x8*)rp;
      win[0] = left ? 0.f : (float)rp[-1];
      #pragma unroll
      for (int w=1; w<9; w++) win[w] = (float)mid[w-1];
      win[9] = right ? 0.f : (float)rp[8];
    } else {
      #pragma unroll
      for (int w=0; w<10; w++) win[w] = 0.f;
    }
    float o[8];
    #pragma unroll
    for (int e=0;e<8;e++){
      float t0 = w0*win[e] + w1*win[e+1] + w2*win[e+2];
      float t1 = w3*win[e] + w4*win[e+1] + w5*win[e+2];
      float t2 = w6*win[e] + w7*win[e+1] + w8*win[e+2];
      o[e] = h0[e] + t2;
      h0[e] = h1[e] + t1;
      h1[e] = t0;
    }
    if (ir > R0){
      bf16x8 ov;
      #pragma unroll
      for (int e=0;e<8;e++) ov[e] = (__bf16)o[e];
      *(bf16x8*)(op + (ir-1)*256 + xb) = ov;
    }
  }
}

// ---------------- refine small kernels ----------------
__global__ __launch_bounds__(64) void k_spatfin(const float* __restrict__ spart, float* __restrict__ lmean, float* __restrict__ lmax){
  int b = blockIdx.x; int c = threadIdx.x;
  float s=0.f, m=-1e30f;
  for (int r=0;r<128;r++){
    s += spart[(i64)(b*128+r)*128 + c*2];
    m = fmaxf(m, spart[(i64)(b*128+r)*128 + c*2+1]);
  }
  lmean[b*64+c] = s*(1.0f/65536.0f);
  lmax[b*64+c]  = m;
}

__global__ __launch_bounds__(64) void k_cw(const float* __restrict__ mean, const float* __restrict__ mxv,
                     const float* __restrict__ w1, const float* __restrict__ w2, float* __restrict__ cw){
  __shared__ float ha[4], hm[4];
  int b = blockIdx.x; int t = threadIdx.x;
  if (t < 4){
    float sa=0.f, sm_=0.f;
    for (int c=0;c<64;c++){ sa += w1[t*64+c]*mean[b*64+c]; sm_ += w1[t*64+c]*mxv[b*64+c]; }
    ha[t] = fmaxf(sa, 0.f); hm[t] = fmaxf(sm_, 0.f);
  }
  __syncthreads();
  float a=0.f;
  #pragma unroll
  for (int j=0;j<4;j++) a += w2[t*4+j]*(ha[j]+hm[j]);
  cw[b*64+t] = sigm(a);
}

__global__ __launch_bounds__(256) void k_sw(const float* __restrict__ mx, const float* __restrict__ mn,
                     const float* __restrict__ w, float* __restrict__ sw){
  int row = blockIdx.x & 255; int b = blockIdx.x >> 8; int t = threadIdx.x;
  const float* m0 = mx + ((i64)b<<16);
  const float* m1 = mn + ((i64)b<<16);
  float acc=0.f;
  for (int ky=0;ky<7;ky++){
    int yy = row+ky-3; if ((unsigned)yy>255u) continue;
    for (int kx=0;kx<7;kx++){
      int xx = t+kx-3; if ((unsigned)xx>255u) continue;
      acc += w[ky*7+kx]*m0[yy*256+xx] + w[49+ky*7+kx]*m1[yy*256+xx];
    }
  }
  sw[((i64)b<<16) + row*256 + t] = sigm(acc);
}

// =====================================================================================
extern "C" void kernel_launch(void* const* d_in, const int* in_sizes, int n_in,
                              void* d_out, int out_size, void* d_ws, size_t ws_size,
                              hipStream_t stream){
  const float* x      = (const float*)d_in[0];
  const float* y      = (const float*)d_in[1];
  const float* conv1w = (const float*)d_in[2];
  const float* ratew1 = (const float*)d_in[3];
  const float* ratew2 = (const float*)d_in[4];
  const float* temp   = (const float*)d_in[5];
  const float* qw     = (const float*)d_in[6];
  const float* qdw    = (const float*)d_in[7];
  const float* kvw    = (const float*)d_in[8];
  const float* kvdw   = (const float*)d_in[9];
  const float* projw  = (const float*)d_in[10];
  const float* spw    = (const float*)d_in[11];
  const float* cgw1   = (const float*)d_in[12];
  const float* cgw2   = (const float*)d_in[13];
  const float* rprojw = (const float*)d_in[14];
  const float* rprojb = (const float*)d_in[15];
  const float* para1  = (const float*)d_in[16];
  const float* para2  = (const float*)d_in[17];
  float* D = (float*)d_out;

  // pick largest batch-group size whose footprint fits: 3 big units + pool
  int nb = 8;
  for (;;){
    size_t unit = (size_t)nb*64*HW_;
    size_t pool = (size_t)nb*3*HW_            // Rbuf
                + (size_t)nb*512 + (size_t)nb*64 + 64
                + 2*(size_t)nb*8*NCHUNK*80    // part (2 sets)
                + 2*(size_t)nb*8*80           // stats (2 sets)
                + 2*(size_t)nb*64*64          // M (2 sets)
                + 3*(size_t)nb*HW_            // mxmap, mnmap, swb
                + (size_t)nb*128*128          // spart
                + 3*(size_t)nb*64;            // lmean, lmax, cwb
    if ((3*unit + pool)*sizeof(float) <= ws_size || nb==1) break;
    nb >>= 1;
  }

  size_t unit = (size_t)nb*64*HW_;
  float* U0 = (float*)d_ws;
  float* U1 = U0 + unit;
  float* U2 = U1 + unit;
  float* sm = U2 + unit;
  float* Rbuf  = sm;  sm += (size_t)nb*3*HW_;
  float* coeff = sm;  sm += (size_t)nb*512;
  float* pooled= sm;  sm += (size_t)nb*64;
  float* flagb = sm;  sm += 64;
  float* part  = sm;  sm += 2*(size_t)nb*8*NCHUNK*80;
  float* stats = sm;  sm += 2*(size_t)nb*8*80;
  float* Mb    = sm;  sm += 2*(size_t)nb*64*64;
  float* mxmap = sm;  sm += (size_t)nb*HW_;
  float* mnmap = sm;  sm += (size_t)nb*HW_;
  float* swb   = sm;  sm += (size_t)nb*HW_;
  float* spart = sm;  sm += (size_t)nb*128*128;
  float* lmean = sm;  sm += (size_t)nb*64;
  float* lmax  = sm;  sm += (size_t)nb*64;
  float* cwb   = sm;  sm += (size_t)nb*64;

  int hgr = nb*8*NCHUNK;     // gram half-grid
  int hdw = nb*128;          // dwb half-grid

  for (int b0 = 0; b0 < 8; b0 += nb){
    const float* yg = y + (i64)b0*64*HW_;
    float*       Dg = D + (i64)b0*64*HW_;
    // bf16 tensor slots: each fp32 unit region holds TWO bf16 tensors of `unit` elements.
    __bf16* U0a = (__bf16*)U0; __bf16* U0c = U0a + unit;
    __bf16* U1a = (__bf16*)U1; __bf16* U1c = U1a + unit;
    __bf16* U2a = (__bf16*)U2; __bf16* U2c = U2a + unit;
    __bf16* Dga = (__bf16*)Dg; __bf16* Dgc = Dga + unit;
    float* Mb1 = Mb + (i64)nb*4096;

    // frontend (xc now bf16 in U0a)
    k_resize <<<nb*3*256, 256,0,stream>>>(x, Rbuf, b0);
    k_conv3  <<<nb*256,   256,0,stream>>>(Rbuf, conv1w, U0a);          // xc = U0a (bf16)
    k_dft    <<<nb*64,    256,0,stream>>>(U0a, coeff, pooled);
    k_thr    <<<nb,       64, 0,stream>>>(pooled, ratew1, ratew2, flagb);

    // fused q-recon (cca0-high + cca1-low); xc dead after
    k_convq2 <<<nb*256,256,0,stream>>>(U0a, coeff, flagb, qw + 0*4096, qw + 1*4096, U1a, U1c); // qh=U1a, ql=U1c
    // fused y-matmuls (X8): kv0, kv1, q2-pre
    k_kvq    <<<nb*128,256,0,stream>>>(yg, kvw + 0*8192, kvw + 1*8192, qw + 2*4096,
                                       U2a, Dga, U2c, Dgc, U0c);       // k0,v0,k1,v1,q2

    // merged cca0+cca1 stats pipeline
    k_gram   <<<2*hgr,256,0,stream>>>(U1a, U2a, U1c, U2c,
                                      qdw + 0*576, kvdw + 0*1152, qdw + 1*576, kvdw + 1*1152,
                                      part, hgr);                      // [qh,ql,k0,k1 dead]
    k_stats_fin<<<2*nb*8, 128,0,stream>>>(part, stats);
    k_dwb    <<<2*hdw,256,0,stream>>>(Dga, Dgc, kvdw + 0*1152 + 576, kvdw + 1*1152 + 576,
                                      U1a, U1c, hdw);                  // v0'=U1a, v1'=U1c [v0,v1 dead]
    k_attn_m <<<2*nb, 64,0,stream>>>(stats, temp, projw, Mb, nb);      // Mb0, Mb1

    k_mm_hi  <<<nb*128,256,0,stream>>>(U1a, Mb,  mxmap, mnmap, Dga);   // high2=Dga
    k_mm_lo  <<<nb*128,256,0,stream>>>(U1c, Mb1, Dgc, spart);          // low2=Dgc

    // refine: high2=Dga, low2=Dgc -> agg=U0a
    k_spatfin <<<nb,     64, 0,stream>>>(spart, lmean, lmax);
    k_cw      <<<nb,     64, 0,stream>>>(lmean, lmax, cgw1, cgw2, cwb);
    k_sw      <<<nb*256, 256,0,stream>>>(mxmap, mnmap, spw, swb);
    k_mm_comb<<<nb*128,256,0,stream>>>(Dgc, Dga, swb, cwb, rprojw, rprojb, U0a);  // agg=U0a

    // cca2 (q2=U0c, kv from agg=U0a)
    k_mm_kvb <<<nb*128,256,0,stream>>>(U0a, kvw + 2*8192, U2a, U2c);   // k2=U2a, v2=U2c
    k_gram   <<<hgr,256,0,stream>>>(U0c, U2a, U0c, U2a,
                                    qdw + 2*576, kvdw + 2*1152, qdw + 2*576, kvdw + 2*1152,
                                    part, hgr);
    k_stats_fin<<<nb*8, 128,0,stream>>>(part, stats);
    k_dwb    <<<hdw,256,0,stream>>>(U2c, U2c, kvdw + 2*1152 + 576, kvdw + 2*1152 + 576,
                                    U1a, U1a, hdw);                    // v'=U1a
    k_attn_m <<<nb, 64,0,stream>>>(stats, temp + 2*8, projw + 2*4096, Mb, nb);
    k_mm_fin <<<nb*128,256,0,stream>>>(U1a, Mb, para1, para2, yg, Dg); // out fp32
  }
}

// Round 10
// 749.018 us; speedup vs baseline: 7.0604x; 1.0337x over previous
//
#include <hip/hip_runtime.h>
#include <math.h>

#define HW_ 65536
#define NCHUNK 16
typedef long long i64;
#define TWO_PI 6.283185307179586476925f

typedef __bf16 bf16x8 __attribute__((ext_vector_type(8)));
typedef __bf16 bf16x4 __attribute__((ext_vector_type(4)));
typedef float f32x4 __attribute__((ext_vector_type(4)));

#define MFMA16(A,B,C) __builtin_amdgcn_mfma_f32_16x16x32_bf16(A,B,C,0,0,0)

__device__ __forceinline__ float sigm(float x){ return 1.0f/(1.0f+expf(-x)); }

// convert 8 consecutive fp32 to a bf16x8 A-fragment
__device__ __forceinline__ bf16x8 cvt_w8(const float* wp){
  float4 w0 = *(const float4*)wp;
  float4 w1 = *(const float4*)(wp+4);
  bf16x8 r;
  r[0]=(__bf16)w0.x; r[1]=(__bf16)w0.y; r[2]=(__bf16)w0.z; r[3]=(__bf16)w0.w;
  r[4]=(__bf16)w1.x; r[5]=(__bf16)w1.y; r[6]=(__bf16)w1.z; r[7]=(__bf16)w1.w;
  return r;
}

__device__ __forceinline__ void st_bf4(__bf16* p, float a, float b, float c, float d){
  bf16x4 v; v[0]=(__bf16)a; v[1]=(__bf16)b; v[2]=(__bf16)c; v[3]=(__bf16)d;
  *(bf16x4*)p = v;
}

// ---------------- resize (nb,3,128,128) -> (nb,3,256,256) bilinear half-pixel ----------------
__global__ __launch_bounds__(256) void k_resize(const float* __restrict__ x, float* __restrict__ R, int b0){
  int idx = blockIdx.x*256 + threadIdx.x;
  int ox = idx & 255;
  int oy = (idx >> 8) & 255;
  int bc = idx >> 16;                               // lb*3 + c
  int lb = bc/3; int c = bc - lb*3;
  float sx = ox*0.5f - 0.25f;
  float sy = oy*0.5f - 0.25f;
  int x0 = (int)floorf(sx); float fx = sx - (float)x0;
  int y0 = (int)floorf(sy); float fy = sy - (float)y0;
  int x1 = min(x0+1,127); int y1 = min(y0+1,127);
  x0 = max(x0,0); y0 = max(y0,0);
  const float* p = x + ((i64)(b0+lb)*3 + c)*16384;
  float v00=p[y0*128+x0], v01=p[y0*128+x1], v10=p[y1*128+x0], v11=p[y1*128+x1];
  R[idx] = (1.0f-fy)*((1.0f-fx)*v00 + fx*v01) + fy*((1.0f-fx)*v10 + fx*v11);
}

// ---------------- conv3x3 3->64 (bf16 out): block per (b,row), all 64 outs per thread ----------------
__global__ __launch_bounds__(256) void k_conv3(const float* __restrict__ R, const float* __restrict__ w, __bf16* __restrict__ out){
  int y = blockIdx.x & 255; int b = blockIdx.x >> 8; int t = threadIdx.x;
  float win[27];
  #pragma unroll
  for (int ci=0;ci<3;ci++){
    #pragma unroll
    for (int ky=0;ky<3;ky++){
      int yy = y+ky-1;
      const float* ip = R + (((i64)(b*3+ci))<<16) + yy*256;
      #pragma unroll
      for (int kx=0;kx<3;kx++){
        int xx = t+kx-1;
        float v = 0.f;
        if ((unsigned)yy<256u && (unsigned)xx<256u) v = ip[xx];
        win[ci*9+ky*3+kx] = v;
      }
    }
  }
  i64 obase = ((i64)b<<22) + (y<<8) + t;
  for (int o=0;o<64;o++){
    const float* wp = w + o*27;
    float acc=0.f;
    #pragma unroll
    for (int j=0;j<27;j++) acc += wp[j]*win[j];
    out[obase + ((i64)o<<16)] = (__bf16)acc;
  }
}

// ---------------- DFT coeffs (7 reals incl. DC) + pooled mean per (b,c), bf16 in ----------------
__global__ __launch_bounds__(256) void k_dft(const __bf16* __restrict__ xc, float* __restrict__ coeff, float* __restrict__ pooled){
  __shared__ float tc[256], ts[256];
  __shared__ float red[256];
  int t = threadIdx.x;
  float ang = TWO_PI * ((float)t/256.0f);
  tc[t] = cosf(ang); ts[t] = sinf(ang);
  __syncthreads();
  int bc = blockIdx.x;
  const __bf16* p = xc + (i64)bc*HW_;
  float s=0, cr=0, ci=0, rr=0, ri=0, dr=0, di=0;
  for (int i=t; i<HW_; i+=256){
    float v = (float)p[i];
    int col = i & 255, row = i >> 8, ds = (row+col)&255;
    s  += v;
    cr += v*tc[col]; ci += v*ts[col];
    rr += v*tc[row]; ri += v*ts[row];
    dr += v*tc[ds];  di += v*ts[ds];
  }
  float vals[7] = {s,cr,ci,rr,ri,dr,di};
  for (int j=0;j<7;j++){
    red[t] = vals[j]; __syncthreads();
    for (int st=128; st>0; st>>=1){ if (t<st) red[t]+=red[t+st]; __syncthreads(); }
    if (t==0) vals[j] = red[0];
    __syncthreads();
  }
  if (t==0){
    const float sc = 1.0f/65536.0f;
    for (int j=0;j<7;j++) coeff[bc*8+j] = vals[j]*sc;
    pooled[bc] = vals[0]*sc;
  }
}

// ---------------- threshold MLP -> per-batch mask flag ----------------
__global__ __launch_bounds__(64) void k_thr(const float* __restrict__ pooled, const float* __restrict__ w1,
                      const float* __restrict__ w2, float* __restrict__ flag){
  __shared__ float hid[8];
  int b = blockIdx.x; int t = threadIdx.x;
  if (t < 8){
    float a = 0.f;
    for (int c=0;c<64;c++) a += pooled[b*64+c]*w1[t*64+c];
    hid[t] = 0.5f*a*(1.0f+erff(a*0.70710678118654752440f));
  }
  __syncthreads();
  if (t==0){
    float t0=0,t1=0;
    for (int k=0;k<8;k++){ t0 += hid[k]*w2[k]; t1 += hid[k]*w2[8+k]; }
    int h_ = (int)(2.0f*sigm(t0));
    int w_ = (int)(2.0f*sigm(t1));
    flag[b] = (h_>0 && w_>0) ? 1.0f : 0.0f;
  }
}

// =====================================================================================
// MM (4px/lane) macros -- retained for k_convq2 only.
// =====================================================================================
#define MM_COMPUTE2(Wbase, BF) \
  bf16x8 af[4][2]; \
  _Pragma("unroll") \
  for (int m=0;m<4;m++){ \
    _Pragma("unroll") \
    for (int s=0;s<2;s++) af[m][s] = cvt_w8((Wbase) + (m*16 + lm)*64 + s*32 + kg*8); \
  } \
  f32x4 acc[4][4]; \
  _Pragma("unroll") \
  for (int m=0;m<4;m++){ \
    _Pragma("unroll") \
    for (int e=0;e<4;e++){ f32x4 z = {0.f,0.f,0.f,0.f}; acc[m][e]=z; } \
  } \
  _Pragma("unroll") \
  for (int m=0;m<4;m++){ \
    _Pragma("unroll") \
    for (int e=0;e<4;e++){ \
      _Pragma("unroll") \
      for (int s=0;s<2;s++) acc[m][e] = MFMA16(af[m][s], BF[s][e], acc[m][e]); \
    } \
  }

#define MM_STORE_BF(outp) \
  _Pragma("unroll") \
  for (int m=0;m<4;m++){ \
    _Pragma("unroll") \
    for (int r=0;r<4;r++){ \
      int oc = m*16 + kg*4 + r; \
      st_bf4((outp) + ibase + ((i64)oc<<16) + 4*lm, acc[m][0][r], acc[m][1][r], acc[m][2][r], acc[m][3][r]); \
    } \
  }

#define MM_SETUP \
  int t = threadIdx.x; \
  int lane = t & 63, wvi = t >> 6; \
  i64 px0 = (i64)blockIdx.x*256 + wvi*64; \
  int b = (int)(px0 >> 16); \
  int p0 = (int)(px0 & (HW_-1)); \
  i64 ibase = ((i64)b<<22) + p0; \
  int lm = lane & 15, kg = lane >> 4;

// =====================================================================================
// X8 MM family: 8 px/lane, 128 px/wave, 16B loads+stores, per-m acc (32 VGPR).
// =====================================================================================
#define X8_SETUP_BLK(BLK) \
  int t = threadIdx.x; \
  int lane = t & 63, wvi = t >> 6; \
  i64 px0 = (i64)(BLK)*512 + (i64)wvi*128; \
  int b = (int)(px0 >> 16); \
  int p0 = (int)(px0 & (HW_-1)); \
  i64 ibase = ((i64)b<<22) + p0; \
  int lm = lane & 15, kg = lane >> 4;

#define X8_SETUP X8_SETUP_BLK(blockIdx.x)

#define X8_FILL_F32(in_ptr) \
  _Pragma("unroll") \
  for (int s=0;s<2;s++){ \
    _Pragma("unroll") \
    for (int j=0;j<8;j++){ \
      const float* p_ = (in_ptr) + ((i64)(s*32 + kg*8 + j)<<16) + 8*lm; \
      float4 a_ = *(const float4*)p_; \
      float4 c_ = *(const float4*)(p_+4); \
      bf[s][0][j]=(__bf16)a_.x; bf[s][1][j]=(__bf16)a_.y; bf[s][2][j]=(__bf16)a_.z; bf[s][3][j]=(__bf16)a_.w; \
      bf[s][4][j]=(__bf16)c_.x; bf[s][5][j]=(__bf16)c_.y; bf[s][6][j]=(__bf16)c_.z; bf[s][7][j]=(__bf16)c_.w; \
    } \
  }

#define X8_FILL_BF(in_ptr) \
  _Pragma("unroll") \
  for (int s=0;s<2;s++){ \
    _Pragma("unroll") \
    for (int j=0;j<8;j++){ \
      bf16x8 u_ = *(const bf16x8*)((in_ptr) + ((i64)(s*32 + kg*8 + j)<<16) + 8*lm); \
      _Pragma("unroll") \
      for (int e=0;e<8;e++) bf[s][e][j] = u_[e]; \
    } \
  }

#define X8_ACC_M(Wbase, BF) \
  bf16x8 af0 = cvt_w8((Wbase) + (m*16 + lm)*64 + kg*8); \
  bf16x8 af1 = cvt_w8((Wbase) + (m*16 + lm)*64 + 32 + kg*8); \
  f32x4 acc[8]; \
  _Pragma("unroll") \
  for (int e=0;e<8;e++){ f32x4 z_ = {0.f,0.f,0.f,0.f}; acc[e]=z_; } \
  _Pragma("unroll") \
  for (int e=0;e<8;e++){ acc[e]=MFMA16(af0,BF[0][e],acc[e]); acc[e]=MFMA16(af1,BF[1][e],acc[e]); }

#define X8_ST_BF(outp) \
  _Pragma("unroll") \
  for (int r=0;r<4;r++){ \
    int oc = m*16 + kg*4 + r; \
    bf16x8 ov; \
    _Pragma("unroll") \
    for (int e=0;e<8;e++) ov[e]=(__bf16)acc[e][r]; \
    *(bf16x8*)((outp) + ibase + ((i64)oc<<16) + 8*lm) = ov; \
  }

#define X8_MM_BF(Wbase, BF, outp) \
  _Pragma("unroll") \
  for (int m=0;m<4;m++){ X8_ACC_M(Wbase, BF) X8_ST_BF(outp) }

// ---------------- fused: DFT recon (shared) -> BOTH high & low conv1x1 (4px/lane, bf16 xc) ----------------
__global__ __launch_bounds__(256) void k_convq2(const __bf16* __restrict__ xc, const float* __restrict__ coeff,
      const float* __restrict__ flag, const float* __restrict__ qwh, const float* __restrict__ qwl,
      __bf16* __restrict__ outh, __bf16* __restrict__ outl){
  __shared__ float tc[256], ts[256];
  {
    int tt = threadIdx.x;
    float ang = TWO_PI * ((float)tt/256.0f);
    tc[tt]=cosf(ang); ts[tt]=sinf(ang);
  }
  __syncthreads();
  MM_SETUP
  float fl = flag[b];
  int y = p0 >> 8;
  int xb = (p0 & 255) + 4*lm;
  float crow = tc[y], srow = ts[y];
  float cx[4], sx[4], cd[4], sd[4];
  #pragma unroll
  for (int e=0;e<4;e++){
    int xx = xb + e;
    cx[e]=tc[xx]; sx[e]=ts[xx];
    int d = (xx + y) & 255;
    cd[e]=tc[d]; sd[e]=ts[d];
  }
  bf16x8 bfh[2][4], bfl[2][4];
  #pragma unroll
  for (int s=0;s<2;s++){
    #pragma unroll
    for (int j=0;j<8;j++){
      int ch = s*32 + kg*8 + j;
      const float* cf = coeff + ((b<<6)+ch)*8;
      float4 ca = *(const float4*)cf;
      float4 cb = *(const float4*)(cf+4);
      float F00=ca.x, cR=ca.y, cI=ca.z, rR=ca.w, rI=cb.x, dR=cb.y, dI=cb.z;
      bf16x4 xr4 = *(const bf16x4*)(xc + ibase + ((i64)ch<<16) + 4*lm);
      float rowR = F00 + rR*crow + rI*srow;
      float rowI = rI*crow - rR*srow;
      #pragma unroll
      for (int e=0;e<4;e++){
        float re = rowR + cR*cx[e] + cI*sx[e] + dR*cd[e] + dI*sd[e];
        float im = rowI + cI*cx[e] - cR*sx[e] + dI*cd[e] - dR*sd[e];
        re*=fl; im*=fl;
        float vl = sqrtf(re*re+im*im);
        float hr = (float)xr4[e] - re;
        float vh = sqrtf(hr*hr + im*im);
        bfh[s][e][j] = (__bf16)vh;
        bfl[s][e][j] = (__bf16)vl;
      }
    }
  }
  {
    MM_COMPUTE2(qwh, bfh)
    MM_STORE_BF(outh)
  }
  {
    MM_COMPUTE2(qwl, bfl)
    MM_STORE_BF(outl)
  }
}

// ---------------- fused conv1x1 from y (X8): kv0, kv1, q2 -- one y read ----------------
__global__ __launch_bounds__(256) void k_kvq(const float* __restrict__ yin,
      const float* __restrict__ kvw0, const float* __restrict__ kvw1, const float* __restrict__ qw2,
      __bf16* __restrict__ k0o, __bf16* __restrict__ v0o,
      __bf16* __restrict__ k1o, __bf16* __restrict__ v1o, __bf16* __restrict__ q2o){
  X8_SETUP
  bf16x8 bf[2][8];
  X8_FILL_F32(yin + ibase)
  X8_MM_BF(kvw0,        bf, k0o)
  X8_MM_BF(kvw0 + 4096, bf, v0o)
  X8_MM_BF(kvw1,        bf, k1o)
  X8_MM_BF(kvw1 + 4096, bf, v1o)
  X8_MM_BF(qw2,         bf, q2o)
}

// ---------------- fused comb + refine conv1x1 + kv2 conv1x1 (agg via LDS, never global) ----------------
// Each X8 wave's comb output (all 64 ch for its own 128 px) is exactly the B-fragment set
// it needs for the kv matmul -> agg round-trips through LDS only. Same bf16 values as the
// old global agg -> bit-identical.
__global__ __launch_bounds__(256) void k_comb_kvb(const __bf16* __restrict__ lo2, const __bf16* __restrict__ hi2,
        const float* __restrict__ swb, const float* __restrict__ cwv,
        const float* __restrict__ w, const float* __restrict__ bias,
        const float* __restrict__ wkv,
        __bf16* __restrict__ kout, __bf16* __restrict__ vout){
  __shared__ __bf16 aggl[64][514];    // [ch][block-local px], +2 px pad
  X8_SETUP
  int pxl = wvi*128 + 8*lm;           // block-local px base for this lane
  const float* swp = swb + ((i64)b<<16) + p0 + 8*lm;
  float4 sw0 = *(const float4*)swp;
  float4 sw1 = *(const float4*)(swp+4);
  float swv[8] = {sw0.x,sw0.y,sw0.z,sw0.w,sw1.x,sw1.y,sw1.z,sw1.w};
  bf16x8 bf[2][8];
  #pragma unroll
  for (int s=0;s<2;s++){
    #pragma unroll
    for (int j=0;j<8;j++){
      int ch = s*32 + kg*8 + j;
      bf16x8 l8 = *(const bf16x8*)(lo2 + ibase + ((i64)ch<<16) + 8*lm);
      bf16x8 h8 = *(const bf16x8*)(hi2 + ibase + ((i64)ch<<16) + 8*lm);
      float cw = cwv[(b<<6) + ch];
      #pragma unroll
      for (int e=0;e<8;e++) bf[s][e][j] = (__bf16)((float)l8[e]*swv[e] + (float)h8[e]*cw);
    }
  }
  #pragma unroll
  for (int m=0;m<4;m++){
    X8_ACC_M(w, bf)
    #pragma unroll
    for (int r=0;r<4;r++){
      int oc = m*16 + kg*4 + r;
      float bv = bias[oc];
      bf16x8 ov;
      #pragma unroll
      for (int e=0;e<8;e++) ov[e]=(__bf16)(acc[e][r]+bv);
      *(bf16x8*)(&aggl[oc][pxl]) = ov;
    }
  }
  __syncthreads();
  // rebuild B-frags from LDS agg (same wave's px, all 64 ch)
  bf16x8 bf2[2][8];
  #pragma unroll
  for (int s=0;s<2;s++){
    #pragma unroll
    for (int j=0;j<8;j++){
      int ch = s*32 + kg*8 + j;
      bf16x8 u_ = *(const bf16x8*)(&aggl[ch][pxl]);
      #pragma unroll
      for (int e=0;e<8;e++) bf2[s][e][j] = u_[e];
    }
  }
  X8_MM_BF(wkv,        bf2, kout)
  X8_MM_BF(wkv + 4096, bf2, vout)
}

// ---------------- merged mconv hi + lo (double-grid) ----------------
__global__ __launch_bounds__(256) void k_mm_hilo(const __bf16* __restrict__ va, const __bf16* __restrict__ vb,
        const float* __restrict__ M0, const float* __restrict__ M1,
        float* __restrict__ mx, float* __restrict__ mn,
        __bf16* __restrict__ outa, __bf16* __restrict__ outb,
        float* __restrict__ spart, int hgrid){
  __shared__ float ls[4][64], lmx[4][64];
  int bx = blockIdx.x;
  int set = (bx >= hgrid) ? 1 : 0;
  int blk = bx - set*hgrid;
  X8_SETUP_BLK(blk)
  if (set == 0){
    // hi: M0 x va + per-px channel max/mean
    bf16x8 bf[2][8];
    X8_FILL_BF(va + ibase)
    const float* Wb = M0 + ((i64)b<<12);
    float smx[8], ssum[8];
    #pragma unroll
    for (int e=0;e<8;e++){ smx[e]=-1e30f; ssum[e]=0.f; }
    #pragma unroll
    for (int m=0;m<4;m++){
      X8_ACC_M(Wb, bf)
      X8_ST_BF(outa)
      #pragma unroll
      for (int r=0;r<4;r++){
        #pragma unroll
        for (int e=0;e<8;e++){ smx[e]=fmaxf(smx[e],acc[e][r]); ssum[e]+=acc[e][r]; }
      }
    }
    #pragma unroll
    for (int e=0;e<8;e++){
      smx[e] = fmaxf(smx[e], __shfl_xor(smx[e],16));
      smx[e] = fmaxf(smx[e], __shfl_xor(smx[e],32));
      ssum[e] += __shfl_xor(ssum[e],16);
      ssum[e] += __shfl_xor(ssum[e],32);
    }
    if (kg==0){
      i64 pbase = ((i64)b<<16) + p0 + 8*lm;
      *(float4*)(mx+pbase)   = make_float4(smx[0],smx[1],smx[2],smx[3]);
      *(float4*)(mx+pbase+4) = make_float4(smx[4],smx[5],smx[6],smx[7]);
      const float iv = 1.0f/64.0f;
      *(float4*)(mn+pbase)   = make_float4(ssum[0]*iv,ssum[1]*iv,ssum[2]*iv,ssum[3]*iv);
      *(float4*)(mn+pbase+4) = make_float4(ssum[4]*iv,ssum[5]*iv,ssum[6]*iv,ssum[7]*iv);
    }
  } else {
    // lo: M1 x vb + per-channel sum/max partials
    bf16x8 bf[2][8];
    X8_FILL_BF(vb + ibase)
    const float* Wb = M1 + ((i64)b<<12);
    #pragma unroll
    for (int m=0;m<4;m++){
      X8_ACC_M(Wb, bf)
      X8_ST_BF(outb)
      #pragma unroll
      for (int r=0;r<4;r++){
        int oc = m*16 + kg*4 + r;
        float s = 0.f, mm = -1e30f;
        #pragma unroll
        for (int e=0;e<8;e++){ s += acc[e][r]; mm = fmaxf(mm, acc[e][r]); }
        #pragma unroll
        for (int off=8; off; off>>=1){ s += __shfl_xor(s,off); mm = fmaxf(mm,__shfl_xor(mm,off)); }
        if (lm==0){ ls[wvi][oc]=s; lmx[wvi][oc]=mm; }
      }
    }
    __syncthreads();
    if (t<64){
      float s = ls[0][t]+ls[1][t]+ls[2][t]+ls[3][t];
      float mm = fmaxf(fmaxf(lmx[0][t],lmx[1][t]),fmaxf(lmx[2][t],lmx[3][t]));
      spart[(i64)blk*128 + t*2]   = s;
      spart[(i64)blk*128 + t*2+1] = mm;
    }
  }
}

// ---------------- final mconv (X8): M x v, *para1 + y*para2, fp32 out ----------------
__global__ __launch_bounds__(256) void k_mm_fin(const __bf16* __restrict__ v, const float* __restrict__ M,
      const float* __restrict__ para1, const float* __restrict__ para2,
      const float* __restrict__ yin, float* __restrict__ out){
  X8_SETUP
  bf16x8 bf[2][8];
  X8_FILL_BF(v + ibase)
  const float* Wb = M + ((i64)b<<12);
  #pragma unroll
  for (int m=0;m<4;m++){
    X8_ACC_M(Wb, bf)
    #pragma unroll
    for (int r=0;r<4;r++){
      int oc = m*16 + kg*4 + r;
      float p1 = para1[oc], p2 = para2[oc];
      const float* yp = yin + ibase + ((i64)oc<<16) + 8*lm;
      float4 y0 = *(const float4*)yp;
      float4 y1 = *(const float4*)(yp+4);
      float* op = out + ibase + ((i64)oc<<16) + 8*lm;
      *(float4*)op     = make_float4(acc[0][r]*p1+y0.x*p2, acc[1][r]*p1+y0.y*p2,
                                     acc[2][r]*p1+y0.z*p2, acc[3][r]*p1+y0.w*p2);
      *(float4*)(op+4) = make_float4(acc[4][r]*p1+y1.x*p2, acc[5][r]*p1+y1.y*p2,
                                     acc[6][r]*p1+y1.z*p2, acc[7][r]*p1+y1.w*p2);
    }
  }
}

// ---------------- Gram-MFMA stats w/ LDS 2-row staging, merged double-set dispatch ----------------
// 2 rows staged per barrier (18 -> 9 syncs); same per-row math + MFMA order.
__global__ __launch_bounds__(256) void k_gram(const __bf16* __restrict__ q0, const __bf16* __restrict__ kk0,
        const __bf16* __restrict__ q1, const __bf16* __restrict__ kk1,
        const float* __restrict__ qdw0, const float* __restrict__ kdw0,
        const float* __restrict__ qdw1, const float* __restrict__ kdw1,
        float* __restrict__ part, int hgrid){
  __shared__ __bf16 lds[2][2][16][264];
  __shared__ float red[4][16][16];
  int bx = blockIdx.x;
  int set = (bx >= hgrid) ? 1 : 0;
  int blk = bx - set*hgrid;
  const __bf16* qpre = set ? q1 : q0;
  const __bf16* kpre = set ? kk1 : kk0;
  const float* qdw = set ? qdw1 : qdw0;
  const float* kdw = set ? kdw1 : kdw0;
  float* ppart = part + (i64)set*hgrid*80;
  int rowblk = blk & 15;
  int bh = blk >> 4;
  int h = bh & 7, b = bh >> 3;
  int t = threadIdx.x;
  int lane = t & 63, wvi = t >> 6;
  int lm = lane & 15, kg = lane >> 4;
  const float* wp = (lm < 8 ? qdw : kdw) + h*72 + (lm&7)*9;
  float w0=wp[0],w1=wp[1],w2=wp[2],w3=wp[3],w4=wp[4],w5=wp[5],w6=wp[6],w7=wp[7],w8=wp[8];
  int p = t >> 4, seg = t & 15;
  const __bf16* plbase = (p < 8 ? qpre : kpre) + (((i64)((b<<6)+(h<<3)+(p&7)))<<16);
  int R0 = rowblk*16;

  float h0c[2][8], h1c[2][8];
  #pragma unroll
  for (int cc=0;cc<2;cc++)
    #pragma unroll
    for (int e=0;e<8;e++){ h0c[cc][e]=0.f; h1c[cc][e]=0.f; }
  f32x4 acc = {0.f,0.f,0.f,0.f};

  // stage rows ir, ir+1 into buffer bi
  auto stage2 = [&](int bi, int ir){
    #pragma unroll
    for (int rr=0;rr<2;rr++){
      int r_ = ir + rr;
      __bf16* dst = &lds[bi][rr][p][seg*16];
      if ((unsigned)r_ < 256u){
        const __bf16* src = plbase + r_*256 + seg*16;
        bf16x8 a = *(const bf16x8*)src;
        bf16x8 c = *(const bf16x8*)(src+8);
        *(bf16x8*)dst = a; *(bf16x8*)(dst+8) = c;
      } else {
        bf16x8 z = {};
        *(bf16x8*)dst = z; *(bf16x8*)(dst+8) = z;
      }
    }
  };

  stage2(0, R0-1);
  __syncthreads();
  int buf = 0;
  for (int pr = 0; pr < 9; pr++){
    int irbase = R0-1 + 2*pr;
    if (pr < 8) stage2(buf^1, irbase+2);
    #pragma unroll
    for (int rr=0;rr<2;rr++){
      int ir = irbase + rr;
      const __bf16* rowp = &lds[buf][rr][lm][0];
      #pragma unroll
      for (int cc=0; cc<2; cc++){
        int xb = (wvi*2 + cc)*32 + kg*8;
        bf16x8 mid = *(const bf16x8*)(rowp + xb);
        float win[10];
        win[0] = (xb==0)   ? 0.f : (float)rowp[xb-1];
        #pragma unroll
        for (int w=1; w<9; w++) win[w] = (float)mid[w-1];
        win[9] = (xb==248) ? 0.f : (float)rowp[xb+8];
        float o[8];
        #pragma unroll
        for (int e=0;e<8;e++){
          float t0 = w0*win[e] + w1*win[e+1] + w2*win[e+2];
          float t1 = w3*win[e] + w4*win[e+1] + w5*win[e+2];
          float t2 = w6*win[e] + w7*win[e+1] + w8*win[e+2];
          o[e] = h0c[cc][e] + t2;
          h0c[cc][e] = h1c[cc][e] + t1;
          h1c[cc][e] = t0;
        }
        if (ir > R0){
          bf16x8 xf;
          #pragma unroll
          for (int e=0;e<8;e++) xf[e] = (__bf16)o[e];
          acc = MFMA16(xf, xf, acc);
        }
      }
    }
    __syncthreads();
    buf ^= 1;
  }
  #pragma unroll
  for (int r=0;r<4;r++) red[wvi][kg*4+r][lm] = acc[r];
  __syncthreads();
  if (t < 80){
    int r, c;
    if (t < 64){ r = t>>3; c = 8 + (t&7); }
    else if (t < 72){ r = t-64; c = r; }
    else { r = 8 + (t-72); c = r; }
    float s = red[0][r][c]+red[1][r][c]+red[2][r][c]+red[3][r][c];
    ppart[(i64)blk*80 + t] = s;
  }
}

__global__ __launch_bounds__(128) void k_stats_fin(const float* __restrict__ part, float* __restrict__ stats){
  int bh = blockIdx.x; int t = threadIdx.x;
  if (t < 80){
    float s=0.f;
    for (int c=0;c<NCHUNK;c++) s += part[((i64)bh*NCHUNK+c)*80 + t];
    stats[bh*80+t] = s;
  }
}

// ---------------- softmax + fold attn into 64x64 M (merged: super-b over 2 sets) ----------------
__global__ __launch_bounds__(64) void k_attn_m(const float* __restrict__ stats, const float* __restrict__ temp,
                         const float* __restrict__ projw, float* __restrict__ M, int nb){
  __shared__ float attn[8][8][8];
  int bsup = blockIdx.x; int t = threadIdx.x;
  int set = (bsup >= nb) ? 1 : 0;
  int h = t >> 3, cc = t & 7;
  const float* st = stats + (bsup*8+h)*80;
  float nq = fmaxf(sqrtf(st[64+cc]), 1e-12f);
  float tmp = temp[set*8 + h];
  const float* pw = projw + set*4096;
  float s[8];
  float mx = -1e30f;
  #pragma unroll
  for (int d=0;d<8;d++){
    float nk = fmaxf(sqrtf(st[72+d]), 1e-12f);
    s[d] = st[cc*8+d]/(nq*nk)*tmp;
    mx = fmaxf(mx, s[d]);
  }
  float sum=0.f;
  #pragma unroll
  for (int d=0;d<8;d++){ s[d]=expf(s[d]-mx); sum+=s[d]; }
  float inv = 1.0f/sum;
  #pragma unroll
  for (int d=0;d<8;d++) attn[h][cc][d] = s[d]*inv;
  __syncthreads();
  int o = t;
  for (int hh=0; hh<8; hh++){
    #pragma unroll
    for (int d=0; d<8; d++){
      float acc=0.f;
      #pragma unroll
      for (int c2=0;c2<8;c2++) acc += pw[o*64 + hh*8 + c2]*attn[hh][c2][d];
      M[((i64)bsup*64 + o)*64 + hh*8 + d] = acc;
    }
  }
}

// ---------------- depthwise 3x3 (v path), merged double-set dispatch ----------------
__global__ __launch_bounds__(256) void k_dwb(const __bf16* __restrict__ in0, const __bf16* __restrict__ in1,
        const float* __restrict__ wd0, const float* __restrict__ wd1,
        __bf16* __restrict__ out0, __bf16* __restrict__ out1, int hgrid){
  int bx = blockIdx.x;
  int set = (bx >= hgrid) ? 1 : 0;
  int blk = bx - set*hgrid;
  const __bf16* in = set ? in1 : in0;
  const float* wd = set ? wd1 : wd0;
  __bf16* out = set ? out1 : out0;
  int half = blk & 1; int c = (blk>>1)&63; int b = blk>>7;
  int t = threadIdx.x;
  int strip = t & 31, rg = t >> 5;
  const __bf16* ip = in + (((i64)((b<<6)+c))<<16);
  __bf16* op = out + (((i64)((b<<6)+c))<<16);
  const float* wp = wd + c*9;
  float w0=wp[0],w1=wp[1],w2=wp[2],w3=wp[3],w4=wp[4],w5=wp[5],w6=wp[6],w7=wp[7],w8=wp[8];
  int R0 = half*128 + rg*16;
  int xb = strip*8;
  bool left = (xb==0), right = (xb==248);
  float h0[8], h1[8];
  #pragma unroll
  for (int e=0;e<8;e++){ h0[e]=0.f; h1[e]=0.f; }
  for (int ir = R0-1; ir <= R0+16; ir++){
    bool rok = ((unsigned)ir < 256u);
    float win[10];
    if (rok){
      const __bf16* rp = ip + ir*256 + xb;
      bf16x8 mid = *(const bf16x8*)rp;
      win[0] = left ? 0.f : (float)rp[-1];
      #pragma unroll
      for (int w=1; w<9; w++) win[w] = (float)mid[w-1];
      win[9] = right ? 0.f : (float)rp[8];
    } else {
      #pragma unroll
      for (int w=0; w<10; w++) win[w] = 0.f;
    }
    float o[8];
    #pragma unroll
    for (int e=0;e<8;e++){
      float t0 = w0*win[e] + w1*win[e+1] + w2*win[e+2];
      float t1 = w3*win[e] + w4*win[e+1] + w5*win[e+2];
      float t2 = w6*win[e] + w7*win[e+1] + w8*win[e+2];
      o[e] = h0[e] + t2;
      h0[e] = h1[e] + t1;
      h1[e] = t0;
    }
    if (ir > R0){
      bf16x8 ov;
      #pragma unroll
      for (int e=0;e<8;e++) ov[e] = (__bf16)o[e];
      *(bf16x8*)(op + (ir-1)*256 + xb) = ov;
    }
  }
}

// ---------------- refine small kernels ----------------
__global__ __launch_bounds__(64) void k_spatfin(const float* __restrict__ spart, float* __restrict__ lmean, float* __restrict__ lmax){
  int b = blockIdx.x; int c = threadIdx.x;
  float s=0.f, m=-1e30f;
  for (int r=0;r<128;r++){
    s += spart[(i64)(b*128+r)*128 + c*2];
    m = fmaxf(m, spart[(i64)(b*128+r)*128 + c*2+1]);
  }
  lmean[b*64+c] = s*(1.0f/65536.0f);
  lmax[b*64+c]  = m;
}

__global__ __launch_bounds__(64) void k_cw(const float* __restrict__ mean, const float* __restrict__ mxv,
                     const float* __restrict__ w1, const float* __restrict__ w2, float* __restrict__ cw){
  __shared__ float ha[4], hm[4];
  int b = blockIdx.x; int t = threadIdx.x;
  if (t < 4){
    float sa=0.f, sm_=0.f;
    for (int c=0;c<64;c++){ sa += w1[t*64+c]*mean[b*64+c]; sm_ += w1[t*64+c]*mxv[b*64+c]; }
    ha[t] = fmaxf(sa, 0.f); hm[t] = fmaxf(sm_, 0.f);
  }
  __syncthreads();
  float a=0.f;
  #pragma unroll
  for (int j=0;j<4;j++) a += w2[t*4+j]*(ha[j]+hm[j]);
  cw[b*64+t] = sigm(a);
}

__global__ __launch_bounds__(256) void k_sw(const float* __restrict__ mx, const float* __restrict__ mn,
                     const float* __restrict__ w, float* __restrict__ sw){
  int row = blockIdx.x & 255; int b = blockIdx.x >> 8; int t = threadIdx.x;
  const float* m0 = mx + ((i64)b<<16);
  const float* m1 = mn + ((i64)b<<16);
  float acc=0.f;
  for (int ky=0;ky<7;ky++){
    int yy = row+ky-3; if ((unsigned)yy>255u) continue;
    for (int kx=0;kx<7;kx++){
      int xx = t+kx-3; if ((unsigned)xx>255u) continue;
      acc += w[ky*7+kx]*m0[yy*256+xx] + w[49+ky*7+kx]*m1[yy*256+xx];
    }
  }
  sw[((i64)b<<16) + row*256 + t] = sigm(acc);
}

// =====================================================================================
extern "C" void kernel_launch(void* const* d_in, const int* in_sizes, int n_in,
                              void* d_out, int out_size, void* d_ws, size_t ws_size,
                              hipStream_t stream){
  const float* x      = (const float*)d_in[0];
  const float* y      = (const float*)d_in[1];
  const float* conv1w = (const float*)d_in[2];
  const float* ratew1 = (const float*)d_in[3];
  const float* ratew2 = (const float*)d_in[4];
  const float* temp   = (const float*)d_in[5];
  const float* qw     = (const float*)d_in[6];
  const float* qdw    = (const float*)d_in[7];
  const float* kvw    = (const float*)d_in[8];
  const float* kvdw   = (const float*)d_in[9];
  const float* projw  = (const float*)d_in[10];
  const float* spw    = (const float*)d_in[11];
  const float* cgw1   = (const float*)d_in[12];
  const float* cgw2   = (const float*)d_in[13];
  const float* rprojw = (const float*)d_in[14];
  const float* rprojb = (const float*)d_in[15];
  const float* para1  = (const float*)d_in[16];
  const float* para2  = (const float*)d_in[17];
  float* D = (float*)d_out;

  // pick largest batch-group size whose footprint fits: 3 big units + pool
  int nb = 8;
  for (;;){
    size_t unit = (size_t)nb*64*HW_;
    size_t pool = (size_t)nb*3*HW_            // Rbuf
                + (size_t)nb*512 + (size_t)nb*64 + 64
                + 2*(size_t)nb*8*NCHUNK*80    // part (2 sets)
                + 2*(size_t)nb*8*80           // stats (2 sets)
                + 2*(size_t)nb*64*64          // M (2 sets)
                + 3*(size_t)nb*HW_            // mxmap, mnmap, swb
                + (size_t)nb*128*128          // spart
                + 3*(size_t)nb*64;            // lmean, lmax, cwb
    if ((3*unit + pool)*sizeof(float) <= ws_size || nb==1) break;
    nb >>= 1;
  }

  size_t unit = (size_t)nb*64*HW_;
  float* U0 = (float*)d_ws;
  float* U1 = U0 + unit;
  float* U2 = U1 + unit;
  float* sm = U2 + unit;
  float* Rbuf  = sm;  sm += (size_t)nb*3*HW_;
  float* coeff = sm;  sm += (size_t)nb*512;
  float* pooled= sm;  sm += (size_t)nb*64;
  float* flagb = sm;  sm += 64;
  float* part  = sm;  sm += 2*(size_t)nb*8*NCHUNK*80;
  float* stats = sm;  sm += 2*(size_t)nb*8*80;
  float* Mb    = sm;  sm += 2*(size_t)nb*64*64;
  float* mxmap = sm;  sm += (size_t)nb*HW_;
  float* mnmap = sm;  sm += (size_t)nb*HW_;
  float* swb   = sm;  sm += (size_t)nb*HW_;
  float* spart = sm;  sm += (size_t)nb*128*128;
  float* lmean = sm;  sm += (size_t)nb*64;
  float* lmax  = sm;  sm += (size_t)nb*64;
  float* cwb   = sm;  sm += (size_t)nb*64;

  int hgr = nb*8*NCHUNK;     // gram half-grid
  int hdw = nb*128;          // dwb half-grid
  int hmm = nb*128;          // X8 half-grid

  for (int b0 = 0; b0 < 8; b0 += nb){
    const float* yg = y + (i64)b0*64*HW_;
    float*       Dg = D + (i64)b0*64*HW_;
    // bf16 tensor slots: each fp32 unit region holds TWO bf16 tensors of `unit` elements.
    __bf16* U0a = (__bf16*)U0; __bf16* U0c = U0a + unit;
    __bf16* U1a = (__bf16*)U1; __bf16* U1c = U1a + unit;
    __bf16* U2a = (__bf16*)U2; __bf16* U2c = U2a + unit;
    __bf16* Dga = (__bf16*)Dg; __bf16* Dgc = Dga + unit;
    float* Mb1 = Mb + (i64)nb*4096;

    // frontend (xc bf16 in U0a)
    k_resize <<<nb*3*256, 256,0,stream>>>(x, Rbuf, b0);
    k_conv3  <<<nb*256,   256,0,stream>>>(Rbuf, conv1w, U0a);          // xc = U0a (bf16)
    k_dft    <<<nb*64,    256,0,stream>>>(U0a, coeff, pooled);
    k_thr    <<<nb,       64, 0,stream>>>(pooled, ratew1, ratew2, flagb);

    // fused q-recon (cca0-high + cca1-low); xc dead after
    k_convq2 <<<nb*256,256,0,stream>>>(U0a, coeff, flagb, qw + 0*4096, qw + 1*4096, U1a, U1c); // qh=U1a, ql=U1c
    // fused y-matmuls (X8): kv0, kv1, q2-pre
    k_kvq    <<<nb*128,256,0,stream>>>(yg, kvw + 0*8192, kvw + 1*8192, qw + 2*4096,
                                       U2a, Dga, U2c, Dgc, U0c);       // k0,v0,k1,v1,q2

    // merged cca0+cca1 stats pipeline
    k_gram   <<<2*hgr,256,0,stream>>>(U1a, U2a, U1c, U2c,
                                      qdw + 0*576, kvdw + 0*1152, qdw + 1*576, kvdw + 1*1152,
                                      part, hgr);                      // [qh,ql,k0,k1 dead]
    k_stats_fin<<<2*nb*8, 128,0,stream>>>(part, stats);
    k_dwb    <<<2*hdw,256,0,stream>>>(Dga, Dgc, kvdw + 0*1152 + 576, kvdw + 1*1152 + 576,
                                      U1a, U1c, hdw);                  // v0'=U1a, v1'=U1c [v0,v1 dead]
    k_attn_m <<<2*nb, 64,0,stream>>>(stats, temp, projw, Mb, nb);      // Mb0, Mb1

    // merged hi+lo
    k_mm_hilo<<<2*hmm,256,0,stream>>>(U1a, U1c, Mb, Mb1, mxmap, mnmap, Dga, Dgc, spart, hmm);
                                                                       // high2=Dga, low2=Dgc

    // refine weights
    k_spatfin <<<nb,     64, 0,stream>>>(spart, lmean, lmax);
    k_cw      <<<nb,     64, 0,stream>>>(lmean, lmax, cgw1, cgw2, cwb);
    k_sw      <<<nb*256, 256,0,stream>>>(mxmap, mnmap, spw, swb);

    // fused comb + refine-proj + kv2 (agg via LDS, never global)
    k_comb_kvb<<<nb*128,256,0,stream>>>(Dgc, Dga, swb, cwb, rprojw, rprojb,
                                        kvw + 2*8192, U2a, U2c);       // k2=U2a, v2=U2c

    // cca2 (q2=U0c)
    k_gram   <<<hgr,256,0,stream>>>(U0c, U2a, U0c, U2a,
                                    qdw + 2*576, kvdw + 2*1152, qdw + 2*576, kvdw + 2*1152,
                                    part, hgr);
    k_stats_fin<<<nb*8, 128,0,stream>>>(part, stats);
    k_dwb    <<<hdw,256,0,stream>>>(U2c, U2c, kvdw + 2*1152 + 576, kvdw + 2*1152 + 576,
                                    U1a, U1a, hdw);                    // v'=U1a
    k_attn_m <<<nb, 64,0,stream>>>(stats, temp + 2*8, projw + 2*4096, Mb, nb);
    k_mm_fin <<<nb*128,256,0,stream>>>(U1a, Mb, para1, para2, yg, Dg); // out fp32
  }
}

// Round 11
// 740.058 us; speedup vs baseline: 7.1459x; 1.0121x over previous
//
#include <hip/hip_runtime.h>
#include <math.h>

#define HW_ 65536
#define NCHUNK 16
typedef long long i64;
#define TWO_PI 6.283185307179586476925f

typedef __bf16 bf16x8 __attribute__((ext_vector_type(8)));
typedef __bf16 bf16x4 __attribute__((ext_vector_type(4)));
typedef float f32x4 __attribute__((ext_vector_type(4)));

#define MFMA16(A,B,C) __builtin_amdgcn_mfma_f32_16x16x32_bf16(A,B,C,0,0,0)

__device__ __forceinline__ float sigm(float x){ return 1.0f/(1.0f+expf(-x)); }

// convert 8 consecutive fp32 to a bf16x8 A-fragment
__device__ __forceinline__ bf16x8 cvt_w8(const float* wp){
  float4 w0 = *(const float4*)wp;
  float4 w1 = *(const float4*)(wp+4);
  bf16x8 r;
  r[0]=(__bf16)w0.x; r[1]=(__bf16)w0.y; r[2]=(__bf16)w0.z; r[3]=(__bf16)w0.w;
  r[4]=(__bf16)w1.x; r[5]=(__bf16)w1.y; r[6]=(__bf16)w1.z; r[7]=(__bf16)w1.w;
  return r;
}

__device__ __forceinline__ void st_bf4(__bf16* p, float a, float b, float c, float d){
  bf16x4 v; v[0]=(__bf16)a; v[1]=(__bf16)b; v[2]=(__bf16)c; v[3]=(__bf16)d;
  *(bf16x4*)p = v;
}

// ---------------- resize (nb,3,128,128) -> (nb,3,256,256) bilinear half-pixel ----------------
__global__ __launch_bounds__(256) void k_resize(const float* __restrict__ x, float* __restrict__ R, int b0){
  int idx = blockIdx.x*256 + threadIdx.x;
  int ox = idx & 255;
  int oy = (idx >> 8) & 255;
  int bc = idx >> 16;                               // lb*3 + c
  int lb = bc/3; int c = bc - lb*3;
  float sx = ox*0.5f - 0.25f;
  float sy = oy*0.5f - 0.25f;
  int x0 = (int)floorf(sx); float fx = sx - (float)x0;
  int y0 = (int)floorf(sy); float fy = sy - (float)y0;
  int x1 = min(x0+1,127); int y1 = min(y0+1,127);
  x0 = max(x0,0); y0 = max(y0,0);
  const float* p = x + ((i64)(b0+lb)*3 + c)*16384;
  float v00=p[y0*128+x0], v01=p[y0*128+x1], v10=p[y1*128+x0], v11=p[y1*128+x1];
  R[idx] = (1.0f-fy)*((1.0f-fx)*v00 + fx*v01) + fy*((1.0f-fx)*v10 + fx*v11);
}

// ---------------- conv3x3 3->64 (bf16 out): block per (b,row), all 64 outs per thread ----------------
__global__ __launch_bounds__(256) void k_conv3(const float* __restrict__ R, const float* __restrict__ w, __bf16* __restrict__ out){
  int y = blockIdx.x & 255; int b = blockIdx.x >> 8; int t = threadIdx.x;
  float win[27];
  #pragma unroll
  for (int ci=0;ci<3;ci++){
    #pragma unroll
    for (int ky=0;ky<3;ky++){
      int yy = y+ky-1;
      const float* ip = R + (((i64)(b*3+ci))<<16) + yy*256;
      #pragma unroll
      for (int kx=0;kx<3;kx++){
        int xx = t+kx-1;
        float v = 0.f;
        if ((unsigned)yy<256u && (unsigned)xx<256u) v = ip[xx];
        win[ci*9+ky*3+kx] = v;
      }
    }
  }
  i64 obase = ((i64)b<<22) + (y<<8) + t;
  for (int o=0;o<64;o++){
    const float* wp = w + o*27;
    float acc=0.f;
    #pragma unroll
    for (int j=0;j<27;j++) acc += wp[j]*win[j];
    out[obase + ((i64)o<<16)] = (__bf16)acc;
  }
}

// ---------------- DFT coeffs (7 reals incl. DC) + pooled mean per (b,c), bf16 in ----------------
__global__ __launch_bounds__(256) void k_dft(const __bf16* __restrict__ xc, float* __restrict__ coeff, float* __restrict__ pooled){
  __shared__ float tc[256], ts[256];
  __shared__ float red[256];
  int t = threadIdx.x;
  float ang = TWO_PI * ((float)t/256.0f);
  tc[t] = cosf(ang); ts[t] = sinf(ang);
  __syncthreads();
  int bc = blockIdx.x;
  const __bf16* p = xc + (i64)bc*HW_;
  float s=0, cr=0, ci=0, rr=0, ri=0, dr=0, di=0;
  for (int i=t; i<HW_; i+=256){
    float v = (float)p[i];
    int col = i & 255, row = i >> 8, ds = (row+col)&255;
    s  += v;
    cr += v*tc[col]; ci += v*ts[col];
    rr += v*tc[row]; ri += v*ts[row];
    dr += v*tc[ds];  di += v*ts[ds];
  }
  float vals[7] = {s,cr,ci,rr,ri,dr,di};
  for (int j=0;j<7;j++){
    red[t] = vals[j]; __syncthreads();
    for (int st=128; st>0; st>>=1){ if (t<st) red[t]+=red[t+st]; __syncthreads(); }
    if (t==0) vals[j] = red[0];
    __syncthreads();
  }
  if (t==0){
    const float sc = 1.0f/65536.0f;
    for (int j=0;j<7;j++) coeff[bc*8+j] = vals[j]*sc;
    pooled[bc] = vals[0]*sc;
  }
}

// ---------------- threshold MLP -> per-batch mask flag ----------------
__global__ __launch_bounds__(64) void k_thr(const float* __restrict__ pooled, const float* __restrict__ w1,
                      const float* __restrict__ w2, float* __restrict__ flag){
  __shared__ float hid[8];
  int b = blockIdx.x; int t = threadIdx.x;
  if (t < 8){
    float a = 0.f;
    for (int c=0;c<64;c++) a += pooled[b*64+c]*w1[t*64+c];
    hid[t] = 0.5f*a*(1.0f+erff(a*0.70710678118654752440f));
  }
  __syncthreads();
  if (t==0){
    float t0=0,t1=0;
    for (int k=0;k<8;k++){ t0 += hid[k]*w2[k]; t1 += hid[k]*w2[8+k]; }
    int h_ = (int)(2.0f*sigm(t0));
    int w_ = (int)(2.0f*sigm(t1));
    flag[b] = (h_>0 && w_>0) ? 1.0f : 0.0f;
  }
}

#define MM_SETUP \
  int t = threadIdx.x; \
  int lane = t & 63, wvi = t >> 6; \
  i64 px0 = (i64)blockIdx.x*256 + wvi*64; \
  int b = (int)(px0 >> 16); \
  int p0 = (int)(px0 & (HW_-1)); \
  i64 ibase = ((i64)b<<22) + p0; \
  int lm = lane & 15, kg = lane >> 4;

// =====================================================================================
// X8 MM family: 8 px/lane, 128 px/wave, 16B loads+stores, per-m acc (32 VGPR).
// =====================================================================================
#define X8_SETUP_BLK(BLK) \
  int t = threadIdx.x; \
  int lane = t & 63, wvi = t >> 6; \
  i64 px0 = (i64)(BLK)*512 + (i64)wvi*128; \
  int b = (int)(px0 >> 16); \
  int p0 = (int)(px0 & (HW_-1)); \
  i64 ibase = ((i64)b<<22) + p0; \
  int lm = lane & 15, kg = lane >> 4;

#define X8_SETUP X8_SETUP_BLK(blockIdx.x)

#define X8_FILL_F32(in_ptr) \
  _Pragma("unroll") \
  for (int s=0;s<2;s++){ \
    _Pragma("unroll") \
    for (int j=0;j<8;j++){ \
      const float* p_ = (in_ptr) + ((i64)(s*32 + kg*8 + j)<<16) + 8*lm; \
      float4 a_ = *(const float4*)p_; \
      float4 c_ = *(const float4*)(p_+4); \
      bf[s][0][j]=(__bf16)a_.x; bf[s][1][j]=(__bf16)a_.y; bf[s][2][j]=(__bf16)a_.z; bf[s][3][j]=(__bf16)a_.w; \
      bf[s][4][j]=(__bf16)c_.x; bf[s][5][j]=(__bf16)c_.y; bf[s][6][j]=(__bf16)c_.z; bf[s][7][j]=(__bf16)c_.w; \
    } \
  }

#define X8_FILL_BF(in_ptr) \
  _Pragma("unroll") \
  for (int s=0;s<2;s++){ \
    _Pragma("unroll") \
    for (int j=0;j<8;j++){ \
      bf16x8 u_ = *(const bf16x8*)((in_ptr) + ((i64)(s*32 + kg*8 + j)<<16) + 8*lm); \
      _Pragma("unroll") \
      for (int e=0;e<8;e++) bf[s][e][j] = u_[e]; \
    } \
  }

#define X8_ACC_M(Wbase, BF) \
  bf16x8 af0 = cvt_w8((Wbase) + (m*16 + lm)*64 + kg*8); \
  bf16x8 af1 = cvt_w8((Wbase) + (m*16 + lm)*64 + 32 + kg*8); \
  f32x4 acc[8]; \
  _Pragma("unroll") \
  for (int e=0;e<8;e++){ f32x4 z_ = {0.f,0.f,0.f,0.f}; acc[e]=z_; } \
  _Pragma("unroll") \
  for (int e=0;e<8;e++){ acc[e]=MFMA16(af0,BF[0][e],acc[e]); acc[e]=MFMA16(af1,BF[1][e],acc[e]); }

#define X8_ST_BF(outp) \
  _Pragma("unroll") \
  for (int r=0;r<4;r++){ \
    int oc = m*16 + kg*4 + r; \
    bf16x8 ov; \
    _Pragma("unroll") \
    for (int e=0;e<8;e++) ov[e]=(__bf16)acc[e][r]; \
    *(bf16x8*)((outp) + ibase + ((i64)oc<<16) + 8*lm) = ov; \
  }

#define X8_MM_BF(Wbase, BF, outp) \
  _Pragma("unroll") \
  for (int m=0;m<4;m++){ X8_ACC_M(Wbase, BF) X8_ST_BF(outp) }

// ---------------- fused: DFT recon (shared) -> BOTH high & low conv1x1 ----------------
// Per-m accumulator scoping (acc[4] live instead of acc[4][4]x2): VGPR ~224 -> ~130.
// Per-acc MFMA order unchanged (s=0 then s=1) -> bit-identical.
__global__ __launch_bounds__(256) void k_convq2(const __bf16* __restrict__ xc, const float* __restrict__ coeff,
      const float* __restrict__ flag, const float* __restrict__ qwh, const float* __restrict__ qwl,
      __bf16* __restrict__ outh, __bf16* __restrict__ outl){
  __shared__ float tc[256], ts[256];
  {
    int tt = threadIdx.x;
    float ang = TWO_PI * ((float)tt/256.0f);
    tc[tt]=cosf(ang); ts[tt]=sinf(ang);
  }
  __syncthreads();
  MM_SETUP
  float fl = flag[b];
  int y = p0 >> 8;
  int xb = (p0 & 255) + 4*lm;
  bf16x8 bfh[2][4], bfl[2][4];
  {
    float crow = tc[y], srow = ts[y];
    float cx[4], sx[4], cd[4], sd[4];
    #pragma unroll
    for (int e=0;e<4;e++){
      int xx = xb + e;
      cx[e]=tc[xx]; sx[e]=ts[xx];
      int d = (xx + y) & 255;
      cd[e]=tc[d]; sd[e]=ts[d];
    }
    #pragma unroll
    for (int s=0;s<2;s++){
      #pragma unroll
      for (int j=0;j<8;j++){
        int ch = s*32 + kg*8 + j;
        const float* cf = coeff + ((b<<6)+ch)*8;
        float4 ca = *(const float4*)cf;
        float4 cb = *(const float4*)(cf+4);
        float F00=ca.x, cR=ca.y, cI=ca.z, rR=ca.w, rI=cb.x, dR=cb.y, dI=cb.z;
        bf16x4 xr4 = *(const bf16x4*)(xc + ibase + ((i64)ch<<16) + 4*lm);
        float rowR = F00 + rR*crow + rI*srow;
        float rowI = rI*crow - rR*srow;
        #pragma unroll
        for (int e=0;e<4;e++){
          float re = rowR + cR*cx[e] + cI*sx[e] + dR*cd[e] + dI*sd[e];
          float im = rowI + cI*cx[e] - cR*sx[e] + dI*cd[e] - dR*sd[e];
          re*=fl; im*=fl;
          float vl = sqrtf(re*re+im*im);
          float hr = (float)xr4[e] - re;
          float vh = sqrtf(hr*hr + im*im);
          bfh[s][e][j] = (__bf16)vh;
          bfl[s][e][j] = (__bf16)vl;
        }
      }
    }
  }
  // high path, per-m acc
  #pragma unroll
  for (int m=0;m<4;m++){
    bf16x8 af0 = cvt_w8(qwh + (m*16 + lm)*64 + kg*8);
    bf16x8 af1 = cvt_w8(qwh + (m*16 + lm)*64 + 32 + kg*8);
    f32x4 acc[4];
    #pragma unroll
    for (int e=0;e<4;e++){ f32x4 z={0.f,0.f,0.f,0.f}; acc[e]=z; }
    #pragma unroll
    for (int e=0;e<4;e++){ acc[e]=MFMA16(af0,bfh[0][e],acc[e]); acc[e]=MFMA16(af1,bfh[1][e],acc[e]); }
    #pragma unroll
    for (int r=0;r<4;r++){
      int oc = m*16 + kg*4 + r;
      st_bf4(outh + ibase + ((i64)oc<<16) + 4*lm, acc[0][r], acc[1][r], acc[2][r], acc[3][r]);
    }
  }
  // low path, per-m acc
  #pragma unroll
  for (int m=0;m<4;m++){
    bf16x8 af0 = cvt_w8(qwl + (m*16 + lm)*64 + kg*8);
    bf16x8 af1 = cvt_w8(qwl + (m*16 + lm)*64 + 32 + kg*8);
    f32x4 acc[4];
    #pragma unroll
    for (int e=0;e<4;e++){ f32x4 z={0.f,0.f,0.f,0.f}; acc[e]=z; }
    #pragma unroll
    for (int e=0;e<4;e++){ acc[e]=MFMA16(af0,bfl[0][e],acc[e]); acc[e]=MFMA16(af1,bfl[1][e],acc[e]); }
    #pragma unroll
    for (int r=0;r<4;r++){
      int oc = m*16 + kg*4 + r;
      st_bf4(outl + ibase + ((i64)oc<<16) + 4*lm, acc[0][r], acc[1][r], acc[2][r], acc[3][r]);
    }
  }
}

// ---------------- fused conv1x1 from y (X8): kv0, kv1, q2 -- one y read ----------------
__global__ __launch_bounds__(256) void k_kvq(const float* __restrict__ yin,
      const float* __restrict__ kvw0, const float* __restrict__ kvw1, const float* __restrict__ qw2,
      __bf16* __restrict__ k0o, __bf16* __restrict__ v0o,
      __bf16* __restrict__ k1o, __bf16* __restrict__ v1o, __bf16* __restrict__ q2o){
  X8_SETUP
  bf16x8 bf[2][8];
  X8_FILL_F32(yin + ibase)
  X8_MM_BF(kvw0,        bf, k0o)
  X8_MM_BF(kvw0 + 4096, bf, v0o)
  X8_MM_BF(kvw1,        bf, k1o)
  X8_MM_BF(kvw1 + 4096, bf, v1o)
  X8_MM_BF(qw2,         bf, q2o)
}

// ---------------- fused comb + refine conv1x1 + kv2 conv1x1 (agg via LDS, never global) ----------------
__global__ __launch_bounds__(256) void k_comb_kvb(const __bf16* __restrict__ lo2, const __bf16* __restrict__ hi2,
        const float* __restrict__ swb, const float* __restrict__ cwv,
        const float* __restrict__ w, const float* __restrict__ bias,
        const float* __restrict__ wkv,
        __bf16* __restrict__ kout, __bf16* __restrict__ vout){
  __shared__ __bf16 aggl[64][514];    // [ch][block-local px], +2 px pad
  X8_SETUP
  int pxl = wvi*128 + 8*lm;           // block-local px base for this lane
  const float* swp = swb + ((i64)b<<16) + p0 + 8*lm;
  float4 sw0 = *(const float4*)swp;
  float4 sw1 = *(const float4*)(swp+4);
  float swv[8] = {sw0.x,sw0.y,sw0.z,sw0.w,sw1.x,sw1.y,sw1.z,sw1.w};
  bf16x8 bf[2][8];
  #pragma unroll
  for (int s=0;s<2;s++){
    #pragma unroll
    for (int j=0;j<8;j++){
      int ch = s*32 + kg*8 + j;
      bf16x8 l8 = *(const bf16x8*)(lo2 + ibase + ((i64)ch<<16) + 8*lm);
      bf16x8 h8 = *(const bf16x8*)(hi2 + ibase + ((i64)ch<<16) + 8*lm);
      float cw = cwv[(b<<6) + ch];
      #pragma unroll
      for (int e=0;e<8;e++) bf[s][e][j] = (__bf16)((float)l8[e]*swv[e] + (float)h8[e]*cw);
    }
  }
  #pragma unroll
  for (int m=0;m<4;m++){
    X8_ACC_M(w, bf)
    #pragma unroll
    for (int r=0;r<4;r++){
      int oc = m*16 + kg*4 + r;
      float bv = bias[oc];
      bf16x8 ov;
      #pragma unroll
      for (int e=0;e<8;e++) ov[e]=(__bf16)(acc[e][r]+bv);
      *(bf16x8*)(&aggl[oc][pxl]) = ov;
    }
  }
  __syncthreads();
  // rebuild B-frags from LDS agg (same wave's px, all 64 ch)
  bf16x8 bf2[2][8];
  #pragma unroll
  for (int s=0;s<2;s++){
    #pragma unroll
    for (int j=0;j<8;j++){
      int ch = s*32 + kg*8 + j;
      bf16x8 u_ = *(const bf16x8*)(&aggl[ch][pxl]);
      #pragma unroll
      for (int e=0;e<8;e++) bf2[s][e][j] = u_[e];
    }
  }
  X8_MM_BF(wkv,        bf2, kout)
  X8_MM_BF(wkv + 4096, bf2, vout)
}

// ---------------- merged mconv hi + lo (double-grid) ----------------
__global__ __launch_bounds__(256) void k_mm_hilo(const __bf16* __restrict__ va, const __bf16* __restrict__ vb,
        const float* __restrict__ M0, const float* __restrict__ M1,
        float* __restrict__ mx, float* __restrict__ mn,
        __bf16* __restrict__ outa, __bf16* __restrict__ outb,
        float* __restrict__ spart, int hgrid){
  __shared__ float ls[4][64], lmx[4][64];
  int bx = blockIdx.x;
  int set = (bx >= hgrid) ? 1 : 0;
  int blk = bx - set*hgrid;
  X8_SETUP_BLK(blk)
  if (set == 0){
    // hi: M0 x va + per-px channel max/mean
    bf16x8 bf[2][8];
    X8_FILL_BF(va + ibase)
    const float* Wb = M0 + ((i64)b<<12);
    float smx[8], ssum[8];
    #pragma unroll
    for (int e=0;e<8;e++){ smx[e]=-1e30f; ssum[e]=0.f; }
    #pragma unroll
    for (int m=0;m<4;m++){
      X8_ACC_M(Wb, bf)
      X8_ST_BF(outa)
      #pragma unroll
      for (int r=0;r<4;r++){
        #pragma unroll
        for (int e=0;e<8;e++){ smx[e]=fmaxf(smx[e],acc[e][r]); ssum[e]+=acc[e][r]; }
      }
    }
    #pragma unroll
    for (int e=0;e<8;e++){
      smx[e] = fmaxf(smx[e], __shfl_xor(smx[e],16));
      smx[e] = fmaxf(smx[e], __shfl_xor(smx[e],32));
      ssum[e] += __shfl_xor(ssum[e],16);
      ssum[e] += __shfl_xor(ssum[e],32);
    }
    if (kg==0){
      i64 pbase = ((i64)b<<16) + p0 + 8*lm;
      *(float4*)(mx+pbase)   = make_float4(smx[0],smx[1],smx[2],smx[3]);
      *(float4*)(mx+pbase+4) = make_float4(smx[4],smx[5],smx[6],smx[7]);
      const float iv = 1.0f/64.0f;
      *(float4*)(mn+pbase)   = make_float4(ssum[0]*iv,ssum[1]*iv,ssum[2]*iv,ssum[3]*iv);
      *(float4*)(mn+pbase+4) = make_float4(ssum[4]*iv,ssum[5]*iv,ssum[6]*iv,ssum[7]*iv);
    }
  } else {
    // lo: M1 x vb + per-channel sum/max partials
    bf16x8 bf[2][8];
    X8_FILL_BF(vb + ibase)
    const float* Wb = M1 + ((i64)b<<12);
    #pragma unroll
    for (int m=0;m<4;m++){
      X8_ACC_M(Wb, bf)
      X8_ST_BF(outb)
      #pragma unroll
      for (int r=0;r<4;r++){
        int oc = m*16 + kg*4 + r;
        float s = 0.f, mm = -1e30f;
        #pragma unroll
        for (int e=0;e<8;e++){ s += acc[e][r]; mm = fmaxf(mm, acc[e][r]); }
        #pragma unroll
        for (int off=8; off; off>>=1){ s += __shfl_xor(s,off); mm = fmaxf(mm,__shfl_xor(mm,off)); }
        if (lm==0){ ls[wvi][oc]=s; lmx[wvi][oc]=mm; }
      }
    }
    __syncthreads();
    if (t<64){
      float s = ls[0][t]+ls[1][t]+ls[2][t]+ls[3][t];
      float mm = fmaxf(fmaxf(lmx[0][t],lmx[1][t]),fmaxf(lmx[2][t],lmx[3][t]));
      spart[(i64)blk*128 + t*2]   = s;
      spart[(i64)blk*128 + t*2+1] = mm;
    }
  }
}

// ---------------- final mconv (X8): M x v, *para1 + y*para2, fp32 out ----------------
__global__ __launch_bounds__(256) void k_mm_fin(const __bf16* __restrict__ v, const float* __restrict__ M,
      const float* __restrict__ para1, const float* __restrict__ para2,
      const float* __restrict__ yin, float* __restrict__ out){
  X8_SETUP
  bf16x8 bf[2][8];
  X8_FILL_BF(v + ibase)
  const float* Wb = M + ((i64)b<<12);
  #pragma unroll
  for (int m=0;m<4;m++){
    X8_ACC_M(Wb, bf)
    #pragma unroll
    for (int r=0;r<4;r++){
      int oc = m*16 + kg*4 + r;
      float p1 = para1[oc], p2 = para2[oc];
      const float* yp = yin + ibase + ((i64)oc<<16) + 8*lm;
      float4 y0 = *(const float4*)yp;
      float4 y1 = *(const float4*)(yp+4);
      float* op = out + ibase + ((i64)oc<<16) + 8*lm;
      *(float4*)op     = make_float4(acc[0][r]*p1+y0.x*p2, acc[1][r]*p1+y0.y*p2,
                                     acc[2][r]*p1+y0.z*p2, acc[3][r]*p1+y0.w*p2);
      *(float4*)(op+4) = make_float4(acc[4][r]*p1+y1.x*p2, acc[5][r]*p1+y1.y*p2,
                                     acc[6][r]*p1+y1.z*p2, acc[7][r]*p1+y1.w*p2);
    }
  }
}

// ---------------- Gram-MFMA stats w/ LDS 2-row staging, merged double-set dispatch ----------------
__global__ __launch_bounds__(256) void k_gram(const __bf16* __restrict__ q0, const __bf16* __restrict__ kk0,
        const __bf16* __restrict__ q1, const __bf16* __restrict__ kk1,
        const float* __restrict__ qdw0, const float* __restrict__ kdw0,
        const float* __restrict__ qdw1, const float* __restrict__ kdw1,
        float* __restrict__ part, int hgrid){
  __shared__ __bf16 lds[2][2][16][264];
  __shared__ float red[4][16][16];
  int bx = blockIdx.x;
  int set = (bx >= hgrid) ? 1 : 0;
  int blk = bx - set*hgrid;
  const __bf16* qpre = set ? q1 : q0;
  const __bf16* kpre = set ? kk1 : kk0;
  const float* qdw = set ? qdw1 : qdw0;
  const float* kdw = set ? kdw1 : kdw0;
  float* ppart = part + (i64)set*hgrid*80;
  int rowblk = blk & 15;
  int bh = blk >> 4;
  int h = bh & 7, b = bh >> 3;
  int t = threadIdx.x;
  int lane = t & 63, wvi = t >> 6;
  int lm = lane & 15, kg = lane >> 4;
  const float* wp = (lm < 8 ? qdw : kdw) + h*72 + (lm&7)*9;
  float w0=wp[0],w1=wp[1],w2=wp[2],w3=wp[3],w4=wp[4],w5=wp[5],w6=wp[6],w7=wp[7],w8=wp[8];
  int p = t >> 4, seg = t & 15;
  const __bf16* plbase = (p < 8 ? qpre : kpre) + (((i64)((b<<6)+(h<<3)+(p&7)))<<16);
  int R0 = rowblk*16;

  float h0c[2][8], h1c[2][8];
  #pragma unroll
  for (int cc=0;cc<2;cc++)
    #pragma unroll
    for (int e=0;e<8;e++){ h0c[cc][e]=0.f; h1c[cc][e]=0.f; }
  f32x4 acc = {0.f,0.f,0.f,0.f};

  // stage rows ir, ir+1 into buffer bi
  auto stage2 = [&](int bi, int ir){
    #pragma unroll
    for (int rr=0;rr<2;rr++){
      int r_ = ir + rr;
      __bf16* dst = &lds[bi][rr][p][seg*16];
      if ((unsigned)r_ < 256u){
        const __bf16* src = plbase + r_*256 + seg*16;
        bf16x8 a = *(const bf16x8*)src;
        bf16x8 c = *(const bf16x8*)(src+8);
        *(bf16x8*)dst = a; *(bf16x8*)(dst+8) = c;
      } else {
        bf16x8 z = {};
        *(bf16x8*)dst = z; *(bf16x8*)(dst+8) = z;
      }
    }
  };

  stage2(0, R0-1);
  __syncthreads();
  int buf = 0;
  for (int pr = 0; pr < 9; pr++){
    int irbase = R0-1 + 2*pr;
    if (pr < 8) stage2(buf^1, irbase+2);
    #pragma unroll
    for (int rr=0;rr<2;rr++){
      int ir = irbase + rr;
      const __bf16* rowp = &lds[buf][rr][lm][0];
      #pragma unroll
      for (int cc=0; cc<2; cc++){
        int xb = (wvi*2 + cc)*32 + kg*8;
        bf16x8 mid = *(const bf16x8*)(rowp + xb);
        float win[10];
        win[0] = (xb==0)   ? 0.f : (float)rowp[xb-1];
        #pragma unroll
        for (int w=1; w<9; w++) win[w] = (float)mid[w-1];
        win[9] = (xb==248) ? 0.f : (float)rowp[xb+8];
        float o[8];
        #pragma unroll
        for (int e=0;e<8;e++){
          float t0 = w0*win[e] + w1*win[e+1] + w2*win[e+2];
          float t1 = w3*win[e] + w4*win[e+1] + w5*win[e+2];
          float t2 = w6*win[e] + w7*win[e+1] + w8*win[e+2];
          o[e] = h0c[cc][e] + t2;
          h0c[cc][e] = h1c[cc][e] + t1;
          h1c[cc][e] = t0;
        }
        if (ir > R0){
          bf16x8 xf;
          #pragma unroll
          for (int e=0;e<8;e++) xf[e] = (__bf16)o[e];
          acc = MFMA16(xf, xf, acc);
        }
      }
    }
    __syncthreads();
    buf ^= 1;
  }
  #pragma unroll
  for (int r=0;r<4;r++) red[wvi][kg*4+r][lm] = acc[r];
  __syncthreads();
  if (t < 80){
    int r, c;
    if (t < 64){ r = t>>3; c = 8 + (t&7); }
    else if (t < 72){ r = t-64; c = r; }
    else { r = 8 + (t-72); c = r; }
    float s = red[0][r][c]+red[1][r][c]+red[2][r][c]+red[3][r][c];
    ppart[(i64)blk*80 + t] = s;
  }
}

__global__ __launch_bounds__(128) void k_stats_fin(const float* __restrict__ part, float* __restrict__ stats){
  int bh = blockIdx.x; int t = threadIdx.x;
  if (t < 80){
    float s=0.f;
    for (int c=0;c<NCHUNK;c++) s += part[((i64)bh*NCHUNK+c)*80 + t];
    stats[bh*80+t] = s;
  }
}

// ---------------- softmax + fold attn into 64x64 M (merged: super-b over 2 sets) ----------------
__global__ __launch_bounds__(64) void k_attn_m(const float* __restrict__ stats, const float* __restrict__ temp,
                         const float* __restrict__ projw, float* __restrict__ M, int nb){
  __shared__ float attn[8][8][8];
  int bsup = blockIdx.x; int t = threadIdx.x;
  int set = (bsup >= nb) ? 1 : 0;
  int h = t >> 3, cc = t & 7;
  const float* st = stats + (bsup*8+h)*80;
  float nq = fmaxf(sqrtf(st[64+cc]), 1e-12f);
  float tmp = temp[set*8 + h];
  const float* pw = projw + set*4096;
  float s[8];
  float mx = -1e30f;
  #pragma unroll
  for (int d=0;d<8;d++){
    float nk = fmaxf(sqrtf(st[72+d]), 1e-12f);
    s[d] = st[cc*8+d]/(nq*nk)*tmp;
    mx = fmaxf(mx, s[d]);
  }
  float sum=0.f;
  #pragma unroll
  for (int d=0;d<8;d++){ s[d]=expf(s[d]-mx); sum+=s[d]; }
  float inv = 1.0f/sum;
  #pragma unroll
  for (int d=0;d<8;d++) attn[h][cc][d] = s[d]*inv;
  __syncthreads();
  int o = t;
  for (int hh=0; hh<8; hh++){
    #pragma unroll
    for (int d=0; d<8; d++){
      float acc=0.f;
      #pragma unroll
      for (int c2=0;c2<8;c2++) acc += pw[o*64 + hh*8 + c2]*attn[hh][c2][d];
      M[((i64)bsup*64 + o)*64 + hh*8 + d] = acc;
    }
  }
}

// ---------------- depthwise 3x3 (v path), merged double-set dispatch ----------------
__global__ __launch_bounds__(256) void k_dwb(const __bf16* __restrict__ in0, const __bf16* __restrict__ in1,
        const float* __restrict__ wd0, const float* __restrict__ wd1,
        __bf16* __restrict__ out0, __bf16* __restrict__ out1, int hgrid){
  int bx = blockIdx.x;
  int set = (bx >= hgrid) ? 1 : 0;
  int blk = bx - set*hgrid;
  const __bf16* in = set ? in1 : in0;
  const float* wd = set ? wd1 : wd0;
  __bf16* out = set ? out1 : out0;
  int half = blk & 1; int c = (blk>>1)&63; int b = blk>>7;
  int t = threadIdx.x;
  int strip = t & 31, rg = t >> 5;
  const __bf16* ip = in + (((i64)((b<<6)+c))<<16);
  __bf16* op = out + (((i64)((b<<6)+c))<<16);
  const float* wp = wd + c*9;
  float w0=wp[0],w1=wp[1],w2=wp[2],w3=wp[3],w4=wp[4],w5=wp[5],w6=wp[6],w7=wp[7],w8=wp[8];
  int R0 = half*128 + rg*16;
  int xb = strip*8;
  bool left = (xb==0), right = (xb==248);
  float h0[8], h1[8];
  #pragma unroll
  for (int e=0;e<8;e++){ h0[e]=0.f; h1[e]=0.f; }
  for (int ir = R0-1; ir <= R0+16; ir++){
    bool rok = ((unsigned)ir < 256u);
    float win[10];
    if (rok){
      const __bf16* rp = ip + ir*256 + xb;
      bf16x8 mid = *(const bf16x8*)rp;
      win[0] = left ? 0.f : (float)rp[-1];
      #pragma unroll
      for (int w=1; w<9; w++) win[w] = (float)mid[w-1];
      win[9] = right ? 0.f : (float)rp[8];
    } else {
      #pragma unroll
      for (int w=0; w<10; w++) win[w] = 0.f;
    }
    float o[8];
    #pragma unroll
    for (int e=0;e<8;e++){
      float t0 = w0*win[e] + w1*win[e+1] + w2*win[e+2];
      float t1 = w3*win[e] + w4*win[e+1] + w5*win[e+2];
      float t2 = w6*win[e] + w7*win[e+1] + w8*win[e+2];
      o[e] = h0[e] + t2;
      h0[e] = h1[e] + t1;
      h1[e] = t0;
    }
    if (ir > R0){
      bf16x8 ov;
      #pragma unroll
      for (int e=0;e<8;e++) ov[e] = (__bf16)o[e];
      *(bf16x8*)(op + (ir-1)*256 + xb) = ov;
    }
  }
}

// ---------------- fused spatfin + cw: per-batch channel stats reduce + gate MLP ----------------
__global__ __launch_bounds__(64) void k_spatcw(const float* __restrict__ spart,
                     const float* __restrict__ w1, const float* __restrict__ w2, float* __restrict__ cw){
  __shared__ float lm_[64], lx_[64];
  __shared__ float ha[4], hm[4];
  int b = blockIdx.x; int c = threadIdx.x;
  float s=0.f, m=-1e30f;
  for (int r=0;r<128;r++){
    s += spart[(i64)(b*128+r)*128 + c*2];
    m = fmaxf(m, spart[(i64)(b*128+r)*128 + c*2+1]);
  }
  lm_[c] = s*(1.0f/65536.0f);
  lx_[c] = m;
  __syncthreads();
  if (c < 4){
    float sa=0.f, sm_=0.f;
    for (int j=0;j<64;j++){ sa += w1[c*64+j]*lm_[j]; sm_ += w1[c*64+j]*lx_[j]; }
    ha[c] = fmaxf(sa, 0.f); hm[c] = fmaxf(sm_, 0.f);
  }
  __syncthreads();
  float a=0.f;
  #pragma unroll
  for (int j=0;j<4;j++) a += w2[c*4+j]*(ha[j]+hm[j]);
  cw[b*64+c] = sigm(a);
}

__global__ __launch_bounds__(256) void k_sw(const float* __restrict__ mx, const float* __restrict__ mn,
                     const float* __restrict__ w, float* __restrict__ sw){
  int row = blockIdx.x & 255; int b = blockIdx.x >> 8; int t = threadIdx.x;
  const float* m0 = mx + ((i64)b<<16);
  const float* m1 = mn + ((i64)b<<16);
  float acc=0.f;
  for (int ky=0;ky<7;ky++){
    int yy = row+ky-3; if ((unsigned)yy>255u) continue;
    for (int kx=0;kx<7;kx++){
      int xx = t+kx-3; if ((unsigned)xx>255u) continue;
      acc += w[ky*7+kx]*m0[yy*256+xx] + w[49+ky*7+kx]*m1[yy*256+xx];
    }
  }
  sw[((i64)b<<16) + row*256 + t] = sigm(acc);
}

// =====================================================================================
extern "C" void kernel_launch(void* const* d_in, const int* in_sizes, int n_in,
                              void* d_out, int out_size, void* d_ws, size_t ws_size,
                              hipStream_t stream){
  const float* x      = (const float*)d_in[0];
  const float* y      = (const float*)d_in[1];
  const float* conv1w = (const float*)d_in[2];
  const float* ratew1 = (const float*)d_in[3];
  const float* ratew2 = (const float*)d_in[4];
  const float* temp   = (const float*)d_in[5];
  const float* qw     = (const float*)d_in[6];
  const float* qdw    = (const float*)d_in[7];
  const float* kvw    = (const float*)d_in[8];
  const float* kvdw   = (const float*)d_in[9];
  const float* projw  = (const float*)d_in[10];
  const float* spw    = (const float*)d_in[11];
  const float* cgw1   = (const float*)d_in[12];
  const float* cgw2   = (const float*)d_in[13];
  const float* rprojw = (const float*)d_in[14];
  const float* rprojb = (const float*)d_in[15];
  const float* para1  = (const float*)d_in[16];
  const float* para2  = (const float*)d_in[17];
  float* D = (float*)d_out;

  // pick largest batch-group size whose footprint fits: 3 big units + pool
  int nb = 8;
  for (;;){
    size_t unit = (size_t)nb*64*HW_;
    size_t pool = (size_t)nb*3*HW_            // Rbuf
                + (size_t)nb*512 + (size_t)nb*64 + 64
                + 2*(size_t)nb*8*NCHUNK*80    // part (2 sets)
                + 2*(size_t)nb*8*80           // stats (2 sets)
                + 2*(size_t)nb*64*64          // M (2 sets)
                + 3*(size_t)nb*HW_            // mxmap, mnmap, swb
                + (size_t)nb*128*128          // spart
                + (size_t)nb*64;              // cwb
    if ((3*unit + pool)*sizeof(float) <= ws_size || nb==1) break;
    nb >>= 1;
  }

  size_t unit = (size_t)nb*64*HW_;
  float* U0 = (float*)d_ws;
  float* U1 = U0 + unit;
  float* U2 = U1 + unit;
  float* sm = U2 + unit;
  float* Rbuf  = sm;  sm += (size_t)nb*3*HW_;
  float* coeff = sm;  sm += (size_t)nb*512;
  float* pooled= sm;  sm += (size_t)nb*64;
  float* flagb = sm;  sm += 64;
  float* part  = sm;  sm += 2*(size_t)nb*8*NCHUNK*80;
  float* stats = sm;  sm += 2*(size_t)nb*8*80;
  float* Mb    = sm;  sm += 2*(size_t)nb*64*64;
  float* mxmap = sm;  sm += (size_t)nb*HW_;
  float* mnmap = sm;  sm += (size_t)nb*HW_;
  float* swb   = sm;  sm += (size_t)nb*HW_;
  float* spart = sm;  sm += (size_t)nb*128*128;
  float* cwb   = sm;  sm += (size_t)nb*64;

  int hgr = nb*8*NCHUNK;     // gram half-grid
  int hdw = nb*128;          // dwb half-grid
  int hmm = nb*128;          // X8 half-grid

  for (int b0 = 0; b0 < 8; b0 += nb){
    const float* yg = y + (i64)b0*64*HW_;
    float*       Dg = D + (i64)b0*64*HW_;
    // bf16 tensor slots: each fp32 unit region holds TWO bf16 tensors of `unit` elements.
    __bf16* U0a = (__bf16*)U0; __bf16* U0c = U0a + unit;
    __bf16* U1a = (__bf16*)U1; __bf16* U1c = U1a + unit;
    __bf16* U2a = (__bf16*)U2; __bf16* U2c = U2a + unit;
    __bf16* Dga = (__bf16*)Dg; __bf16* Dgc = Dga + unit;
    float* Mb1 = Mb + (i64)nb*4096;

    // frontend (xc bf16 in U0a)
    k_resize <<<nb*3*256, 256,0,stream>>>(x, Rbuf, b0);
    k_conv3  <<<nb*256,   256,0,stream>>>(Rbuf, conv1w, U0a);          // xc = U0a (bf16)
    k_dft    <<<nb*64,    256,0,stream>>>(U0a, coeff, pooled);
    k_thr    <<<nb,       64, 0,stream>>>(pooled, ratew1, ratew2, flagb);

    // fused q-recon (cca0-high + cca1-low); xc dead after
    k_convq2 <<<nb*256,256,0,stream>>>(U0a, coeff, flagb, qw + 0*4096, qw + 1*4096, U1a, U1c); // qh=U1a, ql=U1c
    // fused y-matmuls (X8): kv0, kv1, q2-pre
    k_kvq    <<<nb*128,256,0,stream>>>(yg, kvw + 0*8192, kvw + 1*8192, qw + 2*4096,
                                       U2a, Dga, U2c, Dgc, U0c);       // k0,v0,k1,v1,q2

    // merged cca0+cca1 stats pipeline
    k_gram   <<<2*hgr,256,0,stream>>>(U1a, U2a, U1c, U2c,
                                      qdw + 0*576, kvdw + 0*1152, qdw + 1*576, kvdw + 1*1152,
                                      part, hgr);                      // [qh,ql,k0,k1 dead]
    k_stats_fin<<<2*nb*8, 128,0,stream>>>(part, stats);
    k_dwb    <<<2*hdw,256,0,stream>>>(Dga, Dgc, kvdw + 0*1152 + 576, kvdw + 1*1152 + 576,
                                      U1a, U1c, hdw);                  // v0'=U1a, v1'=U1c [v0,v1 dead]
    k_attn_m <<<2*nb, 64,0,stream>>>(stats, temp, projw, Mb, nb);      // Mb0, Mb1

    // merged hi+lo
    k_mm_hilo<<<2*hmm,256,0,stream>>>(U1a, U1c, Mb, Mb1, mxmap, mnmap, Dga, Dgc, spart, hmm);
                                                                       // high2=Dga, low2=Dgc

    // refine weights
    k_spatcw  <<<nb,     64, 0,stream>>>(spart, cgw1, cgw2, cwb);
    k_sw      <<<nb*256, 256,0,stream>>>(mxmap, mnmap, spw, swb);

    // fused comb + refine-proj + kv2 (agg via LDS, never global)
    k_comb_kvb<<<nb*128,256,0,stream>>>(Dgc, Dga, swb, cwb, rprojw, rprojb,
                                        kvw + 2*8192, U2a, U2c);       // k2=U2a, v2=U2c

    // cca2 (q2=U0c)
    k_gram   <<<hgr,256,0,stream>>>(U0c, U2a, U0c, U2a,
                                    qdw + 2*576, kvdw + 2*1152, qdw + 2*576, kvdw + 2*1152,
                                    part, hgr);
    k_stats_fin<<<nb*8, 128,0,stream>>>(part, stats);
    k_dwb    <<<hdw,256,0,stream>>>(U2c, U2c, kvdw + 2*1152 + 576, kvdw + 2*1152 + 576,
                                    U1a, U1a, hdw);                    // v'=U1a
    k_attn_m <<<nb, 64,0,stream>>>(stats, temp + 2*8, projw + 2*4096, Mb, nb);
    k_mm_fin <<<nb*128,256,0,stream>>>(U1a, Mb, para1, para2, yg, Dg); // out fp32
  }
}